// Round 1
// 1467.733 us; speedup vs baseline: 1.4156x; 1.4156x over previous
//
#include <hip/hip_runtime.h>
#include <hip/hip_bf16.h>
#include <math.h>

typedef __attribute__((ext_vector_type(8))) short short8;
typedef __attribute__((ext_vector_type(4))) float floatx4;

// ---------- helpers ----------
__device__ __forceinline__ float siluf(float x) {
    float e = __expf(-fabsf(x));
    float s = (x >= 0.f) ? 1.f / (1.f + e) : e / (1.f + e);
    return x * s;
}
__device__ __forceinline__ float softplusf(float x) {
    if (x > 20.f) return x;
    if (x < -20.f) return __expf(x);
    return log1pf(__expf(x));
}
__device__ __forceinline__ unsigned short f2b(float v) {
    __hip_bfloat16 b = __float2bfloat16(v);
    unsigned short u;
    __builtin_memcpy(&u, &b, 2);
    return u;
}

// ---------- generic 64x64 tiled GEMM (fp32) — stage A + small stage-C ----------
template<bool ACOL, bool BCOL, bool AMUL, int EPI>
__global__ __launch_bounds__(256) void gemm64(
    const float* __restrict__ A, const float* __restrict__ Bw, float* __restrict__ C,
    const float* __restrict__ A2, const float* __restrict__ bias,
    int M, int N, int K, int lda, int ldb, int ldc, int lda2,
    long batA, long batB, long batC)
{
    __shared__ __align__(16) float As[16][64];
    __shared__ __align__(16) float Bs[16][64];
    int tx = threadIdx.x;
    int m0 = blockIdx.x * 64, n0 = blockIdx.y * 64;
    A += blockIdx.z * batA; Bw += blockIdx.z * batB; C += blockIdx.z * batC;
    int tm = tx >> 4, tn = tx & 15;
    float acc[4][4] = {};
    for (int k0 = 0; k0 < K; k0 += 16) {
        for (int i = tx; i < 1024; i += 256) {
            int mm, kk;
            if (ACOL) { mm = i & 63; kk = i >> 6; } else { kk = i & 15; mm = i >> 4; }
            int m = m0 + mm, k = k0 + kk;
            float v = 0.f;
            if (m < M && k < K) {
                long ia = ACOL ? ((long)k * lda + m) : ((long)m * lda + k);
                v = A[ia];
                if (AMUL) v *= siluf(A2[(long)m * lda2 + k]);
            }
            As[kk][mm] = v;
        }
        for (int i = tx; i < 1024; i += 256) {
            int nn, kk;
            if (BCOL) { kk = i & 15; nn = i >> 4; } else { nn = i & 63; kk = i >> 6; }
            int n = n0 + nn, k = k0 + kk;
            float v = 0.f;
            if (n < N && k < K) {
                long ib = BCOL ? ((long)n * ldb + k) : ((long)k * ldb + n);
                v = Bw[ib];
            }
            Bs[kk][nn] = v;
        }
        __syncthreads();
#pragma unroll
        for (int kk = 0; kk < 16; ++kk) {
            float4 av = *(const float4*)&As[kk][tm * 4];
            float4 bv = *(const float4*)&Bs[kk][tn * 4];
            float a[4] = {av.x, av.y, av.z, av.w};
            float b[4] = {bv.x, bv.y, bv.z, bv.w};
#pragma unroll
            for (int i = 0; i < 4; i++)
#pragma unroll
                for (int j = 0; j < 4; j++) acc[i][j] += a[i] * b[j];
        }
        __syncthreads();
    }
#pragma unroll
    for (int i = 0; i < 4; i++) {
        int m = m0 + tm * 4 + i;
        if (m >= M) continue;
#pragma unroll
        for (int j = 0; j < 4; j++) {
            int n = n0 + tn * 4 + j;
            if (n >= N) continue;
            float v = acc[i][j];
            if (EPI == 1) v = softplusf(v + bias[n]);
            C[(long)m * ldc + n] = v;
        }
    }
}

// ---------- split-K fp32 GEMM: Cpart[z] = A[:, z-chunk] @ B[z-chunk, :] ----------
// A row-major [M][lda], B row-major [K][ldb]. Partial tiles ldc = N.
__global__ __launch_bounds__(256) void gemm64_sk(
    const float* __restrict__ A, const float* __restrict__ Bw, float* __restrict__ Cpart,
    int M, int N, int K, int lda, int ldb, int kch)
{
    __shared__ __align__(16) float As[16][64];
    __shared__ __align__(16) float Bs[16][64];
    int tx = threadIdx.x;
    int m0 = blockIdx.x * 64, n0 = blockIdx.y * 64;
    int kbeg = blockIdx.z * kch;
    int kend = min(kbeg + kch, K);
    Cpart += (long)blockIdx.z * M * N;
    int tm = tx >> 4, tn = tx & 15;
    float acc[4][4] = {};
    for (int k0 = kbeg; k0 < kend; k0 += 16) {
        for (int i = tx; i < 1024; i += 256) {
            int kk = i & 15, mm = i >> 4;
            int m = m0 + mm, k = k0 + kk;
            As[kk][mm] = (m < M && k < kend) ? A[(long)m * lda + k] : 0.f;
        }
        for (int i = tx; i < 1024; i += 256) {
            int nn = i & 63, kk = i >> 6;
            int n = n0 + nn, k = k0 + kk;
            Bs[kk][nn] = (n < N && k < kend) ? Bw[(long)k * ldb + n] : 0.f;
        }
        __syncthreads();
#pragma unroll
        for (int kk = 0; kk < 16; ++kk) {
            float4 av = *(const float4*)&As[kk][tm * 4];
            float4 bv = *(const float4*)&Bs[kk][tn * 4];
            float a[4] = {av.x, av.y, av.z, av.w};
            float b[4] = {bv.x, bv.y, bv.z, bv.w};
#pragma unroll
            for (int i = 0; i < 4; i++)
#pragma unroll
                for (int j = 0; j < 4; j++) acc[i][j] += a[i] * b[j];
        }
        __syncthreads();
    }
#pragma unroll
    for (int i = 0; i < 4; i++) {
        int m = m0 + tm * 4 + i;
        if (m >= M) continue;
#pragma unroll
        for (int j = 0; j < 4; j++) {
            int n = n0 + tn * 4 + j;
            if (n >= N) continue;
            Cpart[(long)m * N + n] = acc[i][j];
        }
    }
}

// ---------- sum nz split-K partial buffers ----------
__global__ void sk_reduce(const float* __restrict__ Cpart, float* __restrict__ C,
                          long len, int nz)
{
    long i = (long)blockIdx.x * 256 + threadIdx.x;
    if (i >= len) return;
    float s = 0.f;
    for (int z = 0; z < nz; z++) s += Cpart[(long)z * len + i];
    C[i] = s;
}

// ---------- bf16 MFMA GEMM: C[M,N] = A[M,K] x B[K,N] ----------
// Abf: bf16 bits, row-major [Mpad][K] (Mpad >= gridDim.x*128)
// Bbf: bf16 bits, B TRANSPOSED layout [N][K]
// 128x128 tile, 4 waves (2x2 of 64x64), 16x16x32 MFMA, BK=32.
__global__ __launch_bounds__(256) void mfma_gemm(
    const unsigned short* __restrict__ Abf, const unsigned short* __restrict__ Bbf,
    float* __restrict__ C, int M, int N, int K, int ldc)
{
    __shared__ __align__(16) short As[128 * 40];   // +8 pad kills ds_read conflicts
    __shared__ __align__(16) short Bs[128 * 40];
    int tid = threadIdx.x;
    int m0 = blockIdx.x * 128, n0 = blockIdx.y * 128;
    int w = tid >> 6, l = tid & 63;
    int wm = (w >> 1) * 64, wn = (w & 1) * 64;
    int lr = l & 15, lq = l >> 4;
    int row0 = tid >> 2, kc = (tid & 3) * 8;
    floatx4 acc[4][4];
#pragma unroll
    for (int i = 0; i < 4; i++)
#pragma unroll
        for (int j = 0; j < 4; j++) acc[i][j] = (floatx4){0.f, 0.f, 0.f, 0.f};
    const unsigned short* Ap  = Abf + (long)(m0 + row0) * K + kc;
    const unsigned short* Ap2 = Abf + (long)(m0 + row0 + 64) * K + kc;
    const unsigned short* Bp  = Bbf + (long)(n0 + row0) * K + kc;
    const unsigned short* Bp2 = Bbf + (long)(n0 + row0 + 64) * K + kc;
    for (int k0 = 0; k0 < K; k0 += 32) {
        uint4 a0 = *(const uint4*)(Ap + k0);
        uint4 a1 = *(const uint4*)(Ap2 + k0);
        uint4 b0 = *(const uint4*)(Bp + k0);
        uint4 b1 = *(const uint4*)(Bp2 + k0);
        __syncthreads();
        *(uint4*)&As[row0 * 40 + kc] = a0;
        *(uint4*)&As[(row0 + 64) * 40 + kc] = a1;
        *(uint4*)&Bs[row0 * 40 + kc] = b0;
        *(uint4*)&Bs[(row0 + 64) * 40 + kc] = b1;
        __syncthreads();
        short8 af[4], bfr[4];
#pragma unroll
        for (int i = 0; i < 4; i++) af[i]  = *(const short8*)&As[(wm + i * 16 + lr) * 40 + lq * 8];
#pragma unroll
        for (int i = 0; i < 4; i++) bfr[i] = *(const short8*)&Bs[(wn + i * 16 + lr) * 40 + lq * 8];
#pragma unroll
        for (int i = 0; i < 4; i++)
#pragma unroll
            for (int j = 0; j < 4; j++)
                acc[i][j] = __builtin_amdgcn_mfma_f32_16x16x32_bf16(af[i], bfr[j], acc[i][j], 0, 0, 0);
    }
#pragma unroll
    for (int i = 0; i < 4; i++) {
#pragma unroll
        for (int r = 0; r < 4; r++) {
            int m = m0 + wm + i * 16 + lq * 4 + r;
            if (m >= M) continue;
#pragma unroll
            for (int j = 0; j < 4; j++)
                C[(long)m * ldc + n0 + wn + j * 16 + lr] = acc[i][j][r];
        }
    }
}

// ---------- fp32 [K][N] -> bf16-bits transposed [N][K] (tiled via LDS) ----------
__global__ __launch_bounds__(256) void tpose_cvt(const float* __restrict__ src,
                                                 unsigned short* __restrict__ dst,
                                                 int K, int N)
{
    __shared__ float t[32][33];
    int n0 = blockIdx.x * 32, k0 = blockIdx.y * 32;
    int tid = threadIdx.x;
    int r = tid >> 3, c4 = (tid & 7) * 4;
    float4 v = *(const float4*)&src[(long)(k0 + r) * N + n0 + c4];
    t[r][c4] = v.x; t[r][c4 + 1] = v.y; t[r][c4 + 2] = v.z; t[r][c4 + 3] = v.w;
    __syncthreads();
    ushort4 o;
    o.x = f2b(t[c4][r]);
    o.y = f2b(t[c4 + 1][r]);
    o.z = f2b(t[c4 + 2][r]);
    o.w = f2b(t[c4 + 3][r]);
    *(ushort4*)&dst[(long)(n0 + r) * K + k0 + c4] = o;
}

// ---------- fp32 [M][C] -> bf16-bits [Mpad][C] (zero pad rows >= M) ----------
__global__ void cvt_pad(const float* __restrict__ src, unsigned short* __restrict__ dst,
                        int M, int Mpad, int C)
{
    long i4 = ((long)blockIdx.x * 256 + threadIdx.x) * 4;
    if (i4 >= (long)Mpad * C) return;
    int row = (int)(i4 / C);
    ushort4 o = {0, 0, 0, 0};
    if (row < M) {
        float4 v = *(const float4*)&src[i4];
        o.x = f2b(v.x); o.y = f2b(v.y); o.z = f2b(v.z); o.w = f2b(v.w);
    }
    *(ushort4*)&dst[i4] = o;
}

// ---------- y * silu(z) -> bf16-bits [Mpad][C] ----------
__global__ void gate_cvt(const float* __restrict__ y, const float* __restrict__ z,
                         unsigned short* __restrict__ dst, int M, int Mpad, int C, int ldz)
{
    long i4 = ((long)blockIdx.x * 256 + threadIdx.x) * 4;
    if (i4 >= (long)Mpad * C) return;
    int row = (int)(i4 / C);
    int col = (int)(i4 - (long)row * C);
    ushort4 o = {0, 0, 0, 0};
    if (row < M) {
        float4 yv = *(const float4*)&y[i4];
        float4 zv = *(const float4*)&z[(long)row * ldz + col];
        o.x = f2b(yv.x * siluf(zv.x));
        o.y = f2b(yv.y * siluf(zv.y));
        o.z = f2b(yv.z * siluf(zv.z));
        o.w = f2b(yv.w * siluf(zv.w));
    }
    *(ushort4*)&dst[i4] = o;
}

// ---------- causal depthwise conv (k=4) + bias + silu ----------
__global__ void conv_silu_kernel(const float* __restrict__ xz, const float* __restrict__ w,
                                 const float* __restrict__ bias, float* __restrict__ out,
                                 int Bn, int L, int din, int ldx)
{
    int idx = blockIdx.x * 256 + threadIdx.x;
    int total = Bn * L * din;
    if (idx >= total) return;
    int c = idx % din;
    int r = idx / din;
    int t = r % L;
    int b = r / L;
    float acc = bias[c];
#pragma unroll
    for (int i = 0; i < 4; i++) {
        int tt = t - 3 + i;
        if (tt >= 0) acc += w[c * 4 + i] * xz[((long)(b * L + tt)) * ldx + c];
    }
    out[idx] = siluf(acc);
}

// ---------- selective scan (u/y may alias) ----------
template<int T>
__global__ __launch_bounds__(256) void scan_kernel(
    const float* u, const float* dt,
    const float* xdbl, const float* __restrict__ A_log,
    const float* __restrict__ Dp, float* y,
    int din, int L, int xld, int boff, int coff)
{
    __shared__ float Bc[T][16], Cc[T][16], dtc[T][16], uc[T][16], yc[T][16];
    int tx = threadIdx.x;
    int dl = tx >> 4;
    int n = tx & 15;
    int dbase = blockIdx.x * 16;
    int dg = dbase + dl;
    int b = blockIdx.y;
    bool act = dg < din;
    float Acoef = act ? -__expf(A_log[dg * 16 + n]) : 0.f;
    float Dv = act ? Dp[dg] : 0.f;
    int nvalid = min(16, din - dbase);
    float h = 0.f;
    for (int c0 = 0; c0 < L; c0 += T) {
        int tcnt = min(T, L - c0);
        for (int i = tx; i < T * 16; i += 256) {
            int tt = i >> 4, c = i & 15;
            if (tt < tcnt) {
                long row = (long)b * L + c0 + tt;
                float uv = 0.f, dv = 0.f;
                if (c < nvalid) { uv = u[row * din + dbase + c]; dv = dt[row * din + dbase + c]; }
                uc[tt][c] = uv; dtc[tt][c] = dv;
                Bc[tt][c] = xdbl[row * xld + boff + c];
                Cc[tt][c] = xdbl[row * xld + coff + c];
            }
        }
        __syncthreads();
        for (int tt = 0; tt < tcnt; ++tt) {
            float dtv = dtc[tt][dl];
            float uv = uc[tt][dl];
            float dA = __expf(dtv * Acoef);
            h = dA * h + (dtv * uv) * Bc[tt][n];
            float p = h * Cc[tt][n];
            p += __shfl_xor(p, 1);
            p += __shfl_xor(p, 2);
            p += __shfl_xor(p, 4);
            p += __shfl_xor(p, 8);
            if (n == 0) yc[tt][dl] = p + Dv * uv;
        }
        __syncthreads();
        for (int i = tx; i < tcnt * 16; i += 256) {
            int tt = i >> 4, c = i & 15;
            if (c < nvalid) y[((long)b * L + c0 + tt) * din + dbase + c] = yc[tt][c];
        }
        __syncthreads();
    }
}

// ---------- mean over n (98) + softmax over k (1024), per batch ----------
__global__ void mean_softmax_kernel(const float* __restrict__ sc2, float* __restrict__ s)
{
    __shared__ float vals[1024];
    __shared__ float red[256];
    int b = blockIdx.x, tx = threadIdx.x;
    for (int k = tx; k < 1024; k += 256) {
        const float* row = sc2 + ((long)b * 1024 + k) * 98;
        float sum = 0.f;
        for (int nn = 0; nn < 98; nn++) sum += row[nn];
        vals[k] = sum * (1.f / 98.f);
    }
    __syncthreads();
    float mx = -1e30f;
    for (int k = tx; k < 1024; k += 256) mx = fmaxf(mx, vals[k]);
    red[tx] = mx; __syncthreads();
    for (int st = 128; st > 0; st >>= 1) { if (tx < st) red[tx] = fmaxf(red[tx], red[tx + st]); __syncthreads(); }
    mx = red[0]; __syncthreads();
    float lsum = 0.f;
    for (int k = tx; k < 1024; k += 256) { float e = __expf(vals[k] - mx); vals[k] = e; lsum += e; }
    red[tx] = lsum; __syncthreads();
    for (int st = 128; st > 0; st >>= 1) { if (tx < st) red[tx] += red[tx + st]; __syncthreads(); }
    float inv = 1.f / red[0];
    __syncthreads();
    for (int k = tx; k < 1024; k += 256) s[(long)b * 1024 + k] = vals[k] * inv;
}

// ---------- top-98 sequential selection (jax tie semantics) ----------
__global__ __launch_bounds__(256) void topk_select_kernel(const float* __restrict__ s,
                                                          int* __restrict__ ind,
                                                          float* __restrict__ vtopk)
{
    __shared__ unsigned long long arr[1024];
    __shared__ unsigned long long red[256];
    int b = blockIdx.x, tx = threadIdx.x;
    for (int k = tx; k < 1024; k += 256) {
        float v = s[b * 1024 + k];
        unsigned u = __float_as_uint(v);
        u = (u & 0x80000000u) ? ~u : (u | 0x80000000u);
        arr[k] = ((unsigned long long)u << 32) | (unsigned)(~k);
    }
    __syncthreads();
    for (int r = 0; r < 98; ++r) {
        unsigned long long m = 0ull;
        for (int k = tx; k < 1024; k += 256) m = (arr[k] > m) ? arr[k] : m;
        red[tx] = m; __syncthreads();
        for (int st = 128; st > 0; st >>= 1) {
            if (tx < st && red[tx + st] > red[tx]) red[tx] = red[tx + st];
            __syncthreads();
        }
        unsigned long long best = red[0];
        if (tx == 0) {
            unsigned lo = (unsigned)(best & 0xffffffffu);
            int kidx = (int)(~lo);
            unsigned ub = (unsigned)(best >> 32);
            unsigned fb = (ub & 0x80000000u) ? (ub ^ 0x80000000u) : ~ub;
            ind[b * 98 + r] = kidx;
            vtopk[b * 98 + r] = __uint_as_float(fb);
            arr[kidx] = 0ull;
        }
        __syncthreads();
    }
}

// ---------- gather: h[b,j,:] = img[j,:] + kf[b,:,ind]*v ----------
__global__ void gather_kernel(const float* __restrict__ img, const float* __restrict__ kf,
                              const int* __restrict__ ind, const float* __restrict__ vtopk,
                              float* __restrict__ h)
{
    int j = blockIdx.x, b = blockIdx.y;
    int kidx = ind[b * 98 + j];
    float v = vtopk[b * 98 + j];
    long hbase = ((long)b * 98 + j) * 2048;
    const float* kfb = kf + (long)b * 2048 * 1024 + kidx;
    for (int d = threadIdx.x; d < 2048; d += 256)
        h[hbase + d] = img[(long)j * 2048 + d] + kfb[(long)d * 1024] * v;
}

// ---------- host launch ----------
extern "C" void kernel_launch(void* const* d_in, const int* in_sizes, int n_in,
                              void* d_out, int out_size, void* d_ws, size_t ws_size,
                              hipStream_t stream)
{
    const float* imgF      = (const float*)d_in[0];
    const float* kf        = (const float*)d_in[1];
    const float* a_in_w    = (const float*)d_in[2];
    const float* a_conv_w  = (const float*)d_in[3];
    const float* a_conv_b  = (const float*)d_in[4];
    const float* a_xproj_w = (const float*)d_in[5];
    const float* a_dt_w    = (const float*)d_in[6];
    const float* a_dt_b    = (const float*)d_in[7];
    const float* a_A_log   = (const float*)d_in[8];
    const float* a_D       = (const float*)d_in[9];
    const float* a_out_w   = (const float*)d_in[10];
    const float* c_in_w    = (const float*)d_in[11];
    const float* c_conv_w  = (const float*)d_in[12];
    const float* c_conv_b  = (const float*)d_in[13];
    const float* c_xproj_w = (const float*)d_in[14];
    const float* c_dt_w    = (const float*)d_in[15];
    const float* c_dt_b    = (const float*)d_in[16];
    const float* c_A_log   = (const float*)d_in[17];
    const float* c_D       = (const float*)d_in[18];
    const float* c_out_w   = (const float*)d_in[19];

    float* fout = (float*)d_out;

    float* ws = (float*)d_ws;
    float* h_buf  = ws;                      // 1,605,632 floats
    float* S      = ws + 1605632;
    // stage A
    float* score  = S;                       // 802,816 (reused as score2)
    float* xz_a   = S + 802816;              // 3,211,264
    float* xi_a   = S + 4014080;             // 1,605,632 (scan in-place)
    float* xdbl_a = S + 5619712;             // 319,488
    float* dt_a   = S + 5939200;             // 1,605,632
    float* sbuf   = S + 7544832;             // 8,192
    int*   indb   = (int*)(S + 7553024);     // 784
    float* vtopk  = S + 7553808;             // 784
    // stage C (aliases stage A region)
    float* xz_c   = S;                       // 6,422,528
    float* xi_c   = S + 6422528;             // 3,211,264 (scan in-place)
    float* xdbl_c = S + 9633792;             // 125,440
    float* dt_c   = S + 9759232;             // 3,211,264
    // bf16 scratch (beyond the fp32 region: base float offset 14,576,128)
    unsigned short* cwbf  = (unsigned short*)(ws + 14576128);          // 16,777,216 bf16
    unsigned short* h_bf  = (unsigned short*)(ws + 14576128 + 8388608);// 1,835,008 bf16
    unsigned short* yz_bf = (unsigned short*)(ws + 14576128 + 9306112);// 3,670,016 bf16
    // split-K partials for step 13: upper half of cwbf region (dead between
    // mfma_gemm #11 and tpose_cvt #16, which brackets step 13).
    // float offset 18,770,432 .. +2,007,040 < 22,964,736 (cwbf end). 16 x 784 x 160.
    float* Cpart  = ws + 18770432;
    // total ws: 25,717,248 floats ~= 103 MB

    // ===== stage A (fp32, unchanged) =====
    gemm64<true, true, false, 0><<<dim3(16, 2, 8), 256, 0, stream>>>(
        kf, imgF, score, nullptr, nullptr,
        1024, 98, 2048, 1024, 2048, 98, 0,
        (long)2048 * 1024, 0L, (long)1024 * 98);
    gemm64<false, false, false, 0><<<dim3(128, 7, 1), 256, 0, stream>>>(
        score, a_in_w, xz_a, nullptr, nullptr, 8192, 392, 98, 98, 392, 392, 0, 0L, 0L, 0L);
    conv_silu_kernel<<<6272, 256, 0, stream>>>(xz_a, a_conv_w, a_conv_b, xi_a, 8, 1024, 196, 392);
    gemm64<false, false, false, 0><<<dim3(128, 1, 1), 256, 0, stream>>>(
        xi_a, a_xproj_w, xdbl_a, nullptr, nullptr, 8192, 39, 196, 196, 39, 39, 0, 0L, 0L, 0L);
    gemm64<false, false, false, 1><<<dim3(128, 4, 1), 256, 0, stream>>>(
        xdbl_a, a_dt_w, dt_a, nullptr, a_dt_b, 8192, 196, 7, 39, 196, 196, 0, 0L, 0L, 0L);
    scan_kernel<64><<<dim3(13, 8, 1), 256, 0, stream>>>(
        xi_a, dt_a, xdbl_a, a_A_log, a_D, xi_a, 196, 1024, 39, 7, 23);
    gemm64<false, false, true, 0><<<dim3(128, 2, 1), 256, 0, stream>>>(
        xi_a, a_out_w, score, xz_a + 196, nullptr, 8192, 98, 196, 196, 98, 98, 392, 0L, 0L, 0L);
    mean_softmax_kernel<<<8, 256, 0, stream>>>(score, sbuf);
    topk_select_kernel<<<8, 256, 0, stream>>>(sbuf, indb, vtopk);
    gather_kernel<<<dim3(98, 8, 1), 256, 0, stream>>>(imgF, kf, indb, vtopk, h_buf);

    // ===== stage C =====
    // 11. xz_c = h @ c_in_w  (bf16 MFMA)
    tpose_cvt<<<dim3(256, 64, 1), 256, 0, stream>>>(c_in_w, cwbf, 2048, 8192);
    cvt_pad<<<1792, 256, 0, stream>>>(h_buf, h_bf, 784, 896, 2048);
    mfma_gemm<<<dim3(7, 64, 1), 256, 0, stream>>>(h_bf, cwbf, xz_c, 784, 8192, 2048, 8192);

    // 12. conv + silu -> xi_c
    conv_silu_kernel<<<12544, 256, 0, stream>>>(xz_c, c_conv_w, c_conv_b, xi_c, 8, 98, 4096, 8192);

    // 13. xdbl_c = xi_c @ c_xproj_w (fp32, split-K x16: 624 blocks instead of 39)
    gemm64_sk<<<dim3(13, 3, 16), 256, 0, stream>>>(
        xi_c, c_xproj_w, Cpart, 784, 160, 4096, 4096, 160, 256);
    sk_reduce<<<490, 256, 0, stream>>>(Cpart, xdbl_c, 125440L, 16);

    // 14. dt_c = softplus(xdbl_c[:, :128] @ c_dt_w + c_dt_b) (fp32)
    gemm64<false, false, false, 1><<<dim3(13, 64, 1), 256, 0, stream>>>(
        xdbl_c, c_dt_w, dt_c, nullptr, c_dt_b, 784, 4096, 128, 160, 4096, 4096, 0, 0L, 0L, 0L);

    // 15. selective scan C (in-place)
    scan_kernel<98><<<dim3(256, 8, 1), 256, 0, stream>>>(
        xi_c, dt_c, xdbl_c, c_A_log, c_D, xi_c, 4096, 98, 160, 128, 144);

    // 16. out = (y_c * silu(z_c)) @ c_out_w  (bf16 MFMA, direct to d_out)
    gate_cvt<<<3584, 256, 0, stream>>>(xi_c, xz_c + 4096, yz_bf, 784, 896, 4096, 8192);
    tpose_cvt<<<dim3(64, 128, 1), 256, 0, stream>>>(c_out_w, cwbf, 4096, 2048);
    mfma_gemm<<<dim3(7, 16, 1), 256, 0, stream>>>(yz_bf, cwbf, fout, 784, 2048, 4096, 2048);
}

// Round 4
// 1331.616 us; speedup vs baseline: 1.5603x; 1.1022x over previous
//
#include <hip/hip_runtime.h>
#include <hip/hip_bf16.h>
#include <math.h>

typedef __attribute__((ext_vector_type(8))) short short8;
typedef __attribute__((ext_vector_type(4))) float floatx4;

// ---------- helpers ----------
__device__ __forceinline__ float siluf(float x) {
    float e = __expf(-fabsf(x));
    float s = (x >= 0.f) ? 1.f / (1.f + e) : e / (1.f + e);
    return x * s;
}
__device__ __forceinline__ float softplusf(float x) {
    if (x > 20.f) return x;
    if (x < -20.f) return __expf(x);
    return log1pf(__expf(x));
}
__device__ __forceinline__ unsigned short f2b(float v) {
    __hip_bfloat16 b = __float2bfloat16(v);
    unsigned short u;
    __builtin_memcpy(&u, &b, 2);
    return u;
}

// ---------- generic 64x64 tiled GEMM (fp32) — stage A + small stage-C ----------
template<bool ACOL, bool BCOL, bool AMUL, int EPI>
__global__ __launch_bounds__(256) void gemm64(
    const float* __restrict__ A, const float* __restrict__ Bw, float* __restrict__ C,
    const float* __restrict__ A2, const float* __restrict__ bias,
    int M, int N, int K, int lda, int ldb, int ldc, int lda2,
    long batA, long batB, long batC)
{
    __shared__ __align__(16) float As[16][64];
    __shared__ __align__(16) float Bs[16][64];
    int tx = threadIdx.x;
    int m0 = blockIdx.x * 64, n0 = blockIdx.y * 64;
    A += blockIdx.z * batA; Bw += blockIdx.z * batB; C += blockIdx.z * batC;
    int tm = tx >> 4, tn = tx & 15;
    float acc[4][4] = {};
    for (int k0 = 0; k0 < K; k0 += 16) {
        for (int i = tx; i < 1024; i += 256) {
            int mm, kk;
            if (ACOL) { mm = i & 63; kk = i >> 6; } else { kk = i & 15; mm = i >> 4; }
            int m = m0 + mm, k = k0 + kk;
            float v = 0.f;
            if (m < M && k < K) {
                long ia = ACOL ? ((long)k * lda + m) : ((long)m * lda + k);
                v = A[ia];
                if (AMUL) v *= siluf(A2[(long)m * lda2 + k]);
            }
            As[kk][mm] = v;
        }
        for (int i = tx; i < 1024; i += 256) {
            int nn, kk;
            if (BCOL) { kk = i & 15; nn = i >> 4; } else { nn = i & 63; kk = i >> 6; }
            int n = n0 + nn, k = k0 + kk;
            float v = 0.f;
            if (n < N && k < K) {
                long ib = BCOL ? ((long)n * ldb + k) : ((long)k * ldb + n);
                v = Bw[ib];
            }
            Bs[kk][nn] = v;
        }
        __syncthreads();
#pragma unroll
        for (int kk = 0; kk < 16; ++kk) {
            float4 av = *(const float4*)&As[kk][tm * 4];
            float4 bv = *(const float4*)&Bs[kk][tn * 4];
            float a[4] = {av.x, av.y, av.z, av.w};
            float b[4] = {bv.x, bv.y, bv.z, bv.w};
#pragma unroll
            for (int i = 0; i < 4; i++)
#pragma unroll
                for (int j = 0; j < 4; j++) acc[i][j] += a[i] * b[j];
        }
        __syncthreads();
    }
#pragma unroll
    for (int i = 0; i < 4; i++) {
        int m = m0 + tm * 4 + i;
        if (m >= M) continue;
#pragma unroll
        for (int j = 0; j < 4; j++) {
            int n = n0 + tn * 4 + j;
            if (n >= N) continue;
            float v = acc[i][j];
            if (EPI == 1) v = softplusf(v + bias[n]);
            C[(long)m * ldc + n] = v;
        }
    }
}

// ---------- split-K fp32 GEMM (row-major A,B): Cpart[z] = partial ----------
__global__ __launch_bounds__(256) void gemm64_sk(
    const float* __restrict__ A, const float* __restrict__ Bw, float* __restrict__ Cpart,
    int M, int N, int K, int lda, int ldb, int kch)
{
    __shared__ __align__(16) float As[16][64];
    __shared__ __align__(16) float Bs[16][64];
    int tx = threadIdx.x;
    int m0 = blockIdx.x * 64, n0 = blockIdx.y * 64;
    int kbeg = blockIdx.z * kch;
    int kend = min(kbeg + kch, K);
    Cpart += (long)blockIdx.z * M * N;
    int tm = tx >> 4, tn = tx & 15;
    float acc[4][4] = {};
    for (int k0 = kbeg; k0 < kend; k0 += 16) {
        for (int i = tx; i < 1024; i += 256) {
            int kk = i & 15, mm = i >> 4;
            int m = m0 + mm, k = k0 + kk;
            As[kk][mm] = (m < M && k < kend) ? A[(long)m * lda + k] : 0.f;
        }
        for (int i = tx; i < 1024; i += 256) {
            int nn = i & 63, kk = i >> 6;
            int n = n0 + nn, k = k0 + kk;
            Bs[kk][nn] = (n < N && k < kend) ? Bw[(long)k * ldb + n] : 0.f;
        }
        __syncthreads();
#pragma unroll
        for (int kk = 0; kk < 16; ++kk) {
            float4 av = *(const float4*)&As[kk][tm * 4];
            float4 bv = *(const float4*)&Bs[kk][tn * 4];
            float a[4] = {av.x, av.y, av.z, av.w};
            float b[4] = {bv.x, bv.y, bv.z, bv.w};
#pragma unroll
            for (int i = 0; i < 4; i++)
#pragma unroll
                for (int j = 0; j < 4; j++) acc[i][j] += a[i] * b[j];
        }
        __syncthreads();
    }
#pragma unroll
    for (int i = 0; i < 4; i++) {
        int m = m0 + tm * 4 + i;
        if (m >= M) continue;
#pragma unroll
        for (int j = 0; j < 4; j++) {
            int n = n0 + tn * 4 + j;
            if (n >= N) continue;
            Cpart[(long)m * N + n] = acc[i][j];
        }
    }
}

// ---------- batched split-K fp32 GEMM with layout templates ----------
// blockIdx.z = batch * KZ + kz. Partials: Cpart + kz*partStride + batch*batC.
template<bool ACOL, bool BCOL>
__global__ __launch_bounds__(256) void gemm64_skb(
    const float* __restrict__ A, const float* __restrict__ Bw, float* __restrict__ Cpart,
    int M, int N, int K, int lda, int ldb, int kch, int KZ,
    long batA, long batB, long batC, long partStride)
{
    __shared__ __align__(16) float As[16][64];
    __shared__ __align__(16) float Bs[16][64];
    int tx = threadIdx.x;
    int m0 = blockIdx.x * 64, n0 = blockIdx.y * 64;
    int bz = blockIdx.z / KZ, kz = blockIdx.z - bz * KZ;
    A += (long)bz * batA; Bw += (long)bz * batB;
    Cpart += (long)kz * partStride + (long)bz * batC;
    int kbeg = kz * kch;
    int kend = min(kbeg + kch, K);
    int tm = tx >> 4, tn = tx & 15;
    float acc[4][4] = {};
    for (int k0 = kbeg; k0 < kend; k0 += 16) {
        for (int i = tx; i < 1024; i += 256) {
            int mm, kk;
            if (ACOL) { mm = i & 63; kk = i >> 6; } else { kk = i & 15; mm = i >> 4; }
            int m = m0 + mm, k = k0 + kk;
            float v = 0.f;
            if (m < M && k < kend) {
                long ia = ACOL ? ((long)k * lda + m) : ((long)m * lda + k);
                v = A[ia];
            }
            As[kk][mm] = v;
        }
        for (int i = tx; i < 1024; i += 256) {
            int nn, kk;
            if (BCOL) { kk = i & 15; nn = i >> 4; } else { nn = i & 63; kk = i >> 6; }
            int n = n0 + nn, k = k0 + kk;
            float v = 0.f;
            if (n < N && k < kend) {
                long ib = BCOL ? ((long)n * ldb + k) : ((long)k * ldb + n);
                v = Bw[ib];
            }
            Bs[kk][nn] = v;
        }
        __syncthreads();
#pragma unroll
        for (int kk = 0; kk < 16; ++kk) {
            float4 av = *(const float4*)&As[kk][tm * 4];
            float4 bv = *(const float4*)&Bs[kk][tn * 4];
            float a[4] = {av.x, av.y, av.z, av.w};
            float b[4] = {bv.x, bv.y, bv.z, bv.w};
#pragma unroll
            for (int i = 0; i < 4; i++)
#pragma unroll
                for (int j = 0; j < 4; j++) acc[i][j] += a[i] * b[j];
        }
        __syncthreads();
    }
#pragma unroll
    for (int i = 0; i < 4; i++) {
        int m = m0 + tm * 4 + i;
        if (m >= M) continue;
#pragma unroll
        for (int j = 0; j < 4; j++) {
            int n = n0 + tn * 4 + j;
            if (n >= N) continue;
            Cpart[(long)m * N + n] = acc[i][j];
        }
    }
}

// ---------- sum nz split-K partial buffers ----------
__global__ void sk_reduce(const float* __restrict__ Cpart, float* __restrict__ C,
                          long len, int nz)
{
    long i = (long)blockIdx.x * 256 + threadIdx.x;
    if (i >= len) return;
    float s = 0.f;
    for (int z = 0; z < nz; z++) s += Cpart[(long)z * len + i];
    C[i] = s;
}

// ---------- bf16 MFMA GEMM: C[M,N] = A[M,K] x B[K,N] ----------
// Abf: bf16 bits, row-major [Mpad][K] (Mpad >= gridDim.x*128)
// Bbf: bf16 bits, B TRANSPOSED layout [N][K]
// 128x128 tile, 4 waves (2x2 of 64x64), 16x16x32 MFMA, BK=32.
__global__ __launch_bounds__(256) void mfma_gemm(
    const unsigned short* __restrict__ Abf, const unsigned short* __restrict__ Bbf,
    float* __restrict__ C, int M, int N, int K, int ldc)
{
    __shared__ __align__(16) short As[128 * 40];   // +8 pad kills ds_read conflicts
    __shared__ __align__(16) short Bs[128 * 40];
    int tid = threadIdx.x;
    int m0 = blockIdx.x * 128, n0 = blockIdx.y * 128;
    int w = tid >> 6, l = tid & 63;
    int wm = (w >> 1) * 64, wn = (w & 1) * 64;
    int lr = l & 15, lq = l >> 4;
    int row0 = tid >> 2, kc = (tid & 3) * 8;
    floatx4 acc[4][4];
#pragma unroll
    for (int i = 0; i < 4; i++)
#pragma unroll
        for (int j = 0; j < 4; j++) acc[i][j] = (floatx4){0.f, 0.f, 0.f, 0.f};
    const unsigned short* Ap  = Abf + (long)(m0 + row0) * K + kc;
    const unsigned short* Ap2 = Abf + (long)(m0 + row0 + 64) * K + kc;
    const unsigned short* Bp  = Bbf + (long)(n0 + row0) * K + kc;
    const unsigned short* Bp2 = Bbf + (long)(n0 + row0 + 64) * K + kc;
    for (int k0 = 0; k0 < K; k0 += 32) {
        uint4 a0 = *(const uint4*)(Ap + k0);
        uint4 a1 = *(const uint4*)(Ap2 + k0);
        uint4 b0 = *(const uint4*)(Bp + k0);
        uint4 b1 = *(const uint4*)(Bp2 + k0);
        __syncthreads();
        *(uint4*)&As[row0 * 40 + kc] = a0;
        *(uint4*)&As[(row0 + 64) * 40 + kc] = a1;
        *(uint4*)&Bs[row0 * 40 + kc] = b0;
        *(uint4*)&Bs[(row0 + 64) * 40 + kc] = b1;
        __syncthreads();
        short8 af[4], bfr[4];
#pragma unroll
        for (int i = 0; i < 4; i++) af[i]  = *(const short8*)&As[(wm + i * 16 + lr) * 40 + lq * 8];
#pragma unroll
        for (int i = 0; i < 4; i++) bfr[i] = *(const short8*)&Bs[(wn + i * 16 + lr) * 40 + lq * 8];
#pragma unroll
        for (int i = 0; i < 4; i++)
#pragma unroll
            for (int j = 0; j < 4; j++)
                acc[i][j] = __builtin_amdgcn_mfma_f32_16x16x32_bf16(af[i], bfr[j], acc[i][j], 0, 0, 0);
    }
#pragma unroll
    for (int i = 0; i < 4; i++) {
#pragma unroll
        for (int r = 0; r < 4; r++) {
            int m = m0 + wm + i * 16 + lq * 4 + r;
            if (m >= M) continue;
#pragma unroll
            for (int j = 0; j < 4; j++)
                C[(long)m * ldc + n0 + wn + j * 16 + lr] = acc[i][j][r];
        }
    }
}

// ---------- fp32 [K][N] -> bf16-bits transposed [N][K] (tiled via LDS) ----------
__global__ __launch_bounds__(256) void tpose_cvt(const float* __restrict__ src,
                                                 unsigned short* __restrict__ dst,
                                                 int K, int N)
{
    __shared__ float t[32][33];
    int n0 = blockIdx.x * 32, k0 = blockIdx.y * 32;
    int tid = threadIdx.x;
    int r = tid >> 3, c4 = (tid & 7) * 4;
    float4 v = *(const float4*)&src[(long)(k0 + r) * N + n0 + c4];
    t[r][c4] = v.x; t[r][c4 + 1] = v.y; t[r][c4 + 2] = v.z; t[r][c4 + 3] = v.w;
    __syncthreads();
    ushort4 o;
    o.x = f2b(t[c4][r]);
    o.y = f2b(t[c4 + 1][r]);
    o.z = f2b(t[c4 + 2][r]);
    o.w = f2b(t[c4 + 3][r]);
    *(ushort4*)&dst[(long)(n0 + r) * K + k0 + c4] = o;
}

// ---------- fp32 [M][C] -> bf16-bits [Mpad][C] (zero pad rows >= M) ----------
__global__ void cvt_pad(const float* __restrict__ src, unsigned short* __restrict__ dst,
                        int M, int Mpad, int C)
{
    long i4 = ((long)blockIdx.x * 256 + threadIdx.x) * 4;
    if (i4 >= (long)Mpad * C) return;
    int row = (int)(i4 / C);
    ushort4 o = {0, 0, 0, 0};
    if (row < M) {
        float4 v = *(const float4*)&src[i4];
        o.x = f2b(v.x); o.y = f2b(v.y); o.z = f2b(v.z); o.w = f2b(v.w);
    }
    *(ushort4*)&dst[i4] = o;
}

// ---------- y * silu(z) -> bf16-bits [Mpad][C] ----------
__global__ void gate_cvt(const float* __restrict__ y, const float* __restrict__ z,
                         unsigned short* __restrict__ dst, int M, int Mpad, int C, int ldz)
{
    long i4 = ((long)blockIdx.x * 256 + threadIdx.x) * 4;
    if (i4 >= (long)Mpad * C) return;
    int row = (int)(i4 / C);
    int col = (int)(i4 - (long)row * C);
    ushort4 o = {0, 0, 0, 0};
    if (row < M) {
        float4 yv = *(const float4*)&y[i4];
        float4 zv = *(const float4*)&z[(long)row * ldz + col];
        o.x = f2b(yv.x * siluf(zv.x));
        o.y = f2b(yv.y * siluf(zv.y));
        o.z = f2b(yv.z * siluf(zv.z));
        o.w = f2b(yv.w * siluf(zv.w));
    }
    *(ushort4*)&dst[i4] = o;
}

// ---------- causal depthwise conv (k=4) + bias + silu ----------
__global__ void conv_silu_kernel(const float* __restrict__ xz, const float* __restrict__ w,
                                 const float* __restrict__ bias, float* __restrict__ out,
                                 int Bn, int L, int din, int ldx)
{
    int idx = blockIdx.x * 256 + threadIdx.x;
    int total = Bn * L * din;
    if (idx >= total) return;
    int c = idx % din;
    int r = idx / din;
    int t = r % L;
    int b = r / L;
    float acc = bias[c];
#pragma unroll
    for (int i = 0; i < 4; i++) {
        int tt = t - 3 + i;
        if (tt >= 0) acc += w[c * 4 + i] * xz[((long)(b * L + tt)) * ldx + c];
    }
    out[idx] = siluf(acc);
}

// ---------- selective scan (u/y may alias) ----------
template<int T>
__global__ __launch_bounds__(256) void scan_kernel(
    const float* u, const float* dt,
    const float* xdbl, const float* __restrict__ A_log,
    const float* __restrict__ Dp, float* y,
    int din, int L, int xld, int boff, int coff)
{
    __shared__ float Bc[T][16], Cc[T][16], dtc[T][16], uc[T][16], yc[T][16];
    int tx = threadIdx.x;
    int dl = tx >> 4;
    int n = tx & 15;
    int dbase = blockIdx.x * 16;
    int dg = dbase + dl;
    int b = blockIdx.y;
    bool act = dg < din;
    float Acoef = act ? -__expf(A_log[dg * 16 + n]) : 0.f;
    float Dv = act ? Dp[dg] : 0.f;
    int nvalid = min(16, din - dbase);
    float h = 0.f;
    for (int c0 = 0; c0 < L; c0 += T) {
        int tcnt = min(T, L - c0);
        for (int i = tx; i < T * 16; i += 256) {
            int tt = i >> 4, c = i & 15;
            if (tt < tcnt) {
                long row = (long)b * L + c0 + tt;
                float uv = 0.f, dv = 0.f;
                if (c < nvalid) { uv = u[row * din + dbase + c]; dv = dt[row * din + dbase + c]; }
                uc[tt][c] = uv; dtc[tt][c] = dv;
                Bc[tt][c] = xdbl[row * xld + boff + c];
                Cc[tt][c] = xdbl[row * xld + coff + c];
            }
        }
        __syncthreads();
        for (int tt = 0; tt < tcnt; ++tt) {
            float dtv = dtc[tt][dl];
            float uv = uc[tt][dl];
            float dA = __expf(dtv * Acoef);
            h = dA * h + (dtv * uv) * Bc[tt][n];
            float p = h * Cc[tt][n];
            p += __shfl_xor(p, 1);
            p += __shfl_xor(p, 2);
            p += __shfl_xor(p, 4);
            p += __shfl_xor(p, 8);
            if (n == 0) yc[tt][dl] = p + Dv * uv;
        }
        __syncthreads();
        for (int i = tx; i < tcnt * 16; i += 256) {
            int tt = i >> 4, c = i & 15;
            if (c < nvalid) y[((long)b * L + c0 + tt) * din + dbase + c] = yc[tt][c];
        }
        __syncthreads();
    }
}

// ---------- mean over n (98) + softmax over k (1024), per batch ----------
// coalesced: stage 32 rows (32x98 contiguous floats) in LDS per pass
__global__ __launch_bounds__(256) void mean_softmax_kernel(const float* __restrict__ sc2,
                                                           float* __restrict__ s)
{
    __shared__ float tile[32 * 98];
    __shared__ float vals[1024];
    __shared__ float red[256];
    int b = blockIdx.x, tx = threadIdx.x;
    for (int k0 = 0; k0 < 1024; k0 += 32) {
        const float* base = sc2 + ((long)b * 1024 + k0) * 98;
        for (int i = tx; i < 32 * 98; i += 256) tile[i] = base[i];
        __syncthreads();
        int row = tx >> 3, ln = tx & 7;
        float sum = 0.f;
        for (int nn = ln; nn < 98; nn += 8) sum += tile[row * 98 + nn];
        sum += __shfl_xor(sum, 1);
        sum += __shfl_xor(sum, 2);
        sum += __shfl_xor(sum, 4);
        if (ln == 0) vals[k0 + row] = sum * (1.f / 98.f);
        __syncthreads();
    }
    float mx = -1e30f;
    for (int k = tx; k < 1024; k += 256) mx = fmaxf(mx, vals[k]);
    red[tx] = mx; __syncthreads();
    for (int st = 128; st > 0; st >>= 1) { if (tx < st) red[tx] = fmaxf(red[tx], red[tx + st]); __syncthreads(); }
    mx = red[0]; __syncthreads();
    float lsum = 0.f;
    for (int k = tx; k < 1024; k += 256) { float e = __expf(vals[k] - mx); vals[k] = e; lsum += e; }
    red[tx] = lsum; __syncthreads();
    for (int st = 128; st > 0; st >>= 1) { if (tx < st) red[tx] += red[tx + st]; __syncthreads(); }
    float inv = 1.f / red[0];
    __syncthreads();
    for (int k = tx; k < 1024; k += 256) s[(long)b * 1024 + k] = vals[k] * inv;
}

// ---------- top-98 sequential selection (jax tie semantics) ----------
__global__ __launch_bounds__(256) void topk_select_kernel(const float* __restrict__ s,
                                                          int* __restrict__ ind,
                                                          float* __restrict__ vtopk)
{
    __shared__ unsigned long long arr[1024];
    __shared__ unsigned long long red[256];
    int b = blockIdx.x, tx = threadIdx.x;
    for (int k = tx; k < 1024; k += 256) {
        float v = s[b * 1024 + k];
        unsigned u = __float_as_uint(v);
        u = (u & 0x80000000u) ? ~u : (u | 0x80000000u);
        arr[k] = ((unsigned long long)u << 32) | (unsigned)(~k);
    }
    __syncthreads();
    for (int r = 0; r < 98; ++r) {
        unsigned long long m = 0ull;
        for (int k = tx; k < 1024; k += 256) m = (arr[k] > m) ? arr[k] : m;
        red[tx] = m; __syncthreads();
        for (int st = 128; st > 0; st >>= 1) {
            if (tx < st && red[tx + st] > red[tx]) red[tx] = red[tx + st];
            __syncthreads();
        }
        unsigned long long best = red[0];
        if (tx == 0) {
            unsigned lo = (unsigned)(best & 0xffffffffu);
            int kidx = (int)(~lo);
            unsigned ub = (unsigned)(best >> 32);
            unsigned fb = (ub & 0x80000000u) ? (ub ^ 0x80000000u) : ~ub;
            ind[b * 98 + r] = kidx;
            vtopk[b * 98 + r] = __uint_as_float(fb);
            arr[kidx] = 0ull;
        }
        __syncthreads();
    }
}

// ---------- gather: h[b,j,:] = img[j,:] + kf[b,:,ind]*v ----------
__global__ void gather_kernel(const float* __restrict__ img, const float* __restrict__ kf,
                              const int* __restrict__ ind, const float* __restrict__ vtopk,
                              float* __restrict__ h)
{
    int j = blockIdx.x, b = blockIdx.y;
    int kidx = ind[b * 98 + j];
    float v = vtopk[b * 98 + j];
    long hbase = ((long)b * 98 + j) * 2048;
    const float* kfb = kf + (long)b * 2048 * 1024 + kidx;
    for (int d = threadIdx.x; d < 2048; d += 256)
        h[hbase + d] = img[(long)j * 2048 + d] + kfb[(long)d * 1024] * v;
}

// ---------- host launch ----------
extern "C" void kernel_launch(void* const* d_in, const int* in_sizes, int n_in,
                              void* d_out, int out_size, void* d_ws, size_t ws_size,
                              hipStream_t stream)
{
    const float* imgF      = (const float*)d_in[0];
    const float* kf        = (const float*)d_in[1];
    const float* a_in_w    = (const float*)d_in[2];
    const float* a_conv_w  = (const float*)d_in[3];
    const float* a_conv_b  = (const float*)d_in[4];
    const float* a_xproj_w = (const float*)d_in[5];
    const float* a_dt_w    = (const float*)d_in[6];
    const float* a_dt_b    = (const float*)d_in[7];
    const float* a_A_log   = (const float*)d_in[8];
    const float* a_D       = (const float*)d_in[9];
    const float* a_out_w   = (const float*)d_in[10];
    const float* c_in_w    = (const float*)d_in[11];
    const float* c_conv_w  = (const float*)d_in[12];
    const float* c_conv_b  = (const float*)d_in[13];
    const float* c_xproj_w = (const float*)d_in[14];
    const float* c_dt_w    = (const float*)d_in[15];
    const float* c_dt_b    = (const float*)d_in[16];
    const float* c_A_log   = (const float*)d_in[17];
    const float* c_D       = (const float*)d_in[18];
    const float* c_out_w   = (const float*)d_in[19];

    float* fout = (float*)d_out;

    float* ws = (float*)d_ws;
    float* h_buf  = ws;                      // 1,605,632 floats
    float* S      = ws + 1605632;
    // stage A
    float* score  = S;                       // 802,816 (reused as score2)
    float* xz_a   = S + 802816;              // 3,211,264
    float* xi_a   = S + 4014080;             // 1,605,632 (scan in-place)
    float* xdbl_a = S + 5619712;             // 319,488
    float* dt_a   = S + 5939200;             // 1,605,632
    float* sbuf   = S + 7544832;             // 8,192
    int*   indb   = (int*)(S + 7553024);     // 784
    float* vtopk  = S + 7553808;             // 784
    // stage C (aliases stage A region)
    float* xz_c   = S;                       // 6,422,528
    float* xi_c   = S + 6422528;             // 3,211,264 (scan in-place)
    float* xdbl_c = S + 9633792;             // 125,440
    float* dt_c   = S + 9759232;             // 3,211,264
    // bf16 scratch (beyond the fp32 region: base float offset 14,576,128)
    unsigned short* cwbf  = (unsigned short*)(ws + 14576128);          // 16,777,216 bf16
    unsigned short* h_bf  = (unsigned short*)(ws + 14576128 + 8388608);// 1,835,008 bf16
    unsigned short* yz_bf = (unsigned short*)(ws + 14576128 + 9306112);// 3,670,016 bf16
    // split-K partials:
    //  - step 1 (stage A): bf16 region is dead until step 11 -> reuse it.
    //    8 chunks x 802,816 = 6,422,528 floats at 14,576,128..20,998,656.
    float* CpartS1 = ws + 14576128;
    //  - step 13 (stage C): upper half of cwbf region is dead between
    //    mfma_gemm #11 and tpose_cvt #16. 16 x 784 x 160 floats.
    float* Cpart  = ws + 18770432;
    // total ws: 25,717,248 floats ~= 103 MB

    // ===== stage A (fp32) =====
    // 1. score[b] = kf[b]^T @ imgF^T : split-K x8 (2048 blocks vs 256)
    gemm64_skb<true, true><<<dim3(16, 2, 64), 256, 0, stream>>>(
        kf, imgF, CpartS1,
        1024, 98, 2048, 1024, 2048, 256, 8,
        (long)2048 * 1024, 0L, (long)1024 * 98, 802816L);
    sk_reduce<<<3136, 256, 0, stream>>>(CpartS1, score, 802816L, 8);

    gemm64<false, false, false, 0><<<dim3(128, 7, 1), 256, 0, stream>>>(
        score, a_in_w, xz_a, nullptr, nullptr, 8192, 392, 98, 98, 392, 392, 0, 0L, 0L, 0L);
    conv_silu_kernel<<<6272, 256, 0, stream>>>(xz_a, a_conv_w, a_conv_b, xi_a, 8, 1024, 196, 392);
    gemm64<false, false, false, 0><<<dim3(128, 1, 1), 256, 0, stream>>>(
        xi_a, a_xproj_w, xdbl_a, nullptr, nullptr, 8192, 39, 196, 196, 39, 39, 0, 0L, 0L, 0L);
    gemm64<false, false, false, 1><<<dim3(128, 4, 1), 256, 0, stream>>>(
        xdbl_a, a_dt_w, dt_a, nullptr, a_dt_b, 8192, 196, 7, 39, 196, 196, 0, 0L, 0L, 0L);
    scan_kernel<64><<<dim3(13, 8, 1), 256, 0, stream>>>(
        xi_a, dt_a, xdbl_a, a_A_log, a_D, xi_a, 196, 1024, 39, 7, 23);
    gemm64<false, false, true, 0><<<dim3(128, 2, 1), 256, 0, stream>>>(
        xi_a, a_out_w, score, xz_a + 196, nullptr, 8192, 98, 196, 196, 98, 98, 392, 0L, 0L, 0L);
    mean_softmax_kernel<<<8, 256, 0, stream>>>(score, sbuf);
    topk_select_kernel<<<8, 256, 0, stream>>>(sbuf, indb, vtopk);
    gather_kernel<<<dim3(98, 8, 1), 256, 0, stream>>>(imgF, kf, indb, vtopk, h_buf);

    // ===== stage C =====
    // 11. xz_c = h @ c_in_w  (bf16 MFMA)
    tpose_cvt<<<dim3(256, 64, 1), 256, 0, stream>>>(c_in_w, cwbf, 2048, 8192);
    cvt_pad<<<1792, 256, 0, stream>>>(h_buf, h_bf, 784, 896, 2048);
    mfma_gemm<<<dim3(7, 64, 1), 256, 0, stream>>>(h_bf, cwbf, xz_c, 784, 8192, 2048, 8192);

    // 12. conv + silu -> xi_c
    conv_silu_kernel<<<12544, 256, 0, stream>>>(xz_c, c_conv_w, c_conv_b, xi_c, 8, 98, 4096, 8192);

    // 13. xdbl_c = xi_c @ c_xproj_w (fp32, split-K x16)
    gemm64_sk<<<dim3(13, 3, 16), 256, 0, stream>>>(
        xi_c, c_xproj_w, Cpart, 784, 160, 4096, 4096, 160, 256);
    sk_reduce<<<490, 256, 0, stream>>>(Cpart, xdbl_c, 125440L, 16);

    // 14. dt_c = softplus(xdbl_c[:, :128] @ c_dt_w + c_dt_b) (fp32)
    gemm64<false, false, false, 1><<<dim3(13, 64, 1), 256, 0, stream>>>(
        xdbl_c, c_dt_w, dt_c, nullptr, c_dt_b, 784, 4096, 128, 160, 4096, 4096, 0, 0L, 0L, 0L);

    // 15. selective scan C (in-place)
    scan_kernel<98><<<dim3(256, 8, 1), 256, 0, stream>>>(
        xi_c, dt_c, xdbl_c, c_A_log, c_D, xi_c, 4096, 98, 160, 128, 144);

    // 16. out = (y_c * silu(z_c)) @ c_out_w  (bf16 MFMA, direct to d_out)
    gate_cvt<<<3584, 256, 0, stream>>>(xi_c, xz_c + 4096, yz_bf, 784, 896, 4096, 8192);
    tpose_cvt<<<dim3(64, 128, 1), 256, 0, stream>>>(c_out_w, cwbf, 4096, 2048);
    mfma_gemm<<<dim3(7, 16, 1), 256, 0, stream>>>(yz_bf, cwbf, fout, 784, 2048, 4096, 2048);
}

// Round 5
// 1292.870 us; speedup vs baseline: 1.6071x; 1.0300x over previous
//
#include <hip/hip_runtime.h>
#include <hip/hip_bf16.h>
#include <math.h>

typedef __attribute__((ext_vector_type(8))) short short8;
typedef __attribute__((ext_vector_type(4))) float floatx4;

// ---------- helpers ----------
__device__ __forceinline__ float siluf(float x) {
    float e = __expf(-fabsf(x));
    float s = (x >= 0.f) ? 1.f / (1.f + e) : e / (1.f + e);
    return x * s;
}
__device__ __forceinline__ float softplusf(float x) {
    if (x > 20.f) return x;
    if (x < -20.f) return __expf(x);
    return log1pf(__expf(x));
}
__device__ __forceinline__ unsigned short f2b(float v) {
    __hip_bfloat16 b = __float2bfloat16(v);
    unsigned short u;
    __builtin_memcpy(&u, &b, 2);
    return u;
}

// ---------- generic 64x64 tiled GEMM (fp32) — stage A + small stage-C ----------
template<bool ACOL, bool BCOL, bool AMUL, int EPI>
__global__ __launch_bounds__(256) void gemm64(
    const float* __restrict__ A, const float* __restrict__ Bw, float* __restrict__ C,
    const float* __restrict__ A2, const float* __restrict__ bias,
    int M, int N, int K, int lda, int ldb, int ldc, int lda2,
    long batA, long batB, long batC)
{
    __shared__ __align__(16) float As[16][64];
    __shared__ __align__(16) float Bs[16][64];
    int tx = threadIdx.x;
    int m0 = blockIdx.x * 64, n0 = blockIdx.y * 64;
    A += blockIdx.z * batA; Bw += blockIdx.z * batB; C += blockIdx.z * batC;
    int tm = tx >> 4, tn = tx & 15;
    float acc[4][4] = {};
    for (int k0 = 0; k0 < K; k0 += 16) {
        for (int i = tx; i < 1024; i += 256) {
            int mm, kk;
            if (ACOL) { mm = i & 63; kk = i >> 6; } else { kk = i & 15; mm = i >> 4; }
            int m = m0 + mm, k = k0 + kk;
            float v = 0.f;
            if (m < M && k < K) {
                long ia = ACOL ? ((long)k * lda + m) : ((long)m * lda + k);
                v = A[ia];
                if (AMUL) v *= siluf(A2[(long)m * lda2 + k]);
            }
            As[kk][mm] = v;
        }
        for (int i = tx; i < 1024; i += 256) {
            int nn, kk;
            if (BCOL) { kk = i & 15; nn = i >> 4; } else { nn = i & 63; kk = i >> 6; }
            int n = n0 + nn, k = k0 + kk;
            float v = 0.f;
            if (n < N && k < K) {
                long ib = BCOL ? ((long)n * ldb + k) : ((long)k * ldb + n);
                v = Bw[ib];
            }
            Bs[kk][nn] = v;
        }
        __syncthreads();
#pragma unroll
        for (int kk = 0; kk < 16; ++kk) {
            float4 av = *(const float4*)&As[kk][tm * 4];
            float4 bv = *(const float4*)&Bs[kk][tn * 4];
            float a[4] = {av.x, av.y, av.z, av.w};
            float b[4] = {bv.x, bv.y, bv.z, bv.w};
#pragma unroll
            for (int i = 0; i < 4; i++)
#pragma unroll
                for (int j = 0; j < 4; j++) acc[i][j] += a[i] * b[j];
        }
        __syncthreads();
    }
#pragma unroll
    for (int i = 0; i < 4; i++) {
        int m = m0 + tm * 4 + i;
        if (m >= M) continue;
#pragma unroll
        for (int j = 0; j < 4; j++) {
            int n = n0 + tn * 4 + j;
            if (n >= N) continue;
            float v = acc[i][j];
            if (EPI == 1) v = softplusf(v + bias[n]);
            C[(long)m * ldc + n] = v;
        }
    }
}

// ---------- split-K fp32 GEMM (row-major A,B): Cpart[z] = partial ----------
__global__ __launch_bounds__(256) void gemm64_sk(
    const float* __restrict__ A, const float* __restrict__ Bw, float* __restrict__ Cpart,
    int M, int N, int K, int lda, int ldb, int kch)
{
    __shared__ __align__(16) float As[16][64];
    __shared__ __align__(16) float Bs[16][64];
    int tx = threadIdx.x;
    int m0 = blockIdx.x * 64, n0 = blockIdx.y * 64;
    int kbeg = blockIdx.z * kch;
    int kend = min(kbeg + kch, K);
    Cpart += (long)blockIdx.z * M * N;
    int tm = tx >> 4, tn = tx & 15;
    float acc[4][4] = {};
    for (int k0 = kbeg; k0 < kend; k0 += 16) {
        for (int i = tx; i < 1024; i += 256) {
            int kk = i & 15, mm = i >> 4;
            int m = m0 + mm, k = k0 + kk;
            As[kk][mm] = (m < M && k < kend) ? A[(long)m * lda + k] : 0.f;
        }
        for (int i = tx; i < 1024; i += 256) {
            int nn = i & 63, kk = i >> 6;
            int n = n0 + nn, k = k0 + kk;
            Bs[kk][nn] = (n < N && k < kend) ? Bw[(long)k * ldb + n] : 0.f;
        }
        __syncthreads();
#pragma unroll
        for (int kk = 0; kk < 16; ++kk) {
            float4 av = *(const float4*)&As[kk][tm * 4];
            float4 bv = *(const float4*)&Bs[kk][tn * 4];
            float a[4] = {av.x, av.y, av.z, av.w};
            float b[4] = {bv.x, bv.y, bv.z, bv.w};
#pragma unroll
            for (int i = 0; i < 4; i++)
#pragma unroll
                for (int j = 0; j < 4; j++) acc[i][j] += a[i] * b[j];
        }
        __syncthreads();
    }
#pragma unroll
    for (int i = 0; i < 4; i++) {
        int m = m0 + tm * 4 + i;
        if (m >= M) continue;
#pragma unroll
        for (int j = 0; j < 4; j++) {
            int n = n0 + tn * 4 + j;
            if (n >= N) continue;
            Cpart[(long)m * N + n] = acc[i][j];
        }
    }
}

// ---------- batched split-K fp32 GEMM with layout templates ----------
// blockIdx.z = batch * KZ + kz. Partials: Cpart + kz*partStride + batch*batC.
template<bool ACOL, bool BCOL>
__global__ __launch_bounds__(256) void gemm64_skb(
    const float* __restrict__ A, const float* __restrict__ Bw, float* __restrict__ Cpart,
    int M, int N, int K, int lda, int ldb, int kch, int KZ,
    long batA, long batB, long batC, long partStride)
{
    __shared__ __align__(16) float As[16][64];
    __shared__ __align__(16) float Bs[16][64];
    int tx = threadIdx.x;
    int m0 = blockIdx.x * 64, n0 = blockIdx.y * 64;
    int bz = blockIdx.z / KZ, kz = blockIdx.z - bz * KZ;
    A += (long)bz * batA; Bw += (long)bz * batB;
    Cpart += (long)kz * partStride + (long)bz * batC;
    int kbeg = kz * kch;
    int kend = min(kbeg + kch, K);
    int tm = tx >> 4, tn = tx & 15;
    float acc[4][4] = {};
    for (int k0 = kbeg; k0 < kend; k0 += 16) {
        for (int i = tx; i < 1024; i += 256) {
            int mm, kk;
            if (ACOL) { mm = i & 63; kk = i >> 6; } else { kk = i & 15; mm = i >> 4; }
            int m = m0 + mm, k = k0 + kk;
            float v = 0.f;
            if (m < M && k < kend) {
                long ia = ACOL ? ((long)k * lda + m) : ((long)m * lda + k);
                v = A[ia];
            }
            As[kk][mm] = v;
        }
        for (int i = tx; i < 1024; i += 256) {
            int nn, kk;
            if (BCOL) { kk = i & 15; nn = i >> 4; } else { nn = i & 63; kk = i >> 6; }
            int n = n0 + nn, k = k0 + kk;
            float v = 0.f;
            if (n < N && k < kend) {
                long ib = BCOL ? ((long)n * ldb + k) : ((long)k * ldb + n);
                v = Bw[ib];
            }
            Bs[kk][nn] = v;
        }
        __syncthreads();
#pragma unroll
        for (int kk = 0; kk < 16; ++kk) {
            float4 av = *(const float4*)&As[kk][tm * 4];
            float4 bv = *(const float4*)&Bs[kk][tn * 4];
            float a[4] = {av.x, av.y, av.z, av.w};
            float b[4] = {bv.x, bv.y, bv.z, bv.w};
#pragma unroll
            for (int i = 0; i < 4; i++)
#pragma unroll
                for (int j = 0; j < 4; j++) acc[i][j] += a[i] * b[j];
        }
        __syncthreads();
    }
#pragma unroll
    for (int i = 0; i < 4; i++) {
        int m = m0 + tm * 4 + i;
        if (m >= M) continue;
#pragma unroll
        for (int j = 0; j < 4; j++) {
            int n = n0 + tn * 4 + j;
            if (n >= N) continue;
            Cpart[(long)m * N + n] = acc[i][j];
        }
    }
}

// ---------- sum nz split-K partial buffers ----------
__global__ void sk_reduce(const float* __restrict__ Cpart, float* __restrict__ C,
                          long len, int nz)
{
    long i = (long)blockIdx.x * 256 + threadIdx.x;
    if (i >= len) return;
    float s = 0.f;
    for (int z = 0; z < nz; z++) s += Cpart[(long)z * len + i];
    C[i] = s;
}

// ---------- bf16 MFMA GEMM: C[M,N] = A[M,K] x B[K,N] ----------
// Abf: bf16 bits, row-major [Mpad][K] (Mpad >= gridDim.x*128)
// Bbf: bf16 bits, B TRANSPOSED layout [N][K]
// 128x128 tile, 4 waves (2x2 of 64x64), 16x16x32 MFMA, BK=32.
__global__ __launch_bounds__(256) void mfma_gemm(
    const unsigned short* __restrict__ Abf, const unsigned short* __restrict__ Bbf,
    float* __restrict__ C, int M, int N, int K, int ldc)
{
    __shared__ __align__(16) short As[128 * 40];   // +8 pad kills ds_read conflicts
    __shared__ __align__(16) short Bs[128 * 40];
    int tid = threadIdx.x;
    int m0 = blockIdx.x * 128, n0 = blockIdx.y * 128;
    int w = tid >> 6, l = tid & 63;
    int wm = (w >> 1) * 64, wn = (w & 1) * 64;
    int lr = l & 15, lq = l >> 4;
    int row0 = tid >> 2, kc = (tid & 3) * 8;
    floatx4 acc[4][4];
#pragma unroll
    for (int i = 0; i < 4; i++)
#pragma unroll
        for (int j = 0; j < 4; j++) acc[i][j] = (floatx4){0.f, 0.f, 0.f, 0.f};
    const unsigned short* Ap  = Abf + (long)(m0 + row0) * K + kc;
    const unsigned short* Ap2 = Abf + (long)(m0 + row0 + 64) * K + kc;
    const unsigned short* Bp  = Bbf + (long)(n0 + row0) * K + kc;
    const unsigned short* Bp2 = Bbf + (long)(n0 + row0 + 64) * K + kc;
    for (int k0 = 0; k0 < K; k0 += 32) {
        uint4 a0 = *(const uint4*)(Ap + k0);
        uint4 a1 = *(const uint4*)(Ap2 + k0);
        uint4 b0 = *(const uint4*)(Bp + k0);
        uint4 b1 = *(const uint4*)(Bp2 + k0);
        __syncthreads();
        *(uint4*)&As[row0 * 40 + kc] = a0;
        *(uint4*)&As[(row0 + 64) * 40 + kc] = a1;
        *(uint4*)&Bs[row0 * 40 + kc] = b0;
        *(uint4*)&Bs[(row0 + 64) * 40 + kc] = b1;
        __syncthreads();
        short8 af[4], bfr[4];
#pragma unroll
        for (int i = 0; i < 4; i++) af[i]  = *(const short8*)&As[(wm + i * 16 + lr) * 40 + lq * 8];
#pragma unroll
        for (int i = 0; i < 4; i++) bfr[i] = *(const short8*)&Bs[(wn + i * 16 + lr) * 40 + lq * 8];
#pragma unroll
        for (int i = 0; i < 4; i++)
#pragma unroll
            for (int j = 0; j < 4; j++)
                acc[i][j] = __builtin_amdgcn_mfma_f32_16x16x32_bf16(af[i], bfr[j], acc[i][j], 0, 0, 0);
    }
#pragma unroll
    for (int i = 0; i < 4; i++) {
#pragma unroll
        for (int r = 0; r < 4; r++) {
            int m = m0 + wm + i * 16 + lq * 4 + r;
            if (m >= M) continue;
#pragma unroll
            for (int j = 0; j < 4; j++)
                C[(long)m * ldc + n0 + wn + j * 16 + lr] = acc[i][j][r];
        }
    }
}

// ---------- fp32 [K][N] -> bf16-bits transposed [N][K] (tiled via LDS) ----------
__global__ __launch_bounds__(256) void tpose_cvt(const float* __restrict__ src,
                                                 unsigned short* __restrict__ dst,
                                                 int K, int N)
{
    __shared__ float t[32][33];
    int n0 = blockIdx.x * 32, k0 = blockIdx.y * 32;
    int tid = threadIdx.x;
    int r = tid >> 3, c4 = (tid & 7) * 4;
    float4 v = *(const float4*)&src[(long)(k0 + r) * N + n0 + c4];
    t[r][c4] = v.x; t[r][c4 + 1] = v.y; t[r][c4 + 2] = v.z; t[r][c4 + 3] = v.w;
    __syncthreads();
    ushort4 o;
    o.x = f2b(t[c4][r]);
    o.y = f2b(t[c4 + 1][r]);
    o.z = f2b(t[c4 + 2][r]);
    o.w = f2b(t[c4 + 3][r]);
    *(ushort4*)&dst[(long)(n0 + r) * K + k0 + c4] = o;
}

// ---------- fp32 [M][C] -> bf16-bits [Mpad][C] (zero pad rows >= M) ----------
__global__ void cvt_pad(const float* __restrict__ src, unsigned short* __restrict__ dst,
                        int M, int Mpad, int C)
{
    long i4 = ((long)blockIdx.x * 256 + threadIdx.x) * 4;
    if (i4 >= (long)Mpad * C) return;
    int row = (int)(i4 / C);
    ushort4 o = {0, 0, 0, 0};
    if (row < M) {
        float4 v = *(const float4*)&src[i4];
        o.x = f2b(v.x); o.y = f2b(v.y); o.z = f2b(v.z); o.w = f2b(v.w);
    }
    *(ushort4*)&dst[i4] = o;
}

// ---------- y * silu(z) -> bf16-bits [Mpad][C] ----------
__global__ void gate_cvt(const float* __restrict__ y, const float* __restrict__ z,
                         unsigned short* __restrict__ dst, int M, int Mpad, int C, int ldz)
{
    long i4 = ((long)blockIdx.x * 256 + threadIdx.x) * 4;
    if (i4 >= (long)Mpad * C) return;
    int row = (int)(i4 / C);
    int col = (int)(i4 - (long)row * C);
    ushort4 o = {0, 0, 0, 0};
    if (row < M) {
        float4 yv = *(const float4*)&y[i4];
        float4 zv = *(const float4*)&z[(long)row * ldz + col];
        o.x = f2b(yv.x * siluf(zv.x));
        o.y = f2b(yv.y * siluf(zv.y));
        o.z = f2b(yv.z * siluf(zv.z));
        o.w = f2b(yv.w * siluf(zv.w));
    }
    *(ushort4*)&dst[i4] = o;
}

// ---------- causal depthwise conv (k=4) + bias + silu ----------
__global__ void conv_silu_kernel(const float* __restrict__ xz, const float* __restrict__ w,
                                 const float* __restrict__ bias, float* __restrict__ out,
                                 int Bn, int L, int din, int ldx)
{
    int idx = blockIdx.x * 256 + threadIdx.x;
    int total = Bn * L * din;
    if (idx >= total) return;
    int c = idx % din;
    int r = idx / din;
    int t = r % L;
    int b = r / L;
    float acc = bias[c];
#pragma unroll
    for (int i = 0; i < 4; i++) {
        int tt = t - 3 + i;
        if (tt >= 0) acc += w[c * 4 + i] * xz[((long)(b * L + tt)) * ldx + c];
    }
    out[idx] = siluf(acc);
}

// ---------- selective scan (u/y may alias) ----------
// Inner loop unrolled x8: h-recurrence (exp->fma) is the only true serial
// chain; the 8 shuffle-reduce trees are independent and pipeline their DS
// latency instead of serializing (was ~600 cy/step critical path).
template<int T>
__global__ __launch_bounds__(256) void scan_kernel(
    const float* u, const float* dt,
    const float* xdbl, const float* __restrict__ A_log,
    const float* __restrict__ Dp, float* y,
    int din, int L, int xld, int boff, int coff)
{
    __shared__ float Bc[T][16], Cc[T][16], dtc[T][16], uc[T][16], yc[T][16];
    int tx = threadIdx.x;
    int dl = tx >> 4;
    int n = tx & 15;
    int dbase = blockIdx.x * 16;
    int dg = dbase + dl;
    int b = blockIdx.y;
    bool act = dg < din;
    float Acoef = act ? -__expf(A_log[dg * 16 + n]) : 0.f;
    float Dv = act ? Dp[dg] : 0.f;
    int nvalid = min(16, din - dbase);
    float h = 0.f;
    for (int c0 = 0; c0 < L; c0 += T) {
        int tcnt = min(T, L - c0);
        for (int i = tx; i < T * 16; i += 256) {
            int tt = i >> 4, c = i & 15;
            if (tt < tcnt) {
                long row = (long)b * L + c0 + tt;
                float uv = 0.f, dv = 0.f;
                if (c < nvalid) { uv = u[row * din + dbase + c]; dv = dt[row * din + dbase + c]; }
                uc[tt][c] = uv; dtc[tt][c] = dv;
                Bc[tt][c] = xdbl[row * xld + boff + c];
                Cc[tt][c] = xdbl[row * xld + coff + c];
            }
        }
        __syncthreads();
        int tt = 0;
        for (; tt + 8 <= tcnt; tt += 8) {
            float pbuf[8];
#pragma unroll
            for (int q = 0; q < 8; q++) {
                float dtv = dtc[tt + q][dl];
                float uv = uc[tt + q][dl];
                float dA = __expf(dtv * Acoef);
                h = dA * h + (dtv * uv) * Bc[tt + q][n];
                pbuf[q] = h * Cc[tt + q][n];
            }
#pragma unroll
            for (int q = 0; q < 8; q++) {
                float p = pbuf[q];
                p += __shfl_xor(p, 1);
                p += __shfl_xor(p, 2);
                p += __shfl_xor(p, 4);
                p += __shfl_xor(p, 8);
                if (n == 0) yc[tt + q][dl] = p + Dv * uc[tt + q][dl];
            }
        }
        for (; tt < tcnt; ++tt) {
            float dtv = dtc[tt][dl];
            float uv = uc[tt][dl];
            float dA = __expf(dtv * Acoef);
            h = dA * h + (dtv * uv) * Bc[tt][n];
            float p = h * Cc[tt][n];
            p += __shfl_xor(p, 1);
            p += __shfl_xor(p, 2);
            p += __shfl_xor(p, 4);
            p += __shfl_xor(p, 8);
            if (n == 0) yc[tt][dl] = p + Dv * uv;
        }
        __syncthreads();
        for (int i = tx; i < tcnt * 16; i += 256) {
            int tt2 = i >> 4, c = i & 15;
            if (c < nvalid) y[((long)b * L + c0 + tt2) * din + dbase + c] = yc[tt2][c];
        }
        __syncthreads();
    }
}

// ---------- mean over n (98) + softmax over k (1024), per batch ----------
// coalesced: stage 32 rows (32x98 contiguous floats) in LDS per pass
__global__ __launch_bounds__(256) void mean_softmax_kernel(const float* __restrict__ sc2,
                                                           float* __restrict__ s)
{
    __shared__ float tile[32 * 98];
    __shared__ float vals[1024];
    __shared__ float red[256];
    int b = blockIdx.x, tx = threadIdx.x;
    for (int k0 = 0; k0 < 1024; k0 += 32) {
        const float* base = sc2 + ((long)b * 1024 + k0) * 98;
        for (int i = tx; i < 32 * 98; i += 256) tile[i] = base[i];
        __syncthreads();
        int row = tx >> 3, ln = tx & 7;
        float sum = 0.f;
        for (int nn = ln; nn < 98; nn += 8) sum += tile[row * 98 + nn];
        sum += __shfl_xor(sum, 1);
        sum += __shfl_xor(sum, 2);
        sum += __shfl_xor(sum, 4);
        if (ln == 0) vals[k0 + row] = sum * (1.f / 98.f);
        __syncthreads();
    }
    float mx = -1e30f;
    for (int k = tx; k < 1024; k += 256) mx = fmaxf(mx, vals[k]);
    red[tx] = mx; __syncthreads();
    for (int st = 128; st > 0; st >>= 1) { if (tx < st) red[tx] = fmaxf(red[tx], red[tx + st]); __syncthreads(); }
    mx = red[0]; __syncthreads();
    float lsum = 0.f;
    for (int k = tx; k < 1024; k += 256) { float e = __expf(vals[k] - mx); vals[k] = e; lsum += e; }
    red[tx] = lsum; __syncthreads();
    for (int st = 128; st > 0; st >>= 1) { if (tx < st) red[tx] += red[tx + st]; __syncthreads(); }
    float inv = 1.f / red[0];
    __syncthreads();
    for (int k = tx; k < 1024; k += 256) s[(long)b * 1024 + k] = vals[k] * inv;
}

// ---------- top-98 sequential selection (jax tie semantics) ----------
__global__ __launch_bounds__(256) void topk_select_kernel(const float* __restrict__ s,
                                                          int* __restrict__ ind,
                                                          float* __restrict__ vtopk)
{
    __shared__ unsigned long long arr[1024];
    __shared__ unsigned long long red[256];
    int b = blockIdx.x, tx = threadIdx.x;
    for (int k = tx; k < 1024; k += 256) {
        float v = s[b * 1024 + k];
        unsigned u = __float_as_uint(v);
        u = (u & 0x80000000u) ? ~u : (u | 0x80000000u);
        arr[k] = ((unsigned long long)u << 32) | (unsigned)(~k);
    }
    __syncthreads();
    for (int r = 0; r < 98; ++r) {
        unsigned long long m = 0ull;
        for (int k = tx; k < 1024; k += 256) m = (arr[k] > m) ? arr[k] : m;
        red[tx] = m; __syncthreads();
        for (int st = 128; st > 0; st >>= 1) {
            if (tx < st && red[tx + st] > red[tx]) red[tx] = red[tx + st];
            __syncthreads();
        }
        unsigned long long best = red[0];
        if (tx == 0) {
            unsigned lo = (unsigned)(best & 0xffffffffu);
            int kidx = (int)(~lo);
            unsigned ub = (unsigned)(best >> 32);
            unsigned fb = (ub & 0x80000000u) ? (ub ^ 0x80000000u) : ~ub;
            ind[b * 98 + r] = kidx;
            vtopk[b * 98 + r] = __uint_as_float(fb);
            arr[kidx] = 0ull;
        }
        __syncthreads();
    }
}

// ---------- gather: h[b,j,:] = img[j,:] + kf[b,:,ind]*v ----------
__global__ void gather_kernel(const float* __restrict__ img, const float* __restrict__ kf,
                              const int* __restrict__ ind, const float* __restrict__ vtopk,
                              float* __restrict__ h)
{
    int j = blockIdx.x, b = blockIdx.y;
    int kidx = ind[b * 98 + j];
    float v = vtopk[b * 98 + j];
    long hbase = ((long)b * 98 + j) * 2048;
    const float* kfb = kf + (long)b * 2048 * 1024 + kidx;
    for (int d = threadIdx.x; d < 2048; d += 256)
        h[hbase + d] = img[(long)j * 2048 + d] + kfb[(long)d * 1024] * v;
}

// ---------- host launch ----------
extern "C" void kernel_launch(void* const* d_in, const int* in_sizes, int n_in,
                              void* d_out, int out_size, void* d_ws, size_t ws_size,
                              hipStream_t stream)
{
    const float* imgF      = (const float*)d_in[0];
    const float* kf        = (const float*)d_in[1];
    const float* a_in_w    = (const float*)d_in[2];
    const float* a_conv_w  = (const float*)d_in[3];
    const float* a_conv_b  = (const float*)d_in[4];
    const float* a_xproj_w = (const float*)d_in[5];
    const float* a_dt_w    = (const float*)d_in[6];
    const float* a_dt_b    = (const float*)d_in[7];
    const float* a_A_log   = (const float*)d_in[8];
    const float* a_D       = (const float*)d_in[9];
    const float* a_out_w   = (const float*)d_in[10];
    const float* c_in_w    = (const float*)d_in[11];
    const float* c_conv_w  = (const float*)d_in[12];
    const float* c_conv_b  = (const float*)d_in[13];
    const float* c_xproj_w = (const float*)d_in[14];
    const float* c_dt_w    = (const float*)d_in[15];
    const float* c_dt_b    = (const float*)d_in[16];
    const float* c_A_log   = (const float*)d_in[17];
    const float* c_D       = (const float*)d_in[18];
    const float* c_out_w   = (const float*)d_in[19];

    float* fout = (float*)d_out;

    float* ws = (float*)d_ws;
    float* h_buf  = ws;                      // 1,605,632 floats
    float* S      = ws + 1605632;
    // stage A
    float* score  = S;                       // 802,816 (reused as score2)
    float* xz_a   = S + 802816;              // 3,211,264
    float* xi_a   = S + 4014080;             // 1,605,632 (scan in-place)
    float* xdbl_a = S + 5619712;             // 319,488
    float* dt_a   = S + 5939200;             // 1,605,632
    float* sbuf   = S + 7544832;             // 8,192
    int*   indb   = (int*)(S + 7553024);     // 784
    float* vtopk  = S + 7553808;             // 784
    // stage C (aliases stage A region)
    float* xz_c   = S;                       // 6,422,528
    float* xi_c   = S + 6422528;             // 3,211,264 (scan in-place)
    float* xdbl_c = S + 9633792;             // 125,440
    float* dt_c   = S + 9759232;             // 3,211,264
    // bf16 scratch (beyond the fp32 region: base float offset 14,576,128)
    unsigned short* cwbf  = (unsigned short*)(ws + 14576128);          // 16,777,216 bf16
    unsigned short* h_bf  = (unsigned short*)(ws + 14576128 + 8388608);// 1,835,008 bf16
    unsigned short* yz_bf = (unsigned short*)(ws + 14576128 + 9306112);// 3,670,016 bf16
    // split-K partials:
    //  - step 1 (stage A): bf16 region is dead until step 11 -> reuse it.
    //    8 chunks x 802,816 = 6,422,528 floats at 14,576,128..20,998,656.
    float* CpartS1 = ws + 14576128;
    //  - step 13 (stage C): upper half of cwbf region is dead between
    //    mfma_gemm #11 and tpose_cvt #16. 16 x 784 x 160 floats.
    float* Cpart  = ws + 18770432;
    // total ws: 25,717,248 floats ~= 103 MB

    // ===== stage A (fp32) =====
    // 1. score[b] = kf[b]^T @ imgF^T : split-K x8 (2048 blocks vs 256)
    gemm64_skb<true, true><<<dim3(16, 2, 64), 256, 0, stream>>>(
        kf, imgF, CpartS1,
        1024, 98, 2048, 1024, 2048, 256, 8,
        (long)2048 * 1024, 0L, (long)1024 * 98, 802816L);
    sk_reduce<<<3136, 256, 0, stream>>>(CpartS1, score, 802816L, 8);

    gemm64<false, false, false, 0><<<dim3(128, 7, 1), 256, 0, stream>>>(
        score, a_in_w, xz_a, nullptr, nullptr, 8192, 392, 98, 98, 392, 392, 0, 0L, 0L, 0L);
    conv_silu_kernel<<<6272, 256, 0, stream>>>(xz_a, a_conv_w, a_conv_b, xi_a, 8, 1024, 196, 392);
    gemm64<false, false, false, 0><<<dim3(128, 1, 1), 256, 0, stream>>>(
        xi_a, a_xproj_w, xdbl_a, nullptr, nullptr, 8192, 39, 196, 196, 39, 39, 0, 0L, 0L, 0L);
    gemm64<false, false, false, 1><<<dim3(128, 4, 1), 256, 0, stream>>>(
        xdbl_a, a_dt_w, dt_a, nullptr, a_dt_b, 8192, 196, 7, 39, 196, 196, 0, 0L, 0L, 0L);
    scan_kernel<64><<<dim3(13, 8, 1), 256, 0, stream>>>(
        xi_a, dt_a, xdbl_a, a_A_log, a_D, xi_a, 196, 1024, 39, 7, 23);
    gemm64<false, false, true, 0><<<dim3(128, 2, 1), 256, 0, stream>>>(
        xi_a, a_out_w, score, xz_a + 196, nullptr, 8192, 98, 196, 196, 98, 98, 392, 0L, 0L, 0L);
    mean_softmax_kernel<<<8, 256, 0, stream>>>(score, sbuf);
    topk_select_kernel<<<8, 256, 0, stream>>>(sbuf, indb, vtopk);
    gather_kernel<<<dim3(98, 8, 1), 256, 0, stream>>>(imgF, kf, indb, vtopk, h_buf);

    // ===== stage C =====
    // 11. xz_c = h @ c_in_w  (bf16 MFMA)
    tpose_cvt<<<dim3(256, 64, 1), 256, 0, stream>>>(c_in_w, cwbf, 2048, 8192);
    cvt_pad<<<1792, 256, 0, stream>>>(h_buf, h_bf, 784, 896, 2048);
    mfma_gemm<<<dim3(7, 64, 1), 256, 0, stream>>>(h_bf, cwbf, xz_c, 784, 8192, 2048, 8192);

    // 12. conv + silu -> xi_c
    conv_silu_kernel<<<12544, 256, 0, stream>>>(xz_c, c_conv_w, c_conv_b, xi_c, 8, 98, 4096, 8192);

    // 13. xdbl_c = xi_c @ c_xproj_w (fp32, split-K x16)
    gemm64_sk<<<dim3(13, 3, 16), 256, 0, stream>>>(
        xi_c, c_xproj_w, Cpart, 784, 160, 4096, 4096, 160, 256);
    sk_reduce<<<490, 256, 0, stream>>>(Cpart, xdbl_c, 125440L, 16);

    // 14. dt_c = softplus(xdbl_c[:, :128] @ c_dt_w + c_dt_b) (fp32)
    gemm64<false, false, false, 1><<<dim3(13, 64, 1), 256, 0, stream>>>(
        xdbl_c, c_dt_w, dt_c, nullptr, c_dt_b, 784, 4096, 128, 160, 4096, 4096, 0, 0L, 0L, 0L);

    // 15. selective scan C (in-place)
    scan_kernel<98><<<dim3(256, 8, 1), 256, 0, stream>>>(
        xi_c, dt_c, xdbl_c, c_A_log, c_D, xi_c, 4096, 98, 160, 128, 144);

    // 16. out = (y_c * silu(z_c)) @ c_out_w  (bf16 MFMA, direct to d_out)
    gate_cvt<<<3584, 256, 0, stream>>>(xi_c, xz_c + 4096, yz_bf, 784, 896, 4096, 8192);
    tpose_cvt<<<dim3(64, 128, 1), 256, 0, stream>>>(c_out_w, cwbf, 4096, 2048);
    mfma_gemm<<<dim3(7, 16, 1), 256, 0, stream>>>(yz_bf, cwbf, fout, 784, 2048, 4096, 2048);
}

// Round 6
// 1201.339 us; speedup vs baseline: 1.7295x; 1.0762x over previous
//
#include <hip/hip_runtime.h>
#include <hip/hip_bf16.h>
#include <math.h>

typedef __attribute__((ext_vector_type(8))) short short8;
typedef __attribute__((ext_vector_type(4))) float floatx4;

// ---------- helpers ----------
__device__ __forceinline__ float siluf(float x) {
    float e = __expf(-fabsf(x));
    float s = (x >= 0.f) ? 1.f / (1.f + e) : e / (1.f + e);
    return x * s;
}
__device__ __forceinline__ float softplusf(float x) {
    if (x > 20.f) return x;
    if (x < -20.f) return __expf(x);
    return log1pf(__expf(x));
}
__device__ __forceinline__ unsigned short f2b(float v) {
    __hip_bfloat16 b = __float2bfloat16(v);
    unsigned short u;
    __builtin_memcpy(&u, &b, 2);
    return u;
}

// ---------- generic 64x64 tiled GEMM (fp32) — stage A + small stage-C ----------
template<bool ACOL, bool BCOL, bool AMUL, int EPI>
__global__ __launch_bounds__(256) void gemm64(
    const float* __restrict__ A, const float* __restrict__ Bw, float* __restrict__ C,
    const float* __restrict__ A2, const float* __restrict__ bias,
    int M, int N, int K, int lda, int ldb, int ldc, int lda2,
    long batA, long batB, long batC)
{
    __shared__ __align__(16) float As[16][64];
    __shared__ __align__(16) float Bs[16][64];
    int tx = threadIdx.x;
    int m0 = blockIdx.x * 64, n0 = blockIdx.y * 64;
    A += blockIdx.z * batA; Bw += blockIdx.z * batB; C += blockIdx.z * batC;
    int tm = tx >> 4, tn = tx & 15;
    float acc[4][4] = {};
    for (int k0 = 0; k0 < K; k0 += 16) {
        for (int i = tx; i < 1024; i += 256) {
            int mm, kk;
            if (ACOL) { mm = i & 63; kk = i >> 6; } else { kk = i & 15; mm = i >> 4; }
            int m = m0 + mm, k = k0 + kk;
            float v = 0.f;
            if (m < M && k < K) {
                long ia = ACOL ? ((long)k * lda + m) : ((long)m * lda + k);
                v = A[ia];
                if (AMUL) v *= siluf(A2[(long)m * lda2 + k]);
            }
            As[kk][mm] = v;
        }
        for (int i = tx; i < 1024; i += 256) {
            int nn, kk;
            if (BCOL) { kk = i & 15; nn = i >> 4; } else { nn = i & 63; kk = i >> 6; }
            int n = n0 + nn, k = k0 + kk;
            float v = 0.f;
            if (n < N && k < K) {
                long ib = BCOL ? ((long)n * ldb + k) : ((long)k * ldb + n);
                v = Bw[ib];
            }
            Bs[kk][nn] = v;
        }
        __syncthreads();
#pragma unroll
        for (int kk = 0; kk < 16; ++kk) {
            float4 av = *(const float4*)&As[kk][tm * 4];
            float4 bv = *(const float4*)&Bs[kk][tn * 4];
            float a[4] = {av.x, av.y, av.z, av.w};
            float b[4] = {bv.x, bv.y, bv.z, bv.w};
#pragma unroll
            for (int i = 0; i < 4; i++)
#pragma unroll
                for (int j = 0; j < 4; j++) acc[i][j] += a[i] * b[j];
        }
        __syncthreads();
    }
#pragma unroll
    for (int i = 0; i < 4; i++) {
        int m = m0 + tm * 4 + i;
        if (m >= M) continue;
#pragma unroll
        for (int j = 0; j < 4; j++) {
            int n = n0 + tn * 4 + j;
            if (n >= N) continue;
            float v = acc[i][j];
            if (EPI == 1) v = softplusf(v + bias[n]);
            C[(long)m * ldc + n] = v;
        }
    }
}

// ---------- split-K fp32 GEMM (row-major A,B): Cpart[z] = partial ----------
__global__ __launch_bounds__(256) void gemm64_sk(
    const float* __restrict__ A, const float* __restrict__ Bw, float* __restrict__ Cpart,
    int M, int N, int K, int lda, int ldb, int kch)
{
    __shared__ __align__(16) float As[16][64];
    __shared__ __align__(16) float Bs[16][64];
    int tx = threadIdx.x;
    int m0 = blockIdx.x * 64, n0 = blockIdx.y * 64;
    int kbeg = blockIdx.z * kch;
    int kend = min(kbeg + kch, K);
    Cpart += (long)blockIdx.z * M * N;
    int tm = tx >> 4, tn = tx & 15;
    float acc[4][4] = {};
    for (int k0 = kbeg; k0 < kend; k0 += 16) {
        for (int i = tx; i < 1024; i += 256) {
            int kk = i & 15, mm = i >> 4;
            int m = m0 + mm, k = k0 + kk;
            As[kk][mm] = (m < M && k < kend) ? A[(long)m * lda + k] : 0.f;
        }
        for (int i = tx; i < 1024; i += 256) {
            int nn = i & 63, kk = i >> 6;
            int n = n0 + nn, k = k0 + kk;
            Bs[kk][nn] = (n < N && k < kend) ? Bw[(long)k * ldb + n] : 0.f;
        }
        __syncthreads();
#pragma unroll
        for (int kk = 0; kk < 16; ++kk) {
            float4 av = *(const float4*)&As[kk][tm * 4];
            float4 bv = *(const float4*)&Bs[kk][tn * 4];
            float a[4] = {av.x, av.y, av.z, av.w};
            float b[4] = {bv.x, bv.y, bv.z, bv.w};
#pragma unroll
            for (int i = 0; i < 4; i++)
#pragma unroll
                for (int j = 0; j < 4; j++) acc[i][j] += a[i] * b[j];
        }
        __syncthreads();
    }
#pragma unroll
    for (int i = 0; i < 4; i++) {
        int m = m0 + tm * 4 + i;
        if (m >= M) continue;
#pragma unroll
        for (int j = 0; j < 4; j++) {
            int n = n0 + tn * 4 + j;
            if (n >= N) continue;
            Cpart[(long)m * N + n] = acc[i][j];
        }
    }
}

// ---------- batched split-K fp32 GEMM with layout templates ----------
// blockIdx.z = batch * KZ + kz. Partials: Cpart + kz*partStride + batch*batC.
template<bool ACOL, bool BCOL>
__global__ __launch_bounds__(256) void gemm64_skb(
    const float* __restrict__ A, const float* __restrict__ Bw, float* __restrict__ Cpart,
    int M, int N, int K, int lda, int ldb, int kch, int KZ,
    long batA, long batB, long batC, long partStride)
{
    __shared__ __align__(16) float As[16][64];
    __shared__ __align__(16) float Bs[16][64];
    int tx = threadIdx.x;
    int m0 = blockIdx.x * 64, n0 = blockIdx.y * 64;
    int bz = blockIdx.z / KZ, kz = blockIdx.z - bz * KZ;
    A += (long)bz * batA; Bw += (long)bz * batB;
    Cpart += (long)kz * partStride + (long)bz * batC;
    int kbeg = kz * kch;
    int kend = min(kbeg + kch, K);
    int tm = tx >> 4, tn = tx & 15;
    float acc[4][4] = {};
    for (int k0 = kbeg; k0 < kend; k0 += 16) {
        for (int i = tx; i < 1024; i += 256) {
            int mm, kk;
            if (ACOL) { mm = i & 63; kk = i >> 6; } else { kk = i & 15; mm = i >> 4; }
            int m = m0 + mm, k = k0 + kk;
            float v = 0.f;
            if (m < M && k < kend) {
                long ia = ACOL ? ((long)k * lda + m) : ((long)m * lda + k);
                v = A[ia];
            }
            As[kk][mm] = v;
        }
        for (int i = tx; i < 1024; i += 256) {
            int nn, kk;
            if (BCOL) { kk = i & 15; nn = i >> 4; } else { nn = i & 63; kk = i >> 6; }
            int n = n0 + nn, k = k0 + kk;
            float v = 0.f;
            if (n < N && k < kend) {
                long ib = BCOL ? ((long)n * ldb + k) : ((long)k * ldb + n);
                v = Bw[ib];
            }
            Bs[kk][nn] = v;
        }
        __syncthreads();
#pragma unroll
        for (int kk = 0; kk < 16; ++kk) {
            float4 av = *(const float4*)&As[kk][tm * 4];
            float4 bv = *(const float4*)&Bs[kk][tn * 4];
            float a[4] = {av.x, av.y, av.z, av.w};
            float b[4] = {bv.x, bv.y, bv.z, bv.w};
#pragma unroll
            for (int i = 0; i < 4; i++)
#pragma unroll
                for (int j = 0; j < 4; j++) acc[i][j] += a[i] * b[j];
        }
        __syncthreads();
    }
#pragma unroll
    for (int i = 0; i < 4; i++) {
        int m = m0 + tm * 4 + i;
        if (m >= M) continue;
#pragma unroll
        for (int j = 0; j < 4; j++) {
            int n = n0 + tn * 4 + j;
            if (n >= N) continue;
            Cpart[(long)m * N + n] = acc[i][j];
        }
    }
}

// ---------- sum nz split-K partial buffers ----------
__global__ void sk_reduce(const float* __restrict__ Cpart, float* __restrict__ C,
                          long len, int nz)
{
    long i = (long)blockIdx.x * 256 + threadIdx.x;
    if (i >= len) return;
    float s = 0.f;
    for (int z = 0; z < nz; z++) s += Cpart[(long)z * len + i];
    C[i] = s;
}

// ---------- bf16 MFMA GEMM: C[M,N] = A[M,K] x B[K,N] ----------
// Abf: bf16 bits, row-major [Mpad][K] (Mpad >= gridDim.x*128)
// Bbf: bf16 bits, B TRANSPOSED layout [N][K]
// 128x128 tile, 4 waves (2x2 of 64x64), 16x16x32 MFMA, BK=32.
__global__ __launch_bounds__(256) void mfma_gemm(
    const unsigned short* __restrict__ Abf, const unsigned short* __restrict__ Bbf,
    float* __restrict__ C, int M, int N, int K, int ldc)
{
    __shared__ __align__(16) short As[128 * 40];   // +8 pad kills ds_read conflicts
    __shared__ __align__(16) short Bs[128 * 40];
    int tid = threadIdx.x;
    int m0 = blockIdx.x * 128, n0 = blockIdx.y * 128;
    int w = tid >> 6, l = tid & 63;
    int wm = (w >> 1) * 64, wn = (w & 1) * 64;
    int lr = l & 15, lq = l >> 4;
    int row0 = tid >> 2, kc = (tid & 3) * 8;
    floatx4 acc[4][4];
#pragma unroll
    for (int i = 0; i < 4; i++)
#pragma unroll
        for (int j = 0; j < 4; j++) acc[i][j] = (floatx4){0.f, 0.f, 0.f, 0.f};
    const unsigned short* Ap  = Abf + (long)(m0 + row0) * K + kc;
    const unsigned short* Ap2 = Abf + (long)(m0 + row0 + 64) * K + kc;
    const unsigned short* Bp  = Bbf + (long)(n0 + row0) * K + kc;
    const unsigned short* Bp2 = Bbf + (long)(n0 + row0 + 64) * K + kc;
    for (int k0 = 0; k0 < K; k0 += 32) {
        uint4 a0 = *(const uint4*)(Ap + k0);
        uint4 a1 = *(const uint4*)(Ap2 + k0);
        uint4 b0 = *(const uint4*)(Bp + k0);
        uint4 b1 = *(const uint4*)(Bp2 + k0);
        __syncthreads();
        *(uint4*)&As[row0 * 40 + kc] = a0;
        *(uint4*)&As[(row0 + 64) * 40 + kc] = a1;
        *(uint4*)&Bs[row0 * 40 + kc] = b0;
        *(uint4*)&Bs[(row0 + 64) * 40 + kc] = b1;
        __syncthreads();
        short8 af[4], bfr[4];
#pragma unroll
        for (int i = 0; i < 4; i++) af[i]  = *(const short8*)&As[(wm + i * 16 + lr) * 40 + lq * 8];
#pragma unroll
        for (int i = 0; i < 4; i++) bfr[i] = *(const short8*)&Bs[(wn + i * 16 + lr) * 40 + lq * 8];
#pragma unroll
        for (int i = 0; i < 4; i++)
#pragma unroll
            for (int j = 0; j < 4; j++)
                acc[i][j] = __builtin_amdgcn_mfma_f32_16x16x32_bf16(af[i], bfr[j], acc[i][j], 0, 0, 0);
    }
#pragma unroll
    for (int i = 0; i < 4; i++) {
#pragma unroll
        for (int r = 0; r < 4; r++) {
            int m = m0 + wm + i * 16 + lq * 4 + r;
            if (m >= M) continue;
#pragma unroll
            for (int j = 0; j < 4; j++)
                C[(long)m * ldc + n0 + wn + j * 16 + lr] = acc[i][j][r];
        }
    }
}

// ---------- fp32 [K][N] -> bf16-bits transposed [N][K] (tiled via LDS) ----------
__global__ __launch_bounds__(256) void tpose_cvt(const float* __restrict__ src,
                                                 unsigned short* __restrict__ dst,
                                                 int K, int N)
{
    __shared__ float t[32][33];
    int n0 = blockIdx.x * 32, k0 = blockIdx.y * 32;
    int tid = threadIdx.x;
    int r = tid >> 3, c4 = (tid & 7) * 4;
    float4 v = *(const float4*)&src[(long)(k0 + r) * N + n0 + c4];
    t[r][c4] = v.x; t[r][c4 + 1] = v.y; t[r][c4 + 2] = v.z; t[r][c4 + 3] = v.w;
    __syncthreads();
    ushort4 o;
    o.x = f2b(t[c4][r]);
    o.y = f2b(t[c4 + 1][r]);
    o.z = f2b(t[c4 + 2][r]);
    o.w = f2b(t[c4 + 3][r]);
    *(ushort4*)&dst[(long)(n0 + r) * K + k0 + c4] = o;
}

// ---------- fp32 [M][C] -> bf16-bits [Mpad][C] (zero pad rows >= M) ----------
__global__ void cvt_pad(const float* __restrict__ src, unsigned short* __restrict__ dst,
                        int M, int Mpad, int C)
{
    long i4 = ((long)blockIdx.x * 256 + threadIdx.x) * 4;
    if (i4 >= (long)Mpad * C) return;
    int row = (int)(i4 / C);
    ushort4 o = {0, 0, 0, 0};
    if (row < M) {
        float4 v = *(const float4*)&src[i4];
        o.x = f2b(v.x); o.y = f2b(v.y); o.z = f2b(v.z); o.w = f2b(v.w);
    }
    *(ushort4*)&dst[i4] = o;
}

// ---------- y * silu(z) -> bf16-bits [Mpad][C] ----------
__global__ void gate_cvt(const float* __restrict__ y, const float* __restrict__ z,
                         unsigned short* __restrict__ dst, int M, int Mpad, int C, int ldz)
{
    long i4 = ((long)blockIdx.x * 256 + threadIdx.x) * 4;
    if (i4 >= (long)Mpad * C) return;
    int row = (int)(i4 / C);
    int col = (int)(i4 - (long)row * C);
    ushort4 o = {0, 0, 0, 0};
    if (row < M) {
        float4 yv = *(const float4*)&y[i4];
        float4 zv = *(const float4*)&z[(long)row * ldz + col];
        o.x = f2b(yv.x * siluf(zv.x));
        o.y = f2b(yv.y * siluf(zv.y));
        o.z = f2b(yv.z * siluf(zv.z));
        o.w = f2b(yv.w * siluf(zv.w));
    }
    *(ushort4*)&dst[i4] = o;
}

// ---------- causal depthwise conv (k=4) + bias + silu ----------
__global__ void conv_silu_kernel(const float* __restrict__ xz, const float* __restrict__ w,
                                 const float* __restrict__ bias, float* __restrict__ out,
                                 int Bn, int L, int din, int ldx)
{
    int idx = blockIdx.x * 256 + threadIdx.x;
    int total = Bn * L * din;
    if (idx >= total) return;
    int c = idx % din;
    int r = idx / din;
    int t = r % L;
    int b = r / L;
    float acc = bias[c];
#pragma unroll
    for (int i = 0; i < 4; i++) {
        int tt = t - 3 + i;
        if (tt >= 0) acc += w[c * 4 + i] * xz[((long)(b * L + tt)) * ldx + c];
    }
    out[idx] = siluf(acc);
}

// ---------- selective scan (u/y may alias) ----------
// 16-step groups; shuffle-reduce trees issued LEVEL-MAJOR so the 16
// independent DS ops per level pipeline their ~120cy latency (tree-major
// order serialized: ~500 cy/step measured r5). Butterfly add order per
// tree unchanged -> bit-identical results.
template<int T>
__global__ __launch_bounds__(256) void scan_kernel(
    const float* u, const float* dt,
    const float* xdbl, const float* __restrict__ A_log,
    const float* __restrict__ Dp, float* y,
    int din, int L, int xld, int boff, int coff)
{
    __shared__ float Bc[T][16], Cc[T][16], dtc[T][16], uc[T][16], yc[T][16];
    int tx = threadIdx.x;
    int dl = tx >> 4;
    int n = tx & 15;
    int dbase = blockIdx.x * 16;
    int dg = dbase + dl;
    int b = blockIdx.y;
    bool act = dg < din;
    float Acoef = act ? -__expf(A_log[dg * 16 + n]) : 0.f;
    float Dv = act ? Dp[dg] : 0.f;
    int nvalid = min(16, din - dbase);
    float h = 0.f;
    for (int c0 = 0; c0 < L; c0 += T) {
        int tcnt = min(T, L - c0);
        for (int i = tx; i < T * 16; i += 256) {
            int tt = i >> 4, c = i & 15;
            if (tt < tcnt) {
                long row = (long)b * L + c0 + tt;
                float uv = 0.f, dv = 0.f;
                if (c < nvalid) { uv = u[row * din + dbase + c]; dv = dt[row * din + dbase + c]; }
                uc[tt][c] = uv; dtc[tt][c] = dv;
                Bc[tt][c] = xdbl[row * xld + boff + c];
                Cc[tt][c] = xdbl[row * xld + coff + c];
            }
        }
        __syncthreads();
        int tt = 0;
        for (; tt + 16 <= tcnt; tt += 16) {
            float pbuf[16];
#pragma unroll
            for (int q = 0; q < 16; q++) {
                float dtv = dtc[tt + q][dl];
                float uv = uc[tt + q][dl];
                float dA = __expf(dtv * Acoef);
                h = dA * h + (dtv * uv) * Bc[tt + q][n];
                pbuf[q] = h * Cc[tt + q][n];
            }
            // level-major butterfly: 16 independent shuffles per level
#pragma unroll
            for (int q = 0; q < 16; q++) pbuf[q] += __shfl_xor(pbuf[q], 1);
#pragma unroll
            for (int q = 0; q < 16; q++) pbuf[q] += __shfl_xor(pbuf[q], 2);
#pragma unroll
            for (int q = 0; q < 16; q++) pbuf[q] += __shfl_xor(pbuf[q], 4);
#pragma unroll
            for (int q = 0; q < 16; q++) pbuf[q] += __shfl_xor(pbuf[q], 8);
            if (n == 0) {
#pragma unroll
                for (int q = 0; q < 16; q++)
                    yc[tt + q][dl] = pbuf[q] + Dv * uc[tt + q][dl];
            }
        }
        for (; tt < tcnt; ++tt) {
            float dtv = dtc[tt][dl];
            float uv = uc[tt][dl];
            float dA = __expf(dtv * Acoef);
            h = dA * h + (dtv * uv) * Bc[tt][n];
            float p = h * Cc[tt][n];
            p += __shfl_xor(p, 1);
            p += __shfl_xor(p, 2);
            p += __shfl_xor(p, 4);
            p += __shfl_xor(p, 8);
            if (n == 0) yc[tt][dl] = p + Dv * uv;
        }
        __syncthreads();
        for (int i = tx; i < tcnt * 16; i += 256) {
            int tt2 = i >> 4, c = i & 15;
            if (c < nvalid) y[((long)b * L + c0 + tt2) * din + dbase + c] = yc[tt2][c];
        }
        __syncthreads();
    }
}

// ---------- mean over n (98) + softmax over k (1024), per batch ----------
// coalesced: stage 32 rows (32x98 contiguous floats) in LDS per pass
__global__ __launch_bounds__(256) void mean_softmax_kernel(const float* __restrict__ sc2,
                                                           float* __restrict__ s)
{
    __shared__ float tile[32 * 98];
    __shared__ float vals[1024];
    __shared__ float red[256];
    int b = blockIdx.x, tx = threadIdx.x;
    for (int k0 = 0; k0 < 1024; k0 += 32) {
        const float* base = sc2 + ((long)b * 1024 + k0) * 98;
        for (int i = tx; i < 32 * 98; i += 256) tile[i] = base[i];
        __syncthreads();
        int row = tx >> 3, ln = tx & 7;
        float sum = 0.f;
        for (int nn = ln; nn < 98; nn += 8) sum += tile[row * 98 + nn];
        sum += __shfl_xor(sum, 1);
        sum += __shfl_xor(sum, 2);
        sum += __shfl_xor(sum, 4);
        if (ln == 0) vals[k0 + row] = sum * (1.f / 98.f);
        __syncthreads();
    }
    float mx = -1e30f;
    for (int k = tx; k < 1024; k += 256) mx = fmaxf(mx, vals[k]);
    red[tx] = mx; __syncthreads();
    for (int st = 128; st > 0; st >>= 1) { if (tx < st) red[tx] = fmaxf(red[tx], red[tx + st]); __syncthreads(); }
    mx = red[0]; __syncthreads();
    float lsum = 0.f;
    for (int k = tx; k < 1024; k += 256) { float e = __expf(vals[k] - mx); vals[k] = e; lsum += e; }
    red[tx] = lsum; __syncthreads();
    for (int st = 128; st > 0; st >>= 1) { if (tx < st) red[tx] += red[tx + st]; __syncthreads(); }
    float inv = 1.f / red[0];
    __syncthreads();
    for (int k = tx; k < 1024; k += 256) s[(long)b * 1024 + k] = vals[k] * inv;
}

// ---------- top-98 sequential selection (jax tie semantics) ----------
__global__ __launch_bounds__(256) void topk_select_kernel(const float* __restrict__ s,
                                                          int* __restrict__ ind,
                                                          float* __restrict__ vtopk)
{
    __shared__ unsigned long long arr[1024];
    __shared__ unsigned long long red[256];
    int b = blockIdx.x, tx = threadIdx.x;
    for (int k = tx; k < 1024; k += 256) {
        float v = s[b * 1024 + k];
        unsigned u = __float_as_uint(v);
        u = (u & 0x80000000u) ? ~u : (u | 0x80000000u);
        arr[k] = ((unsigned long long)u << 32) | (unsigned)(~k);
    }
    __syncthreads();
    for (int r = 0; r < 98; ++r) {
        unsigned long long m = 0ull;
        for (int k = tx; k < 1024; k += 256) m = (arr[k] > m) ? arr[k] : m;
        red[tx] = m; __syncthreads();
        for (int st = 128; st > 0; st >>= 1) {
            if (tx < st && red[tx + st] > red[tx]) red[tx] = red[tx + st];
            __syncthreads();
        }
        unsigned long long best = red[0];
        if (tx == 0) {
            unsigned lo = (unsigned)(best & 0xffffffffu);
            int kidx = (int)(~lo);
            unsigned ub = (unsigned)(best >> 32);
            unsigned fb = (ub & 0x80000000u) ? (ub ^ 0x80000000u) : ~ub;
            ind[b * 98 + r] = kidx;
            vtopk[b * 98 + r] = __uint_as_float(fb);
            arr[kidx] = 0ull;
        }
        __syncthreads();
    }
}

// ---------- gather: h[b,j,:] = img[j,:] + kf[b,:,ind]*v ----------
__global__ void gather_kernel(const float* __restrict__ img, const float* __restrict__ kf,
                              const int* __restrict__ ind, const float* __restrict__ vtopk,
                              float* __restrict__ h)
{
    int j = blockIdx.x, b = blockIdx.y;
    int kidx = ind[b * 98 + j];
    float v = vtopk[b * 98 + j];
    long hbase = ((long)b * 98 + j) * 2048;
    const float* kfb = kf + (long)b * 2048 * 1024 + kidx;
    for (int d = threadIdx.x; d < 2048; d += 256)
        h[hbase + d] = img[(long)j * 2048 + d] + kfb[(long)d * 1024] * v;
}

// ---------- host launch ----------
extern "C" void kernel_launch(void* const* d_in, const int* in_sizes, int n_in,
                              void* d_out, int out_size, void* d_ws, size_t ws_size,
                              hipStream_t stream)
{
    const float* imgF      = (const float*)d_in[0];
    const float* kf        = (const float*)d_in[1];
    const float* a_in_w    = (const float*)d_in[2];
    const float* a_conv_w  = (const float*)d_in[3];
    const float* a_conv_b  = (const float*)d_in[4];
    const float* a_xproj_w = (const float*)d_in[5];
    const float* a_dt_w    = (const float*)d_in[6];
    const float* a_dt_b    = (const float*)d_in[7];
    const float* a_A_log   = (const float*)d_in[8];
    const float* a_D       = (const float*)d_in[9];
    const float* a_out_w   = (const float*)d_in[10];
    const float* c_in_w    = (const float*)d_in[11];
    const float* c_conv_w  = (const float*)d_in[12];
    const float* c_conv_b  = (const float*)d_in[13];
    const float* c_xproj_w = (const float*)d_in[14];
    const float* c_dt_w    = (const float*)d_in[15];
    const float* c_dt_b    = (const float*)d_in[16];
    const float* c_A_log   = (const float*)d_in[17];
    const float* c_D       = (const float*)d_in[18];
    const float* c_out_w   = (const float*)d_in[19];

    float* fout = (float*)d_out;

    float* ws = (float*)d_ws;
    float* h_buf  = ws;                      // 1,605,632 floats
    float* S      = ws + 1605632;
    // stage A
    float* score  = S;                       // 802,816 (reused as score2)
    float* xz_a   = S + 802816;              // 3,211,264
    float* xi_a   = S + 4014080;             // 1,605,632 (scan in-place)
    float* xdbl_a = S + 5619712;             // 319,488
    float* dt_a   = S + 5939200;             // 1,605,632
    float* sbuf   = S + 7544832;             // 8,192
    int*   indb   = (int*)(S + 7553024);     // 784
    float* vtopk  = S + 7553808;             // 784
    // stage C (aliases stage A region)
    float* xz_c   = S;                       // 6,422,528
    float* xi_c   = S + 6422528;             // 3,211,264 (scan in-place)
    float* xdbl_c = S + 9633792;             // 125,440
    float* dt_c   = S + 9759232;             // 3,211,264
    // bf16 scratch (beyond the fp32 region: base float offset 14,576,128)
    unsigned short* cwbf  = (unsigned short*)(ws + 14576128);          // 16,777,216 bf16
    unsigned short* h_bf  = (unsigned short*)(ws + 14576128 + 8388608);// 1,835,008 bf16
    unsigned short* yz_bf = (unsigned short*)(ws + 14576128 + 9306112);// 3,670,016 bf16
    // split-K partials:
    //  - step 1 (stage A): bf16 region is dead until step 11 -> reuse it.
    //    8 chunks x 802,816 = 6,422,528 floats at 14,576,128..20,998,656.
    float* CpartS1 = ws + 14576128;
    //  - step 13 (stage C): upper half of cwbf region is dead between
    //    mfma_gemm #11 and tpose_cvt #16. 16 x 784 x 160 floats.
    float* Cpart  = ws + 18770432;
    // total ws: 25,717,248 floats ~= 103 MB

    // ===== stage A (fp32) =====
    // 1. score[b] = kf[b]^T @ imgF^T : split-K x8 (2048 blocks vs 256)
    gemm64_skb<true, true><<<dim3(16, 2, 64), 256, 0, stream>>>(
        kf, imgF, CpartS1,
        1024, 98, 2048, 1024, 2048, 256, 8,
        (long)2048 * 1024, 0L, (long)1024 * 98, 802816L);
    sk_reduce<<<3136, 256, 0, stream>>>(CpartS1, score, 802816L, 8);

    gemm64<false, false, false, 0><<<dim3(128, 7, 1), 256, 0, stream>>>(
        score, a_in_w, xz_a, nullptr, nullptr, 8192, 392, 98, 98, 392, 392, 0, 0L, 0L, 0L);
    conv_silu_kernel<<<6272, 256, 0, stream>>>(xz_a, a_conv_w, a_conv_b, xi_a, 8, 1024, 196, 392);
    gemm64<false, false, false, 0><<<dim3(128, 1, 1), 256, 0, stream>>>(
        xi_a, a_xproj_w, xdbl_a, nullptr, nullptr, 8192, 39, 196, 196, 39, 39, 0, 0L, 0L, 0L);
    gemm64<false, false, false, 1><<<dim3(128, 4, 1), 256, 0, stream>>>(
        xdbl_a, a_dt_w, dt_a, nullptr, a_dt_b, 8192, 196, 7, 39, 196, 196, 0, 0L, 0L, 0L);
    scan_kernel<64><<<dim3(13, 8, 1), 256, 0, stream>>>(
        xi_a, dt_a, xdbl_a, a_A_log, a_D, xi_a, 196, 1024, 39, 7, 23);
    gemm64<false, false, true, 0><<<dim3(128, 2, 1), 256, 0, stream>>>(
        xi_a, a_out_w, score, xz_a + 196, nullptr, 8192, 98, 196, 196, 98, 98, 392, 0L, 0L, 0L);
    mean_softmax_kernel<<<8, 256, 0, stream>>>(score, sbuf);
    topk_select_kernel<<<8, 256, 0, stream>>>(sbuf, indb, vtopk);
    gather_kernel<<<dim3(98, 8, 1), 256, 0, stream>>>(imgF, kf, indb, vtopk, h_buf);

    // ===== stage C =====
    // 11. xz_c = h @ c_in_w  (bf16 MFMA)
    tpose_cvt<<<dim3(256, 64, 1), 256, 0, stream>>>(c_in_w, cwbf, 2048, 8192);
    cvt_pad<<<1792, 256, 0, stream>>>(h_buf, h_bf, 784, 896, 2048);
    mfma_gemm<<<dim3(7, 64, 1), 256, 0, stream>>>(h_bf, cwbf, xz_c, 784, 8192, 2048, 8192);

    // 12. conv + silu -> xi_c
    conv_silu_kernel<<<12544, 256, 0, stream>>>(xz_c, c_conv_w, c_conv_b, xi_c, 8, 98, 4096, 8192);

    // 13. xdbl_c = xi_c @ c_xproj_w (fp32, split-K x16)
    gemm64_sk<<<dim3(13, 3, 16), 256, 0, stream>>>(
        xi_c, c_xproj_w, Cpart, 784, 160, 4096, 4096, 160, 256);
    sk_reduce<<<490, 256, 0, stream>>>(Cpart, xdbl_c, 125440L, 16);

    // 14. dt_c = softplus(xdbl_c[:, :128] @ c_dt_w + c_dt_b) (fp32)
    gemm64<false, false, false, 1><<<dim3(13, 64, 1), 256, 0, stream>>>(
        xdbl_c, c_dt_w, dt_c, nullptr, c_dt_b, 784, 4096, 128, 160, 4096, 4096, 0, 0L, 0L, 0L);

    // 15. selective scan C (in-place)
    scan_kernel<98><<<dim3(256, 8, 1), 256, 0, stream>>>(
        xi_c, dt_c, xdbl_c, c_A_log, c_D, xi_c, 4096, 98, 160, 128, 144);

    // 16. out = (y_c * silu(z_c)) @ c_out_w  (bf16 MFMA, direct to d_out)
    gate_cvt<<<3584, 256, 0, stream>>>(xi_c, xz_c + 4096, yz_bf, 784, 896, 4096, 8192);
    tpose_cvt<<<dim3(64, 128, 1), 256, 0, stream>>>(c_out_w, cwbf, 4096, 2048);
    mfma_gemm<<<dim3(7, 16, 1), 256, 0, stream>>>(yz_bf, cwbf, fout, 784, 2048, 4096, 2048);
}

// Round 7
// 1133.387 us; speedup vs baseline: 1.8332x; 1.0600x over previous
//
#include <hip/hip_runtime.h>
#include <hip/hip_bf16.h>
#include <math.h>

typedef __attribute__((ext_vector_type(8))) short short8;
typedef __attribute__((ext_vector_type(4))) float floatx4;

// ---------- helpers ----------
__device__ __forceinline__ float siluf(float x) {
    float e = __expf(-fabsf(x));
    float s = (x >= 0.f) ? 1.f / (1.f + e) : e / (1.f + e);
    return x * s;
}
__device__ __forceinline__ float softplusf(float x) {
    if (x > 20.f) return x;
    if (x < -20.f) return __expf(x);
    return log1pf(__expf(x));
}
__device__ __forceinline__ unsigned short f2b(float v) {
    __hip_bfloat16 b = __float2bfloat16(v);
    unsigned short u;
    __builtin_memcpy(&u, &b, 2);
    return u;
}

// ---------- generic 64x64 tiled GEMM (fp32) — LDS rows padded to 68 ----------
// (64-stride rows put consecutive-kk staging writes all in one bank: 16-way
//  conflict. 68 = bank stride 4, rows stay 16B-aligned.)
template<bool ACOL, bool BCOL, bool AMUL, int EPI>
__global__ __launch_bounds__(256) void gemm64(
    const float* __restrict__ A, const float* __restrict__ Bw, float* __restrict__ C,
    const float* __restrict__ A2, const float* __restrict__ bias,
    int M, int N, int K, int lda, int ldb, int ldc, int lda2,
    long batA, long batB, long batC)
{
    __shared__ __align__(16) float As[16][68];
    __shared__ __align__(16) float Bs[16][68];
    int tx = threadIdx.x;
    int m0 = blockIdx.x * 64, n0 = blockIdx.y * 64;
    A += blockIdx.z * batA; Bw += blockIdx.z * batB; C += blockIdx.z * batC;
    int tm = tx >> 4, tn = tx & 15;
    float acc[4][4] = {};
    for (int k0 = 0; k0 < K; k0 += 16) {
        for (int i = tx; i < 1024; i += 256) {
            int mm, kk;
            if (ACOL) { mm = i & 63; kk = i >> 6; } else { kk = i & 15; mm = i >> 4; }
            int m = m0 + mm, k = k0 + kk;
            float v = 0.f;
            if (m < M && k < K) {
                long ia = ACOL ? ((long)k * lda + m) : ((long)m * lda + k);
                v = A[ia];
                if (AMUL) v *= siluf(A2[(long)m * lda2 + k]);
            }
            As[kk][mm] = v;
        }
        for (int i = tx; i < 1024; i += 256) {
            int nn, kk;
            if (BCOL) { kk = i & 15; nn = i >> 4; } else { nn = i & 63; kk = i >> 6; }
            int n = n0 + nn, k = k0 + kk;
            float v = 0.f;
            if (n < N && k < K) {
                long ib = BCOL ? ((long)n * ldb + k) : ((long)k * ldb + n);
                v = Bw[ib];
            }
            Bs[kk][nn] = v;
        }
        __syncthreads();
#pragma unroll
        for (int kk = 0; kk < 16; ++kk) {
            float4 av = *(const float4*)&As[kk][tm * 4];
            float4 bv = *(const float4*)&Bs[kk][tn * 4];
            float a[4] = {av.x, av.y, av.z, av.w};
            float b[4] = {bv.x, bv.y, bv.z, bv.w};
#pragma unroll
            for (int i = 0; i < 4; i++)
#pragma unroll
                for (int j = 0; j < 4; j++) acc[i][j] += a[i] * b[j];
        }
        __syncthreads();
    }
#pragma unroll
    for (int i = 0; i < 4; i++) {
        int m = m0 + tm * 4 + i;
        if (m >= M) continue;
#pragma unroll
        for (int j = 0; j < 4; j++) {
            int n = n0 + tn * 4 + j;
            if (n >= N) continue;
            float v = acc[i][j];
            if (EPI == 1) v = softplusf(v + bias[n]);
            C[(long)m * ldc + n] = v;
        }
    }
}

// ---------- split-K fp32 GEMM (row-major A,B): Cpart[z] = partial ----------
__global__ __launch_bounds__(256) void gemm64_sk(
    const float* __restrict__ A, const float* __restrict__ Bw, float* __restrict__ Cpart,
    int M, int N, int K, int lda, int ldb, int kch)
{
    __shared__ __align__(16) float As[16][68];
    __shared__ __align__(16) float Bs[16][68];
    int tx = threadIdx.x;
    int m0 = blockIdx.x * 64, n0 = blockIdx.y * 64;
    int kbeg = blockIdx.z * kch;
    int kend = min(kbeg + kch, K);
    Cpart += (long)blockIdx.z * M * N;
    int tm = tx >> 4, tn = tx & 15;
    float acc[4][4] = {};
    for (int k0 = kbeg; k0 < kend; k0 += 16) {
        for (int i = tx; i < 1024; i += 256) {
            int kk = i & 15, mm = i >> 4;
            int m = m0 + mm, k = k0 + kk;
            As[kk][mm] = (m < M && k < kend) ? A[(long)m * lda + k] : 0.f;
        }
        for (int i = tx; i < 1024; i += 256) {
            int nn = i & 63, kk = i >> 6;
            int n = n0 + nn, k = k0 + kk;
            Bs[kk][nn] = (n < N && k < kend) ? Bw[(long)k * ldb + n] : 0.f;
        }
        __syncthreads();
#pragma unroll
        for (int kk = 0; kk < 16; ++kk) {
            float4 av = *(const float4*)&As[kk][tm * 4];
            float4 bv = *(const float4*)&Bs[kk][tn * 4];
            float a[4] = {av.x, av.y, av.z, av.w};
            float b[4] = {bv.x, bv.y, bv.z, bv.w};
#pragma unroll
            for (int i = 0; i < 4; i++)
#pragma unroll
                for (int j = 0; j < 4; j++) acc[i][j] += a[i] * b[j];
        }
        __syncthreads();
    }
#pragma unroll
    for (int i = 0; i < 4; i++) {
        int m = m0 + tm * 4 + i;
        if (m >= M) continue;
#pragma unroll
        for (int j = 0; j < 4; j++) {
            int n = n0 + tn * 4 + j;
            if (n >= N) continue;
            Cpart[(long)m * N + n] = acc[i][j];
        }
    }
}

// ---------- step-1 specialized split-K GEMM ----------
// score[b][q][n] = sum_d kf[b][d][q] * img[n][d]; M=1024,N=98,K=2048.
// grid (16, 2, 64): z = bz*8 + kz, kch=256. Vectorized float4 staging,
// padded LDS. FMA order per thread identical to generic path.
__global__ __launch_bounds__(256) void gemm_s1(
    const float* __restrict__ kf, const float* __restrict__ img,
    float* __restrict__ Cpart)
{
    __shared__ __align__(16) float As[16][68];
    __shared__ __align__(16) float Bs[16][68];
    int tx = threadIdx.x;
    int m0 = blockIdx.x * 64, n0 = blockIdx.y * 64;
    int bz = blockIdx.z >> 3, kz = blockIdx.z & 7;
    const float* A = kf + (long)bz * 2048 * 1024;      // [d][q] col-major A
    float* Cp = Cpart + (long)kz * 802816 + (long)bz * 100352;
    int kbeg = kz * 256;
    int tm = tx >> 4, tn = tx & 15;
    int akk = tx >> 4, amq = (tx & 15) * 4;            // A stage: 16 k-rows x 64 m
    int bnn = tx >> 2, bkq = (tx & 3) * 4;             // B stage: 64 n-rows x 16 k
    bool bvalid = (n0 + bnn) < 98;
    const float* Bp = img + (long)(n0 + bnn) * 2048;
    float acc[4][4] = {};
    for (int k0 = kbeg; k0 < kbeg + 256; k0 += 16) {
        float4 av = *(const float4*)&A[(long)(k0 + akk) * 1024 + m0 + amq];
        float4 bv = bvalid ? *(const float4*)&Bp[k0 + bkq] : (float4){0.f, 0.f, 0.f, 0.f};
        __syncthreads();
        *(float4*)&As[akk][amq] = av;
        Bs[bkq + 0][bnn] = bv.x;
        Bs[bkq + 1][bnn] = bv.y;
        Bs[bkq + 2][bnn] = bv.z;
        Bs[bkq + 3][bnn] = bv.w;
        __syncthreads();
#pragma unroll
        for (int kk = 0; kk < 16; ++kk) {
            float4 a4 = *(const float4*)&As[kk][tm * 4];
            float4 b4 = *(const float4*)&Bs[kk][tn * 4];
            float a[4] = {a4.x, a4.y, a4.z, a4.w};
            float b[4] = {b4.x, b4.y, b4.z, b4.w};
#pragma unroll
            for (int i = 0; i < 4; i++)
#pragma unroll
                for (int j = 0; j < 4; j++) acc[i][j] += a[i] * b[j];
        }
    }
#pragma unroll
    for (int i = 0; i < 4; i++) {
        int m = m0 + tm * 4 + i;
#pragma unroll
        for (int j = 0; j < 4; j++) {
            int n = n0 + tn * 4 + j;
            if (n < 98) Cp[(long)m * 98 + n] = acc[i][j];
        }
    }
}

// ---------- sum nz split-K partial buffers ----------
__global__ void sk_reduce(const float* __restrict__ Cpart, float* __restrict__ C,
                          long len, int nz)
{
    long i = (long)blockIdx.x * 256 + threadIdx.x;
    if (i >= len) return;
    float s = 0.f;
    for (int z = 0; z < nz; z++) s += Cpart[(long)z * len + i];
    C[i] = s;
}

// ---------- bf16 MFMA GEMM: C[M,N] = A[M,K] x B[K,N] ----------
// Abf: bf16 bits, row-major [Mpad][K] (Mpad >= gridDim.x*128)
// Bbf: bf16 bits, B TRANSPOSED layout [N][K]
// 128x128 tile, 4 waves (2x2 of 64x64), 16x16x32 MFMA, BK=32.
__global__ __launch_bounds__(256) void mfma_gemm(
    const unsigned short* __restrict__ Abf, const unsigned short* __restrict__ Bbf,
    float* __restrict__ C, int M, int N, int K, int ldc)
{
    __shared__ __align__(16) short As[128 * 40];   // +8 pad kills ds_read conflicts
    __shared__ __align__(16) short Bs[128 * 40];
    int tid = threadIdx.x;
    int m0 = blockIdx.x * 128, n0 = blockIdx.y * 128;
    int w = tid >> 6, l = tid & 63;
    int wm = (w >> 1) * 64, wn = (w & 1) * 64;
    int lr = l & 15, lq = l >> 4;
    int row0 = tid >> 2, kc = (tid & 3) * 8;
    floatx4 acc[4][4];
#pragma unroll
    for (int i = 0; i < 4; i++)
#pragma unroll
        for (int j = 0; j < 4; j++) acc[i][j] = (floatx4){0.f, 0.f, 0.f, 0.f};
    const unsigned short* Ap  = Abf + (long)(m0 + row0) * K + kc;
    const unsigned short* Ap2 = Abf + (long)(m0 + row0 + 64) * K + kc;
    const unsigned short* Bp  = Bbf + (long)(n0 + row0) * K + kc;
    const unsigned short* Bp2 = Bbf + (long)(n0 + row0 + 64) * K + kc;
    for (int k0 = 0; k0 < K; k0 += 32) {
        uint4 a0 = *(const uint4*)(Ap + k0);
        uint4 a1 = *(const uint4*)(Ap2 + k0);
        uint4 b0 = *(const uint4*)(Bp + k0);
        uint4 b1 = *(const uint4*)(Bp2 + k0);
        __syncthreads();
        *(uint4*)&As[row0 * 40 + kc] = a0;
        *(uint4*)&As[(row0 + 64) * 40 + kc] = a1;
        *(uint4*)&Bs[row0 * 40 + kc] = b0;
        *(uint4*)&Bs[(row0 + 64) * 40 + kc] = b1;
        __syncthreads();
        short8 af[4], bfr[4];
#pragma unroll
        for (int i = 0; i < 4; i++) af[i]  = *(const short8*)&As[(wm + i * 16 + lr) * 40 + lq * 8];
#pragma unroll
        for (int i = 0; i < 4; i++) bfr[i] = *(const short8*)&Bs[(wn + i * 16 + lr) * 40 + lq * 8];
#pragma unroll
        for (int i = 0; i < 4; i++)
#pragma unroll
            for (int j = 0; j < 4; j++)
                acc[i][j] = __builtin_amdgcn_mfma_f32_16x16x32_bf16(af[i], bfr[j], acc[i][j], 0, 0, 0);
    }
#pragma unroll
    for (int i = 0; i < 4; i++) {
#pragma unroll
        for (int r = 0; r < 4; r++) {
            int m = m0 + wm + i * 16 + lq * 4 + r;
            if (m >= M) continue;
#pragma unroll
            for (int j = 0; j < 4; j++)
                C[(long)m * ldc + n0 + wn + j * 16 + lr] = acc[i][j][r];
        }
    }
}

// ---------- fp32 [K][N] -> bf16-bits transposed [N][K] (tiled via LDS) ----------
__global__ __launch_bounds__(256) void tpose_cvt(const float* __restrict__ src,
                                                 unsigned short* __restrict__ dst,
                                                 int K, int N)
{
    __shared__ float t[32][33];
    int n0 = blockIdx.x * 32, k0 = blockIdx.y * 32;
    int tid = threadIdx.x;
    int r = tid >> 3, c4 = (tid & 7) * 4;
    float4 v = *(const float4*)&src[(long)(k0 + r) * N + n0 + c4];
    t[r][c4] = v.x; t[r][c4 + 1] = v.y; t[r][c4 + 2] = v.z; t[r][c4 + 3] = v.w;
    __syncthreads();
    ushort4 o;
    o.x = f2b(t[c4][r]);
    o.y = f2b(t[c4 + 1][r]);
    o.z = f2b(t[c4 + 2][r]);
    o.w = f2b(t[c4 + 3][r]);
    *(ushort4*)&dst[(long)(n0 + r) * K + k0 + c4] = o;
}

// ---------- fp32 [M][C] -> bf16-bits [Mpad][C] (zero pad rows >= M) ----------
__global__ void cvt_pad(const float* __restrict__ src, unsigned short* __restrict__ dst,
                        int M, int Mpad, int C)
{
    long i4 = ((long)blockIdx.x * 256 + threadIdx.x) * 4;
    if (i4 >= (long)Mpad * C) return;
    int row = (int)(i4 / C);
    ushort4 o = {0, 0, 0, 0};
    if (row < M) {
        float4 v = *(const float4*)&src[i4];
        o.x = f2b(v.x); o.y = f2b(v.y); o.z = f2b(v.z); o.w = f2b(v.w);
    }
    *(ushort4*)&dst[i4] = o;
}

// ---------- y * silu(z) -> bf16-bits [Mpad][C] ----------
__global__ void gate_cvt(const float* __restrict__ y, const float* __restrict__ z,
                         unsigned short* __restrict__ dst, int M, int Mpad, int C, int ldz)
{
    long i4 = ((long)blockIdx.x * 256 + threadIdx.x) * 4;
    if (i4 >= (long)Mpad * C) return;
    int row = (int)(i4 / C);
    int col = (int)(i4 - (long)row * C);
    ushort4 o = {0, 0, 0, 0};
    if (row < M) {
        float4 yv = *(const float4*)&y[i4];
        float4 zv = *(const float4*)&z[(long)row * ldz + col];
        o.x = f2b(yv.x * siluf(zv.x));
        o.y = f2b(yv.y * siluf(zv.y));
        o.z = f2b(yv.z * siluf(zv.z));
        o.w = f2b(yv.w * siluf(zv.w));
    }
    *(ushort4*)&dst[i4] = o;
}

// ---------- causal depthwise conv (k=4) + bias + silu ----------
__global__ void conv_silu_kernel(const float* __restrict__ xz, const float* __restrict__ w,
                                 const float* __restrict__ bias, float* __restrict__ out,
                                 int Bn, int L, int din, int ldx)
{
    int idx = blockIdx.x * 256 + threadIdx.x;
    int total = Bn * L * din;
    if (idx >= total) return;
    int c = idx % din;
    int r = idx / din;
    int t = r % L;
    int b = r / L;
    float acc = bias[c];
#pragma unroll
    for (int i = 0; i < 4; i++) {
        int tt = t - 3 + i;
        if (tt >= 0) acc += w[c * 4 + i] * xz[((long)(b * L + tt)) * ldx + c];
    }
    out[idx] = siluf(acc);
}

// ---------- selective scan (u/y may alias) ----------
// 16-step groups; shuffle-reduce trees issued LEVEL-MAJOR so the 16
// independent DS ops per level pipeline their ~120cy latency (tree-major
// order serialized: ~500 cy/step measured r5). Butterfly add order per
// tree unchanged -> bit-identical results.
template<int T>
__global__ __launch_bounds__(256) void scan_kernel(
    const float* u, const float* dt,
    const float* xdbl, const float* __restrict__ A_log,
    const float* __restrict__ Dp, float* y,
    int din, int L, int xld, int boff, int coff)
{
    __shared__ float Bc[T][16], Cc[T][16], dtc[T][16], uc[T][16], yc[T][16];
    int tx = threadIdx.x;
    int dl = tx >> 4;
    int n = tx & 15;
    int dbase = blockIdx.x * 16;
    int dg = dbase + dl;
    int b = blockIdx.y;
    bool act = dg < din;
    float Acoef = act ? -__expf(A_log[dg * 16 + n]) : 0.f;
    float Dv = act ? Dp[dg] : 0.f;
    int nvalid = min(16, din - dbase);
    float h = 0.f;
    for (int c0 = 0; c0 < L; c0 += T) {
        int tcnt = min(T, L - c0);
        for (int i = tx; i < T * 16; i += 256) {
            int tt = i >> 4, c = i & 15;
            if (tt < tcnt) {
                long row = (long)b * L + c0 + tt;
                float uv = 0.f, dv = 0.f;
                if (c < nvalid) { uv = u[row * din + dbase + c]; dv = dt[row * din + dbase + c]; }
                uc[tt][c] = uv; dtc[tt][c] = dv;
                Bc[tt][c] = xdbl[row * xld + boff + c];
                Cc[tt][c] = xdbl[row * xld + coff + c];
            }
        }
        __syncthreads();
        int tt = 0;
        for (; tt + 16 <= tcnt; tt += 16) {
            float pbuf[16];
#pragma unroll
            for (int q = 0; q < 16; q++) {
                float dtv = dtc[tt + q][dl];
                float uv = uc[tt + q][dl];
                float dA = __expf(dtv * Acoef);
                h = dA * h + (dtv * uv) * Bc[tt + q][n];
                pbuf[q] = h * Cc[tt + q][n];
            }
            // level-major butterfly: 16 independent shuffles per level
#pragma unroll
            for (int q = 0; q < 16; q++) pbuf[q] += __shfl_xor(pbuf[q], 1);
#pragma unroll
            for (int q = 0; q < 16; q++) pbuf[q] += __shfl_xor(pbuf[q], 2);
#pragma unroll
            for (int q = 0; q < 16; q++) pbuf[q] += __shfl_xor(pbuf[q], 4);
#pragma unroll
            for (int q = 0; q < 16; q++) pbuf[q] += __shfl_xor(pbuf[q], 8);
            if (n == 0) {
#pragma unroll
                for (int q = 0; q < 16; q++)
                    yc[tt + q][dl] = pbuf[q] + Dv * uc[tt + q][dl];
            }
        }
        for (; tt < tcnt; ++tt) {
            float dtv = dtc[tt][dl];
            float uv = uc[tt][dl];
            float dA = __expf(dtv * Acoef);
            h = dA * h + (dtv * uv) * Bc[tt][n];
            float p = h * Cc[tt][n];
            p += __shfl_xor(p, 1);
            p += __shfl_xor(p, 2);
            p += __shfl_xor(p, 4);
            p += __shfl_xor(p, 8);
            if (n == 0) yc[tt][dl] = p + Dv * uv;
        }
        __syncthreads();
        for (int i = tx; i < tcnt * 16; i += 256) {
            int tt2 = i >> 4, c = i & 15;
            if (c < nvalid) y[((long)b * L + c0 + tt2) * din + dbase + c] = yc[tt2][c];
        }
        __syncthreads();
    }
}

// ---------- mean over n (98) + softmax over k (1024), per batch ----------
// coalesced: stage 32 rows (32x98 contiguous floats) in LDS per pass
__global__ __launch_bounds__(256) void mean_softmax_kernel(const float* __restrict__ sc2,
                                                           float* __restrict__ s)
{
    __shared__ float tile[32 * 98];
    __shared__ float vals[1024];
    __shared__ float red[256];
    int b = blockIdx.x, tx = threadIdx.x;
    for (int k0 = 0; k0 < 1024; k0 += 32) {
        const float* base = sc2 + ((long)b * 1024 + k0) * 98;
        for (int i = tx; i < 32 * 98; i += 256) tile[i] = base[i];
        __syncthreads();
        int row = tx >> 3, ln = tx & 7;
        float sum = 0.f;
        for (int nn = ln; nn < 98; nn += 8) sum += tile[row * 98 + nn];
        sum += __shfl_xor(sum, 1);
        sum += __shfl_xor(sum, 2);
        sum += __shfl_xor(sum, 4);
        if (ln == 0) vals[k0 + row] = sum * (1.f / 98.f);
        __syncthreads();
    }
    float mx = -1e30f;
    for (int k = tx; k < 1024; k += 256) mx = fmaxf(mx, vals[k]);
    red[tx] = mx; __syncthreads();
    for (int st = 128; st > 0; st >>= 1) { if (tx < st) red[tx] = fmaxf(red[tx], red[tx + st]); __syncthreads(); }
    mx = red[0]; __syncthreads();
    float lsum = 0.f;
    for (int k = tx; k < 1024; k += 256) { float e = __expf(vals[k] - mx); vals[k] = e; lsum += e; }
    red[tx] = lsum; __syncthreads();
    for (int st = 128; st > 0; st >>= 1) { if (tx < st) red[tx] += red[tx + st]; __syncthreads(); }
    float inv = 1.f / red[0];
    __syncthreads();
    for (int k = tx; k < 1024; k += 256) s[(long)b * 1024 + k] = vals[k] * inv;
}

// ---------- top-98 sequential selection (jax tie semantics) ----------
__global__ __launch_bounds__(256) void topk_select_kernel(const float* __restrict__ s,
                                                          int* __restrict__ ind,
                                                          float* __restrict__ vtopk)
{
    __shared__ unsigned long long arr[1024];
    __shared__ unsigned long long red[256];
    int b = blockIdx.x, tx = threadIdx.x;
    for (int k = tx; k < 1024; k += 256) {
        float v = s[b * 1024 + k];
        unsigned u = __float_as_uint(v);
        u = (u & 0x80000000u) ? ~u : (u | 0x80000000u);
        arr[k] = ((unsigned long long)u << 32) | (unsigned)(~k);
    }
    __syncthreads();
    for (int r = 0; r < 98; ++r) {
        unsigned long long m = 0ull;
        for (int k = tx; k < 1024; k += 256) m = (arr[k] > m) ? arr[k] : m;
        red[tx] = m; __syncthreads();
        for (int st = 128; st > 0; st >>= 1) {
            if (tx < st && red[tx + st] > red[tx]) red[tx] = red[tx + st];
            __syncthreads();
        }
        unsigned long long best = red[0];
        if (tx == 0) {
            unsigned lo = (unsigned)(best & 0xffffffffu);
            int kidx = (int)(~lo);
            unsigned ub = (unsigned)(best >> 32);
            unsigned fb = (ub & 0x80000000u) ? (ub ^ 0x80000000u) : ~ub;
            ind[b * 98 + r] = kidx;
            vtopk[b * 98 + r] = __uint_as_float(fb);
            arr[kidx] = 0ull;
        }
        __syncthreads();
    }
}

// ---------- gather: h[b,j,:] = img[j,:] + kf[b,:,ind]*v ----------
__global__ void gather_kernel(const float* __restrict__ img, const float* __restrict__ kf,
                              const int* __restrict__ ind, const float* __restrict__ vtopk,
                              float* __restrict__ h)
{
    int j = blockIdx.x, b = blockIdx.y;
    int kidx = ind[b * 98 + j];
    float v = vtopk[b * 98 + j];
    long hbase = ((long)b * 98 + j) * 2048;
    const float* kfb = kf + (long)b * 2048 * 1024 + kidx;
    for (int d = threadIdx.x; d < 2048; d += 256)
        h[hbase + d] = img[(long)j * 2048 + d] + kfb[(long)d * 1024] * v;
}

// ---------- host launch ----------
extern "C" void kernel_launch(void* const* d_in, const int* in_sizes, int n_in,
                              void* d_out, int out_size, void* d_ws, size_t ws_size,
                              hipStream_t stream)
{
    const float* imgF      = (const float*)d_in[0];
    const float* kf        = (const float*)d_in[1];
    const float* a_in_w    = (const float*)d_in[2];
    const float* a_conv_w  = (const float*)d_in[3];
    const float* a_conv_b  = (const float*)d_in[4];
    const float* a_xproj_w = (const float*)d_in[5];
    const float* a_dt_w    = (const float*)d_in[6];
    const float* a_dt_b    = (const float*)d_in[7];
    const float* a_A_log   = (const float*)d_in[8];
    const float* a_D       = (const float*)d_in[9];
    const float* a_out_w   = (const float*)d_in[10];
    const float* c_in_w    = (const float*)d_in[11];
    const float* c_conv_w  = (const float*)d_in[12];
    const float* c_conv_b  = (const float*)d_in[13];
    const float* c_xproj_w = (const float*)d_in[14];
    const float* c_dt_w    = (const float*)d_in[15];
    const float* c_dt_b    = (const float*)d_in[16];
    const float* c_A_log   = (const float*)d_in[17];
    const float* c_D       = (const float*)d_in[18];
    const float* c_out_w   = (const float*)d_in[19];

    float* fout = (float*)d_out;

    float* ws = (float*)d_ws;
    float* h_buf  = ws;                      // 1,605,632 floats
    float* S      = ws + 1605632;
    // stage A
    float* score  = S;                       // 802,816 (reused as score2)
    float* xz_a   = S + 802816;              // 3,211,264
    float* xi_a   = S + 4014080;             // 1,605,632 (scan in-place)
    float* xdbl_a = S + 5619712;             // 319,488
    float* dt_a   = S + 5939200;             // 1,605,632
    float* sbuf   = S + 7544832;             // 8,192
    int*   indb   = (int*)(S + 7553024);     // 784
    float* vtopk  = S + 7553808;             // 784
    // stage C (aliases stage A region)
    float* xz_c   = S;                       // 6,422,528
    float* xi_c   = S + 6422528;             // 3,211,264 (scan in-place)
    float* xdbl_c = S + 9633792;             // 125,440
    float* dt_c   = S + 9759232;             // 3,211,264
    // bf16 scratch (beyond the fp32 region: base float offset 14,576,128)
    unsigned short* cwbf  = (unsigned short*)(ws + 14576128);          // 16,777,216 bf16
    unsigned short* h_bf  = (unsigned short*)(ws + 14576128 + 8388608);// 1,835,008 bf16
    unsigned short* yz_bf = (unsigned short*)(ws + 14576128 + 9306112);// 3,670,016 bf16
    // split-K partials:
    //  - step 1 (stage A): bf16 region is dead until step 11 -> reuse it.
    //    8 chunks x 802,816 = 6,422,528 floats at 14,576,128..20,998,656.
    float* CpartS1 = ws + 14576128;
    //  - step 13 (stage C): upper half of cwbf region is dead between
    //    mfma_gemm #11 and tpose_cvt #16. 16 x 784 x 160 floats.
    float* Cpart  = ws + 18770432;
    // total ws: 25,717,248 floats ~= 103 MB

    // ===== stage A (fp32) =====
    // 1. score[b] = kf[b]^T @ imgF^T : specialized split-K x8 (2048 blocks)
    gemm_s1<<<dim3(16, 2, 64), 256, 0, stream>>>(kf, imgF, CpartS1);
    sk_reduce<<<3136, 256, 0, stream>>>(CpartS1, score, 802816L, 8);

    gemm64<false, false, false, 0><<<dim3(128, 7, 1), 256, 0, stream>>>(
        score, a_in_w, xz_a, nullptr, nullptr, 8192, 392, 98, 98, 392, 392, 0, 0L, 0L, 0L);
    conv_silu_kernel<<<6272, 256, 0, stream>>>(xz_a, a_conv_w, a_conv_b, xi_a, 8, 1024, 196, 392);
    gemm64<false, false, false, 0><<<dim3(128, 1, 1), 256, 0, stream>>>(
        xi_a, a_xproj_w, xdbl_a, nullptr, nullptr, 8192, 39, 196, 196, 39, 39, 0, 0L, 0L, 0L);
    gemm64<false, false, false, 1><<<dim3(128, 4, 1), 256, 0, stream>>>(
        xdbl_a, a_dt_w, dt_a, nullptr, a_dt_b, 8192, 196, 7, 39, 196, 196, 0, 0L, 0L, 0L);
    scan_kernel<64><<<dim3(13, 8, 1), 256, 0, stream>>>(
        xi_a, dt_a, xdbl_a, a_A_log, a_D, xi_a, 196, 1024, 39, 7, 23);
    gemm64<false, false, true, 0><<<dim3(128, 2, 1), 256, 0, stream>>>(
        xi_a, a_out_w, score, xz_a + 196, nullptr, 8192, 98, 196, 196, 98, 98, 392, 0L, 0L, 0L);
    mean_softmax_kernel<<<8, 256, 0, stream>>>(score, sbuf);
    topk_select_kernel<<<8, 256, 0, stream>>>(sbuf, indb, vtopk);
    gather_kernel<<<dim3(98, 8, 1), 256, 0, stream>>>(imgF, kf, indb, vtopk, h_buf);

    // ===== stage C =====
    // 11. xz_c = h @ c_in_w  (bf16 MFMA)
    tpose_cvt<<<dim3(256, 64, 1), 256, 0, stream>>>(c_in_w, cwbf, 2048, 8192);
    cvt_pad<<<1792, 256, 0, stream>>>(h_buf, h_bf, 784, 896, 2048);
    mfma_gemm<<<dim3(7, 64, 1), 256, 0, stream>>>(h_bf, cwbf, xz_c, 784, 8192, 2048, 8192);

    // 12. conv + silu -> xi_c
    conv_silu_kernel<<<12544, 256, 0, stream>>>(xz_c, c_conv_w, c_conv_b, xi_c, 8, 98, 4096, 8192);

    // 13. xdbl_c = xi_c @ c_xproj_w (fp32, split-K x16)
    gemm64_sk<<<dim3(13, 3, 16), 256, 0, stream>>>(
        xi_c, c_xproj_w, Cpart, 784, 160, 4096, 4096, 160, 256);
    sk_reduce<<<490, 256, 0, stream>>>(Cpart, xdbl_c, 125440L, 16);

    // 14. dt_c = softplus(xdbl_c[:, :128] @ c_dt_w + c_dt_b) (fp32)
    gemm64<false, false, false, 1><<<dim3(13, 64, 1), 256, 0, stream>>>(
        xdbl_c, c_dt_w, dt_c, nullptr, c_dt_b, 784, 4096, 128, 160, 4096, 4096, 0, 0L, 0L, 0L);

    // 15. selective scan C (in-place)
    scan_kernel<98><<<dim3(256, 8, 1), 256, 0, stream>>>(
        xi_c, dt_c, xdbl_c, c_A_log, c_D, xi_c, 4096, 98, 160, 128, 144);

    // 16. out = (y_c * silu(z_c)) @ c_out_w  (bf16 MFMA, direct to d_out)
    gate_cvt<<<3584, 256, 0, stream>>>(xi_c, xz_c + 4096, yz_bf, 784, 896, 4096, 8192);
    tpose_cvt<<<dim3(64, 128, 1), 256, 0, stream>>>(c_out_w, cwbf, 4096, 2048);
    mfma_gemm<<<dim3(7, 16, 1), 256, 0, stream>>>(yz_bf, cwbf, fout, 784, 2048, 4096, 2048);
}

// Round 8
// 1064.702 us; speedup vs baseline: 1.9515x; 1.0645x over previous
//
#include <hip/hip_runtime.h>
#include <hip/hip_bf16.h>
#include <math.h>

typedef __attribute__((ext_vector_type(8))) short short8;
typedef __attribute__((ext_vector_type(4))) float floatx4;

// ---------- helpers ----------
__device__ __forceinline__ float siluf(float x) {
    float e = __expf(-fabsf(x));
    float s = (x >= 0.f) ? 1.f / (1.f + e) : e / (1.f + e);
    return x * s;
}
__device__ __forceinline__ float softplusf(float x) {
    if (x > 20.f) return x;
    if (x < -20.f) return __expf(x);
    return log1pf(__expf(x));
}
__device__ __forceinline__ unsigned short f2b(float v) {
    __hip_bfloat16 b = __float2bfloat16(v);
    unsigned short u;
    __builtin_memcpy(&u, &b, 2);
    return u;
}
// DPP lane-add: x += x[neighbor] per 16-lane row, VALU-speed (no LDS pipe).
template<int CTRL>
__device__ __forceinline__ float dpp_add(float x) {
    int yi = __builtin_amdgcn_mov_dpp(__float_as_int(x), CTRL, 0xF, 0xF, true);
    return x + __int_as_float(yi);
}
// Sum over the 16-lane row (n-dim). For lane (n==0) the add order is
// bit-identical to the xor1/2/4/8 butterfly: ((p0+p1)+(p2+p3)) per quad,
// then (s0+s1)+(s2+s3) via row_ror:4 + row_ror:8.
__device__ __forceinline__ float row16_sum(float p) {
    p = dpp_add<0xB1>(p);    // quad_perm [1,0,3,2]  : xor 1
    p = dpp_add<0x4E>(p);    // quad_perm [2,3,0,1]  : xor 2
    p = dpp_add<0x124>(p);   // row_ror:4
    p = dpp_add<0x128>(p);   // row_ror:8
    return p;
}

// ---------- generic 64x64 tiled GEMM (fp32) — LDS rows padded to 68 ----------
// (64-stride rows put consecutive-kk staging writes all in one bank: 16-way
//  conflict. 68 = bank stride 4, rows stay 16B-aligned.)
template<bool ACOL, bool BCOL, bool AMUL, int EPI>
__global__ __launch_bounds__(256) void gemm64(
    const float* __restrict__ A, const float* __restrict__ Bw, float* __restrict__ C,
    const float* __restrict__ A2, const float* __restrict__ bias,
    int M, int N, int K, int lda, int ldb, int ldc, int lda2,
    long batA, long batB, long batC)
{
    __shared__ __align__(16) float As[16][68];
    __shared__ __align__(16) float Bs[16][68];
    int tx = threadIdx.x;
    int m0 = blockIdx.x * 64, n0 = blockIdx.y * 64;
    A += blockIdx.z * batA; Bw += blockIdx.z * batB; C += blockIdx.z * batC;
    int tm = tx >> 4, tn = tx & 15;
    float acc[4][4] = {};
    for (int k0 = 0; k0 < K; k0 += 16) {
        for (int i = tx; i < 1024; i += 256) {
            int mm, kk;
            if (ACOL) { mm = i & 63; kk = i >> 6; } else { kk = i & 15; mm = i >> 4; }
            int m = m0 + mm, k = k0 + kk;
            float v = 0.f;
            if (m < M && k < K) {
                long ia = ACOL ? ((long)k * lda + m) : ((long)m * lda + k);
                v = A[ia];
                if (AMUL) v *= siluf(A2[(long)m * lda2 + k]);
            }
            As[kk][mm] = v;
        }
        for (int i = tx; i < 1024; i += 256) {
            int nn, kk;
            if (BCOL) { kk = i & 15; nn = i >> 4; } else { nn = i & 63; kk = i >> 6; }
            int n = n0 + nn, k = k0 + kk;
            float v = 0.f;
            if (n < N && k < K) {
                long ib = BCOL ? ((long)n * ldb + k) : ((long)k * ldb + n);
                v = Bw[ib];
            }
            Bs[kk][nn] = v;
        }
        __syncthreads();
#pragma unroll
        for (int kk = 0; kk < 16; ++kk) {
            float4 av = *(const float4*)&As[kk][tm * 4];
            float4 bv = *(const float4*)&Bs[kk][tn * 4];
            float a[4] = {av.x, av.y, av.z, av.w};
            float b[4] = {bv.x, bv.y, bv.z, bv.w};
#pragma unroll
            for (int i = 0; i < 4; i++)
#pragma unroll
                for (int j = 0; j < 4; j++) acc[i][j] += a[i] * b[j];
        }
        __syncthreads();
    }
#pragma unroll
    for (int i = 0; i < 4; i++) {
        int m = m0 + tm * 4 + i;
        if (m >= M) continue;
#pragma unroll
        for (int j = 0; j < 4; j++) {
            int n = n0 + tn * 4 + j;
            if (n >= N) continue;
            float v = acc[i][j];
            if (EPI == 1) v = softplusf(v + bias[n]);
            C[(long)m * ldc + n] = v;
        }
    }
}

// ---------- split-K fp32 GEMM (row-major A,B): Cpart[z] = partial ----------
__global__ __launch_bounds__(256) void gemm64_sk(
    const float* __restrict__ A, const float* __restrict__ Bw, float* __restrict__ Cpart,
    int M, int N, int K, int lda, int ldb, int kch)
{
    __shared__ __align__(16) float As[16][68];
    __shared__ __align__(16) float Bs[16][68];
    int tx = threadIdx.x;
    int m0 = blockIdx.x * 64, n0 = blockIdx.y * 64;
    int kbeg = blockIdx.z * kch;
    int kend = min(kbeg + kch, K);
    Cpart += (long)blockIdx.z * M * N;
    int tm = tx >> 4, tn = tx & 15;
    float acc[4][4] = {};
    for (int k0 = kbeg; k0 < kend; k0 += 16) {
        for (int i = tx; i < 1024; i += 256) {
            int kk = i & 15, mm = i >> 4;
            int m = m0 + mm, k = k0 + kk;
            As[kk][mm] = (m < M && k < kend) ? A[(long)m * lda + k] : 0.f;
        }
        for (int i = tx; i < 1024; i += 256) {
            int nn = i & 63, kk = i >> 6;
            int n = n0 + nn, k = k0 + kk;
            Bs[kk][nn] = (n < N && k < kend) ? Bw[(long)k * ldb + n] : 0.f;
        }
        __syncthreads();
#pragma unroll
        for (int kk = 0; kk < 16; ++kk) {
            float4 av = *(const float4*)&As[kk][tm * 4];
            float4 bv = *(const float4*)&Bs[kk][tn * 4];
            float a[4] = {av.x, av.y, av.z, av.w};
            float b[4] = {bv.x, bv.y, bv.z, bv.w};
#pragma unroll
            for (int i = 0; i < 4; i++)
#pragma unroll
                for (int j = 0; j < 4; j++) acc[i][j] += a[i] * b[j];
        }
        __syncthreads();
    }
#pragma unroll
    for (int i = 0; i < 4; i++) {
        int m = m0 + tm * 4 + i;
        if (m >= M) continue;
#pragma unroll
        for (int j = 0; j < 4; j++) {
            int n = n0 + tn * 4 + j;
            if (n >= N) continue;
            Cpart[(long)m * N + n] = acc[i][j];
        }
    }
}

// ---------- step-1 specialized split-K GEMM ----------
// score[b][q][n] = sum_d kf[b][d][q] * img[n][d]; M=1024,N=98,K=2048.
// grid (16, 2, 64): z = bz*8 + kz, kch=256. Vectorized float4 staging,
// padded LDS. FMA order per thread identical to generic path.
__global__ __launch_bounds__(256) void gemm_s1(
    const float* __restrict__ kf, const float* __restrict__ img,
    float* __restrict__ Cpart)
{
    __shared__ __align__(16) float As[16][68];
    __shared__ __align__(16) float Bs[16][68];
    int tx = threadIdx.x;
    int m0 = blockIdx.x * 64, n0 = blockIdx.y * 64;
    int bz = blockIdx.z >> 3, kz = blockIdx.z & 7;
    const float* A = kf + (long)bz * 2048 * 1024;      // [d][q] col-major A
    float* Cp = Cpart + (long)kz * 802816 + (long)bz * 100352;
    int kbeg = kz * 256;
    int tm = tx >> 4, tn = tx & 15;
    int akk = tx >> 4, amq = (tx & 15) * 4;            // A stage: 16 k-rows x 64 m
    int bnn = tx >> 2, bkq = (tx & 3) * 4;             // B stage: 64 n-rows x 16 k
    bool bvalid = (n0 + bnn) < 98;
    const float* Bp = img + (long)(n0 + bnn) * 2048;
    float acc[4][4] = {};
    for (int k0 = kbeg; k0 < kbeg + 256; k0 += 16) {
        float4 av = *(const float4*)&A[(long)(k0 + akk) * 1024 + m0 + amq];
        float4 bv = bvalid ? *(const float4*)&Bp[k0 + bkq] : (float4){0.f, 0.f, 0.f, 0.f};
        __syncthreads();
        *(float4*)&As[akk][amq] = av;
        Bs[bkq + 0][bnn] = bv.x;
        Bs[bkq + 1][bnn] = bv.y;
        Bs[bkq + 2][bnn] = bv.z;
        Bs[bkq + 3][bnn] = bv.w;
        __syncthreads();
#pragma unroll
        for (int kk = 0; kk < 16; ++kk) {
            float4 a4 = *(const float4*)&As[kk][tm * 4];
            float4 b4 = *(const float4*)&Bs[kk][tn * 4];
            float a[4] = {a4.x, a4.y, a4.z, a4.w};
            float b[4] = {b4.x, b4.y, b4.z, b4.w};
#pragma unroll
            for (int i = 0; i < 4; i++)
#pragma unroll
                for (int j = 0; j < 4; j++) acc[i][j] += a[i] * b[j];
        }
    }
#pragma unroll
    for (int i = 0; i < 4; i++) {
        int m = m0 + tm * 4 + i;
#pragma unroll
        for (int j = 0; j < 4; j++) {
            int n = n0 + tn * 4 + j;
            if (n < 98) Cp[(long)m * 98 + n] = acc[i][j];
        }
    }
}

// ---------- sum nz split-K partial buffers ----------
__global__ void sk_reduce(const float* __restrict__ Cpart, float* __restrict__ C,
                          long len, int nz)
{
    long i = (long)blockIdx.x * 256 + threadIdx.x;
    if (i >= len) return;
    float s = 0.f;
    for (int z = 0; z < nz; z++) s += Cpart[(long)z * len + i];
    C[i] = s;
}

// ---------- bf16 MFMA GEMM: C[M,N] = A[M,K] x B[K,N] ----------
// Abf: bf16 bits, row-major [Mpad][K] (Mpad >= gridDim.x*128)
// Bbf: bf16 bits, B TRANSPOSED layout [N][K]
// 128x128 tile, 4 waves (2x2 of 64x64), 16x16x32 MFMA, BK=32.
__global__ __launch_bounds__(256) void mfma_gemm(
    const unsigned short* __restrict__ Abf, const unsigned short* __restrict__ Bbf,
    float* __restrict__ C, int M, int N, int K, int ldc)
{
    __shared__ __align__(16) short As[128 * 40];   // +8 pad kills ds_read conflicts
    __shared__ __align__(16) short Bs[128 * 40];
    int tid = threadIdx.x;
    int m0 = blockIdx.x * 128, n0 = blockIdx.y * 128;
    int w = tid >> 6, l = tid & 63;
    int wm = (w >> 1) * 64, wn = (w & 1) * 64;
    int lr = l & 15, lq = l >> 4;
    int row0 = tid >> 2, kc = (tid & 3) * 8;
    floatx4 acc[4][4];
#pragma unroll
    for (int i = 0; i < 4; i++)
#pragma unroll
        for (int j = 0; j < 4; j++) acc[i][j] = (floatx4){0.f, 0.f, 0.f, 0.f};
    const unsigned short* Ap  = Abf + (long)(m0 + row0) * K + kc;
    const unsigned short* Ap2 = Abf + (long)(m0 + row0 + 64) * K + kc;
    const unsigned short* Bp  = Bbf + (long)(n0 + row0) * K + kc;
    const unsigned short* Bp2 = Bbf + (long)(n0 + row0 + 64) * K + kc;
    for (int k0 = 0; k0 < K; k0 += 32) {
        uint4 a0 = *(const uint4*)(Ap + k0);
        uint4 a1 = *(const uint4*)(Ap2 + k0);
        uint4 b0 = *(const uint4*)(Bp + k0);
        uint4 b1 = *(const uint4*)(Bp2 + k0);
        __syncthreads();
        *(uint4*)&As[row0 * 40 + kc] = a0;
        *(uint4*)&As[(row0 + 64) * 40 + kc] = a1;
        *(uint4*)&Bs[row0 * 40 + kc] = b0;
        *(uint4*)&Bs[(row0 + 64) * 40 + kc] = b1;
        __syncthreads();
        short8 af[4], bfr[4];
#pragma unroll
        for (int i = 0; i < 4; i++) af[i]  = *(const short8*)&As[(wm + i * 16 + lr) * 40 + lq * 8];
#pragma unroll
        for (int i = 0; i < 4; i++) bfr[i] = *(const short8*)&Bs[(wn + i * 16 + lr) * 40 + lq * 8];
#pragma unroll
        for (int i = 0; i < 4; i++)
#pragma unroll
            for (int j = 0; j < 4; j++)
                acc[i][j] = __builtin_amdgcn_mfma_f32_16x16x32_bf16(af[i], bfr[j], acc[i][j], 0, 0, 0);
    }
#pragma unroll
    for (int i = 0; i < 4; i++) {
#pragma unroll
        for (int r = 0; r < 4; r++) {
            int m = m0 + wm + i * 16 + lq * 4 + r;
            if (m >= M) continue;
#pragma unroll
            for (int j = 0; j < 4; j++)
                C[(long)m * ldc + n0 + wn + j * 16 + lr] = acc[i][j][r];
        }
    }
}

// ---------- fp32 [K][N] -> bf16-bits transposed [N][K] (tiled via LDS) ----------
__global__ __launch_bounds__(256) void tpose_cvt(const float* __restrict__ src,
                                                 unsigned short* __restrict__ dst,
                                                 int K, int N)
{
    __shared__ float t[32][33];
    int n0 = blockIdx.x * 32, k0 = blockIdx.y * 32;
    int tid = threadIdx.x;
    int r = tid >> 3, c4 = (tid & 7) * 4;
    float4 v = *(const float4*)&src[(long)(k0 + r) * N + n0 + c4];
    t[r][c4] = v.x; t[r][c4 + 1] = v.y; t[r][c4 + 2] = v.z; t[r][c4 + 3] = v.w;
    __syncthreads();
    ushort4 o;
    o.x = f2b(t[c4][r]);
    o.y = f2b(t[c4 + 1][r]);
    o.z = f2b(t[c4 + 2][r]);
    o.w = f2b(t[c4 + 3][r]);
    *(ushort4*)&dst[(long)(n0 + r) * K + k0 + c4] = o;
}

// ---------- fp32 [M][C] -> bf16-bits [Mpad][C] (zero pad rows >= M) ----------
__global__ void cvt_pad(const float* __restrict__ src, unsigned short* __restrict__ dst,
                        int M, int Mpad, int C)
{
    long i4 = ((long)blockIdx.x * 256 + threadIdx.x) * 4;
    if (i4 >= (long)Mpad * C) return;
    int row = (int)(i4 / C);
    ushort4 o = {0, 0, 0, 0};
    if (row < M) {
        float4 v = *(const float4*)&src[i4];
        o.x = f2b(v.x); o.y = f2b(v.y); o.z = f2b(v.z); o.w = f2b(v.w);
    }
    *(ushort4*)&dst[i4] = o;
}

// ---------- y * silu(z) -> bf16-bits [Mpad][C] ----------
__global__ void gate_cvt(const float* __restrict__ y, const float* __restrict__ z,
                         unsigned short* __restrict__ dst, int M, int Mpad, int C, int ldz)
{
    long i4 = ((long)blockIdx.x * 256 + threadIdx.x) * 4;
    if (i4 >= (long)Mpad * C) return;
    int row = (int)(i4 / C);
    int col = (int)(i4 - (long)row * C);
    ushort4 o = {0, 0, 0, 0};
    if (row < M) {
        float4 yv = *(const float4*)&y[i4];
        float4 zv = *(const float4*)&z[(long)row * ldz + col];
        o.x = f2b(yv.x * siluf(zv.x));
        o.y = f2b(yv.y * siluf(zv.y));
        o.z = f2b(yv.z * siluf(zv.z));
        o.w = f2b(yv.w * siluf(zv.w));
    }
    *(ushort4*)&dst[i4] = o;
}

// ---------- causal depthwise conv (k=4) + bias + silu ----------
__global__ void conv_silu_kernel(const float* __restrict__ xz, const float* __restrict__ w,
                                 const float* __restrict__ bias, float* __restrict__ out,
                                 int Bn, int L, int din, int ldx)
{
    int idx = blockIdx.x * 256 + threadIdx.x;
    int total = Bn * L * din;
    if (idx >= total) return;
    int c = idx % din;
    int r = idx / din;
    int t = r % L;
    int b = r / L;
    float acc = bias[c];
#pragma unroll
    for (int i = 0; i < 4; i++) {
        int tt = t - 3 + i;
        if (tt >= 0) acc += w[c * 4 + i] * xz[((long)(b * L + tt)) * ldx + c];
    }
    out[idx] = siluf(acc);
}

// ---------- selective scan (u/y may alias) ----------
// 16-step groups; n-reduce done with DPP (quad_perm + row_ror) entirely on
// the VALU pipe — no LDS-pipe shuffle latency (ds_swizzle ~120cy was the
// critical path at 1 wave/SIMD occupancy). Lane n==0's add order is
// bit-identical to the original xor butterfly.
template<int T>
__global__ __launch_bounds__(256) void scan_kernel(
    const float* u, const float* dt,
    const float* xdbl, const float* __restrict__ A_log,
    const float* __restrict__ Dp, float* y,
    int din, int L, int xld, int boff, int coff)
{
    __shared__ float Bc[T][16], Cc[T][16], dtc[T][16], uc[T][16], yc[T][16];
    int tx = threadIdx.x;
    int dl = tx >> 4;
    int n = tx & 15;
    int dbase = blockIdx.x * 16;
    int dg = dbase + dl;
    int b = blockIdx.y;
    bool act = dg < din;
    float Acoef = act ? -__expf(A_log[dg * 16 + n]) : 0.f;
    float Dv = act ? Dp[dg] : 0.f;
    int nvalid = min(16, din - dbase);
    float h = 0.f;
    for (int c0 = 0; c0 < L; c0 += T) {
        int tcnt = min(T, L - c0);
        for (int i = tx; i < T * 16; i += 256) {
            int tt = i >> 4, c = i & 15;
            if (tt < tcnt) {
                long row = (long)b * L + c0 + tt;
                float uv = 0.f, dv = 0.f;
                if (c < nvalid) { uv = u[row * din + dbase + c]; dv = dt[row * din + dbase + c]; }
                uc[tt][c] = uv; dtc[tt][c] = dv;
                Bc[tt][c] = xdbl[row * xld + boff + c];
                Cc[tt][c] = xdbl[row * xld + coff + c];
            }
        }
        __syncthreads();
        int tt = 0;
        for (; tt + 16 <= tcnt; tt += 16) {
            float pbuf[16];
#pragma unroll
            for (int q = 0; q < 16; q++) {
                float dtv = dtc[tt + q][dl];
                float uv = uc[tt + q][dl];
                float dA = __expf(dtv * Acoef);
                h = dA * h + (dtv * uv) * Bc[tt + q][n];
                pbuf[q] = h * Cc[tt + q][n];
            }
#pragma unroll
            for (int q = 0; q < 16; q++) pbuf[q] = row16_sum(pbuf[q]);
            if (n == 0) {
#pragma unroll
                for (int q = 0; q < 16; q++)
                    yc[tt + q][dl] = pbuf[q] + Dv * uc[tt + q][dl];
            }
        }
        for (; tt < tcnt; ++tt) {
            float dtv = dtc[tt][dl];
            float uv = uc[tt][dl];
            float dA = __expf(dtv * Acoef);
            h = dA * h + (dtv * uv) * Bc[tt][n];
            float p = row16_sum(h * Cc[tt][n]);
            if (n == 0) yc[tt][dl] = p + Dv * uv;
        }
        __syncthreads();
        for (int i = tx; i < tcnt * 16; i += 256) {
            int tt2 = i >> 4, c = i & 15;
            if (c < nvalid) y[((long)b * L + c0 + tt2) * din + dbase + c] = yc[tt2][c];
        }
        __syncthreads();
    }
}

// ---------- mean over n (98) + softmax over k (1024), per batch ----------
// coalesced: stage 32 rows (32x98 contiguous floats) in LDS per pass
__global__ __launch_bounds__(256) void mean_softmax_kernel(const float* __restrict__ sc2,
                                                           float* __restrict__ s)
{
    __shared__ float tile[32 * 98];
    __shared__ float vals[1024];
    __shared__ float red[256];
    int b = blockIdx.x, tx = threadIdx.x;
    for (int k0 = 0; k0 < 1024; k0 += 32) {
        const float* base = sc2 + ((long)b * 1024 + k0) * 98;
        for (int i = tx; i < 32 * 98; i += 256) tile[i] = base[i];
        __syncthreads();
        int row = tx >> 3, ln = tx & 7;
        float sum = 0.f;
        for (int nn = ln; nn < 98; nn += 8) sum += tile[row * 98 + nn];
        sum += __shfl_xor(sum, 1);
        sum += __shfl_xor(sum, 2);
        sum += __shfl_xor(sum, 4);
        if (ln == 0) vals[k0 + row] = sum * (1.f / 98.f);
        __syncthreads();
    }
    float mx = -1e30f;
    for (int k = tx; k < 1024; k += 256) mx = fmaxf(mx, vals[k]);
    red[tx] = mx; __syncthreads();
    for (int st = 128; st > 0; st >>= 1) { if (tx < st) red[tx] = fmaxf(red[tx], red[tx + st]); __syncthreads(); }
    mx = red[0]; __syncthreads();
    float lsum = 0.f;
    for (int k = tx; k < 1024; k += 256) { float e = __expf(vals[k] - mx); vals[k] = e; lsum += e; }
    red[tx] = lsum; __syncthreads();
    for (int st = 128; st > 0; st >>= 1) { if (tx < st) red[tx] += red[tx + st]; __syncthreads(); }
    float inv = 1.f / red[0];
    __syncthreads();
    for (int k = tx; k < 1024; k += 256) s[(long)b * 1024 + k] = vals[k] * inv;
}

// ---------- top-98 sequential selection (jax tie semantics) ----------
__global__ __launch_bounds__(256) void topk_select_kernel(const float* __restrict__ s,
                                                          int* __restrict__ ind,
                                                          float* __restrict__ vtopk)
{
    __shared__ unsigned long long arr[1024];
    __shared__ unsigned long long red[256];
    int b = blockIdx.x, tx = threadIdx.x;
    for (int k = tx; k < 1024; k += 256) {
        float v = s[b * 1024 + k];
        unsigned u = __float_as_uint(v);
        u = (u & 0x80000000u) ? ~u : (u | 0x80000000u);
        arr[k] = ((unsigned long long)u << 32) | (unsigned)(~k);
    }
    __syncthreads();
    for (int r = 0; r < 98; ++r) {
        unsigned long long m = 0ull;
        for (int k = tx; k < 1024; k += 256) m = (arr[k] > m) ? arr[k] : m;
        red[tx] = m; __syncthreads();
        for (int st = 128; st > 0; st >>= 1) {
            if (tx < st && red[tx + st] > red[tx]) red[tx] = red[tx + st];
            __syncthreads();
        }
        unsigned long long best = red[0];
        if (tx == 0) {
            unsigned lo = (unsigned)(best & 0xffffffffu);
            int kidx = (int)(~lo);
            unsigned ub = (unsigned)(best >> 32);
            unsigned fb = (ub & 0x80000000u) ? (ub ^ 0x80000000u) : ~ub;
            ind[b * 98 + r] = kidx;
            vtopk[b * 98 + r] = __uint_as_float(fb);
            arr[kidx] = 0ull;
        }
        __syncthreads();
    }
}

// ---------- gather: h[b,j,:] = img[j,:] + kf[b,:,ind]*v ----------
__global__ void gather_kernel(const float* __restrict__ img, const float* __restrict__ kf,
                              const int* __restrict__ ind, const float* __restrict__ vtopk,
                              float* __restrict__ h)
{
    int j = blockIdx.x, b = blockIdx.y;
    int kidx = ind[b * 98 + j];
    float v = vtopk[b * 98 + j];
    long hbase = ((long)b * 98 + j) * 2048;
    const float* kfb = kf + (long)b * 2048 * 1024 + kidx;
    for (int d = threadIdx.x; d < 2048; d += 256)
        h[hbase + d] = img[(long)j * 2048 + d] + kfb[(long)d * 1024] * v;
}

// ---------- host launch ----------
extern "C" void kernel_launch(void* const* d_in, const int* in_sizes, int n_in,
                              void* d_out, int out_size, void* d_ws, size_t ws_size,
                              hipStream_t stream)
{
    const float* imgF      = (const float*)d_in[0];
    const float* kf        = (const float*)d_in[1];
    const float* a_in_w    = (const float*)d_in[2];
    const float* a_conv_w  = (const float*)d_in[3];
    const float* a_conv_b  = (const float*)d_in[4];
    const float* a_xproj_w = (const float*)d_in[5];
    const float* a_dt_w    = (const float*)d_in[6];
    const float* a_dt_b    = (const float*)d_in[7];
    const float* a_A_log   = (const float*)d_in[8];
    const float* a_D       = (const float*)d_in[9];
    const float* a_out_w   = (const float*)d_in[10];
    const float* c_in_w    = (const float*)d_in[11];
    const float* c_conv_w  = (const float*)d_in[12];
    const float* c_conv_b  = (const float*)d_in[13];
    const float* c_xproj_w = (const float*)d_in[14];
    const float* c_dt_w    = (const float*)d_in[15];
    const float* c_dt_b    = (const float*)d_in[16];
    const float* c_A_log   = (const float*)d_in[17];
    const float* c_D       = (const float*)d_in[18];
    const float* c_out_w   = (const float*)d_in[19];

    float* fout = (float*)d_out;

    float* ws = (float*)d_ws;
    float* h_buf  = ws;                      // 1,605,632 floats
    float* S      = ws + 1605632;
    // stage A
    float* score  = S;                       // 802,816 (reused as score2)
    float* xz_a   = S + 802816;              // 3,211,264
    float* xi_a   = S + 4014080;             // 1,605,632 (scan in-place)
    float* xdbl_a = S + 5619712;             // 319,488
    float* dt_a   = S + 5939200;             // 1,605,632
    float* sbuf   = S + 7544832;             // 8,192
    int*   indb   = (int*)(S + 7553024);     // 784
    float* vtopk  = S + 7553808;             // 784
    // stage C (aliases stage A region)
    float* xz_c   = S;                       // 6,422,528
    float* xi_c   = S + 6422528;             // 3,211,264 (scan in-place)
    float* xdbl_c = S + 9633792;             // 125,440
    float* dt_c   = S + 9759232;             // 3,211,264
    // bf16 scratch (beyond the fp32 region: base float offset 14,576,128)
    unsigned short* cwbf  = (unsigned short*)(ws + 14576128);          // 16,777,216 bf16
    unsigned short* h_bf  = (unsigned short*)(ws + 14576128 + 8388608);// 1,835,008 bf16
    unsigned short* yz_bf = (unsigned short*)(ws + 14576128 + 9306112);// 3,670,016 bf16
    // split-K partials:
    //  - step 1 (stage A): bf16 region is dead until step 11 -> reuse it.
    //    8 chunks x 802,816 = 6,422,528 floats at 14,576,128..20,998,656.
    float* CpartS1 = ws + 14576128;
    //  - step 13 (stage C): upper half of cwbf region is dead between
    //    mfma_gemm #11 and tpose_cvt #16. 16 x 784 x 160 floats.
    float* Cpart  = ws + 18770432;
    // total ws: 25,717,248 floats ~= 103 MB

    // ===== stage A (fp32) =====
    // 1. score[b] = kf[b]^T @ imgF^T : specialized split-K x8 (2048 blocks)
    gemm_s1<<<dim3(16, 2, 64), 256, 0, stream>>>(kf, imgF, CpartS1);
    sk_reduce<<<3136, 256, 0, stream>>>(CpartS1, score, 802816L, 8);

    gemm64<false, false, false, 0><<<dim3(128, 7, 1), 256, 0, stream>>>(
        score, a_in_w, xz_a, nullptr, nullptr, 8192, 392, 98, 98, 392, 392, 0, 0L, 0L, 0L);
    conv_silu_kernel<<<6272, 256, 0, stream>>>(xz_a, a_conv_w, a_conv_b, xi_a, 8, 1024, 196, 392);
    gemm64<false, false, false, 0><<<dim3(128, 1, 1), 256, 0, stream>>>(
        xi_a, a_xproj_w, xdbl_a, nullptr, nullptr, 8192, 39, 196, 196, 39, 39, 0, 0L, 0L, 0L);
    gemm64<false, false, false, 1><<<dim3(128, 4, 1), 256, 0, stream>>>(
        xdbl_a, a_dt_w, dt_a, nullptr, a_dt_b, 8192, 196, 7, 39, 196, 196, 0, 0L, 0L, 0L);
    scan_kernel<64><<<dim3(13, 8, 1), 256, 0, stream>>>(
        xi_a, dt_a, xdbl_a, a_A_log, a_D, xi_a, 196, 1024, 39, 7, 23);
    gemm64<false, false, true, 0><<<dim3(128, 2, 1), 256, 0, stream>>>(
        xi_a, a_out_w, score, xz_a + 196, nullptr, 8192, 98, 196, 196, 98, 98, 392, 0L, 0L, 0L);
    mean_softmax_kernel<<<8, 256, 0, stream>>>(score, sbuf);
    topk_select_kernel<<<8, 256, 0, stream>>>(sbuf, indb, vtopk);
    gather_kernel<<<dim3(98, 8, 1), 256, 0, stream>>>(imgF, kf, indb, vtopk, h_buf);

    // ===== stage C =====
    // 11. xz_c = h @ c_in_w  (bf16 MFMA)
    tpose_cvt<<<dim3(256, 64, 1), 256, 0, stream>>>(c_in_w, cwbf, 2048, 8192);
    cvt_pad<<<1792, 256, 0, stream>>>(h_buf, h_bf, 784, 896, 2048);
    mfma_gemm<<<dim3(7, 64, 1), 256, 0, stream>>>(h_bf, cwbf, xz_c, 784, 8192, 2048, 8192);

    // 12. conv + silu -> xi_c
    conv_silu_kernel<<<12544, 256, 0, stream>>>(xz_c, c_conv_w, c_conv_b, xi_c, 8, 98, 4096, 8192);

    // 13. xdbl_c = xi_c @ c_xproj_w (fp32, split-K x16)
    gemm64_sk<<<dim3(13, 3, 16), 256, 0, stream>>>(
        xi_c, c_xproj_w, Cpart, 784, 160, 4096, 4096, 160, 256);
    sk_reduce<<<490, 256, 0, stream>>>(Cpart, xdbl_c, 125440L, 16);

    // 14. dt_c = softplus(xdbl_c[:, :128] @ c_dt_w + c_dt_b) (fp32)
    gemm64<false, false, false, 1><<<dim3(13, 64, 1), 256, 0, stream>>>(
        xdbl_c, c_dt_w, dt_c, nullptr, c_dt_b, 784, 4096, 128, 160, 4096, 4096, 0, 0L, 0L, 0L);

    // 15. selective scan C (in-place)
    scan_kernel<98><<<dim3(256, 8, 1), 256, 0, stream>>>(
        xi_c, dt_c, xdbl_c, c_A_log, c_D, xi_c, 4096, 98, 160, 128, 144);

    // 16. out = (y_c * silu(z_c)) @ c_out_w  (bf16 MFMA, direct to d_out)
    gate_cvt<<<3584, 256, 0, stream>>>(xi_c, xz_c + 4096, yz_bf, 784, 896, 4096, 8192);
    tpose_cvt<<<dim3(64, 128, 1), 256, 0, stream>>>(c_out_w, cwbf, 4096, 2048);
    mfma_gemm<<<dim3(7, 16, 1), 256, 0, stream>>>(yz_bf, cwbf, fout, 784, 2048, 4096, 2048);
}

// Round 9
// 956.124 us; speedup vs baseline: 2.1731x; 1.1136x over previous
//
#include <hip/hip_runtime.h>
#include <hip/hip_bf16.h>
#include <math.h>

typedef __attribute__((ext_vector_type(8))) short short8;
typedef __attribute__((ext_vector_type(4))) float floatx4;

// ---------- helpers ----------
__device__ __forceinline__ float siluf(float x) {
    float e = __expf(-fabsf(x));
    float s = (x >= 0.f) ? 1.f / (1.f + e) : e / (1.f + e);
    return x * s;
}
__device__ __forceinline__ float softplusf(float x) {
    if (x > 20.f) return x;
    if (x < -20.f) return __expf(x);
    return log1pf(__expf(x));
}
__device__ __forceinline__ unsigned short f2b(float v) {
    __hip_bfloat16 b = __float2bfloat16(v);
    unsigned short u;
    __builtin_memcpy(&u, &b, 2);
    return u;
}
// DPP lane-add: x += x[neighbor] per 16-lane row, VALU-speed (no LDS pipe).
template<int CTRL>
__device__ __forceinline__ float dpp_add(float x) {
    int yi = __builtin_amdgcn_mov_dpp(__float_as_int(x), CTRL, 0xF, 0xF, true);
    return x + __int_as_float(yi);
}
// Sum over the 16-lane row (n-dim). For lane (n==0) the add order is
// bit-identical to the xor1/2/4/8 butterfly: ((p0+p1)+(p2+p3)) per quad,
// then (s0+s1)+(s2+s3) via row_ror:4 + row_ror:8.
__device__ __forceinline__ float row16_sum(float p) {
    p = dpp_add<0xB1>(p);    // quad_perm [1,0,3,2]  : xor 1
    p = dpp_add<0x4E>(p);    // quad_perm [2,3,0,1]  : xor 2
    p = dpp_add<0x124>(p);   // row_ror:4
    p = dpp_add<0x128>(p);   // row_ror:8
    return p;
}

// ---------- generic 64x64 tiled GEMM (fp32) — LDS rows padded to 68 ----------
// (64-stride rows put consecutive-kk staging writes all in one bank: 16-way
//  conflict. 68 = bank stride 4, rows stay 16B-aligned.)
template<bool ACOL, bool BCOL, bool AMUL, int EPI>
__global__ __launch_bounds__(256) void gemm64(
    const float* __restrict__ A, const float* __restrict__ Bw, float* __restrict__ C,
    const float* __restrict__ A2, const float* __restrict__ bias,
    int M, int N, int K, int lda, int ldb, int ldc, int lda2,
    long batA, long batB, long batC)
{
    __shared__ __align__(16) float As[16][68];
    __shared__ __align__(16) float Bs[16][68];
    int tx = threadIdx.x;
    int m0 = blockIdx.x * 64, n0 = blockIdx.y * 64;
    A += blockIdx.z * batA; Bw += blockIdx.z * batB; C += blockIdx.z * batC;
    int tm = tx >> 4, tn = tx & 15;
    float acc[4][4] = {};
    for (int k0 = 0; k0 < K; k0 += 16) {
        for (int i = tx; i < 1024; i += 256) {
            int mm, kk;
            if (ACOL) { mm = i & 63; kk = i >> 6; } else { kk = i & 15; mm = i >> 4; }
            int m = m0 + mm, k = k0 + kk;
            float v = 0.f;
            if (m < M && k < K) {
                long ia = ACOL ? ((long)k * lda + m) : ((long)m * lda + k);
                v = A[ia];
                if (AMUL) v *= siluf(A2[(long)m * lda2 + k]);
            }
            As[kk][mm] = v;
        }
        for (int i = tx; i < 1024; i += 256) {
            int nn, kk;
            if (BCOL) { kk = i & 15; nn = i >> 4; } else { nn = i & 63; kk = i >> 6; }
            int n = n0 + nn, k = k0 + kk;
            float v = 0.f;
            if (n < N && k < K) {
                long ib = BCOL ? ((long)n * ldb + k) : ((long)k * ldb + n);
                v = Bw[ib];
            }
            Bs[kk][nn] = v;
        }
        __syncthreads();
#pragma unroll
        for (int kk = 0; kk < 16; ++kk) {
            float4 av = *(const float4*)&As[kk][tm * 4];
            float4 bv = *(const float4*)&Bs[kk][tn * 4];
            float a[4] = {av.x, av.y, av.z, av.w};
            float b[4] = {bv.x, bv.y, bv.z, bv.w};
#pragma unroll
            for (int i = 0; i < 4; i++)
#pragma unroll
                for (int j = 0; j < 4; j++) acc[i][j] += a[i] * b[j];
        }
        __syncthreads();
    }
#pragma unroll
    for (int i = 0; i < 4; i++) {
        int m = m0 + tm * 4 + i;
        if (m >= M) continue;
#pragma unroll
        for (int j = 0; j < 4; j++) {
            int n = n0 + tn * 4 + j;
            if (n >= N) continue;
            float v = acc[i][j];
            if (EPI == 1) v = softplusf(v + bias[n]);
            C[(long)m * ldc + n] = v;
        }
    }
}

// ---------- split-K fp32 GEMM (row-major A,B): Cpart[z] = partial ----------
__global__ __launch_bounds__(256) void gemm64_sk(
    const float* __restrict__ A, const float* __restrict__ Bw, float* __restrict__ Cpart,
    int M, int N, int K, int lda, int ldb, int kch)
{
    __shared__ __align__(16) float As[16][68];
    __shared__ __align__(16) float Bs[16][68];
    int tx = threadIdx.x;
    int m0 = blockIdx.x * 64, n0 = blockIdx.y * 64;
    int kbeg = blockIdx.z * kch;
    int kend = min(kbeg + kch, K);
    Cpart += (long)blockIdx.z * M * N;
    int tm = tx >> 4, tn = tx & 15;
    float acc[4][4] = {};
    for (int k0 = kbeg; k0 < kend; k0 += 16) {
        for (int i = tx; i < 1024; i += 256) {
            int kk = i & 15, mm = i >> 4;
            int m = m0 + mm, k = k0 + kk;
            As[kk][mm] = (m < M && k < kend) ? A[(long)m * lda + k] : 0.f;
        }
        for (int i = tx; i < 1024; i += 256) {
            int nn = i & 63, kk = i >> 6;
            int n = n0 + nn, k = k0 + kk;
            Bs[kk][nn] = (n < N && k < kend) ? Bw[(long)k * ldb + n] : 0.f;
        }
        __syncthreads();
#pragma unroll
        for (int kk = 0; kk < 16; ++kk) {
            float4 av = *(const float4*)&As[kk][tm * 4];
            float4 bv = *(const float4*)&Bs[kk][tn * 4];
            float a[4] = {av.x, av.y, av.z, av.w};
            float b[4] = {bv.x, bv.y, bv.z, bv.w};
#pragma unroll
            for (int i = 0; i < 4; i++)
#pragma unroll
                for (int j = 0; j < 4; j++) acc[i][j] += a[i] * b[j];
        }
        __syncthreads();
    }
#pragma unroll
    for (int i = 0; i < 4; i++) {
        int m = m0 + tm * 4 + i;
        if (m >= M) continue;
#pragma unroll
        for (int j = 0; j < 4; j++) {
            int n = n0 + tn * 4 + j;
            if (n >= N) continue;
            Cpart[(long)m * N + n] = acc[i][j];
        }
    }
}

// ---------- step-1 specialized split-K GEMM ----------
// score[b][q][n] = sum_d kf[b][d][q] * img[n][d]; M=1024,N=98,K=2048.
// grid (16, 2, 64): z = bz*8 + kz, kch=256. Vectorized float4 staging,
// padded LDS. FMA order per thread identical to generic path.
__global__ __launch_bounds__(256) void gemm_s1(
    const float* __restrict__ kf, const float* __restrict__ img,
    float* __restrict__ Cpart)
{
    __shared__ __align__(16) float As[16][68];
    __shared__ __align__(16) float Bs[16][68];
    int tx = threadIdx.x;
    int m0 = blockIdx.x * 64, n0 = blockIdx.y * 64;
    int bz = blockIdx.z >> 3, kz = blockIdx.z & 7;
    const float* A = kf + (long)bz * 2048 * 1024;      // [d][q] col-major A
    float* Cp = Cpart + (long)kz * 802816 + (long)bz * 100352;
    int kbeg = kz * 256;
    int tm = tx >> 4, tn = tx & 15;
    int akk = tx >> 4, amq = (tx & 15) * 4;            // A stage: 16 k-rows x 64 m
    int bnn = tx >> 2, bkq = (tx & 3) * 4;             // B stage: 64 n-rows x 16 k
    bool bvalid = (n0 + bnn) < 98;
    const float* Bp = img + (long)(n0 + bnn) * 2048;
    float acc[4][4] = {};
    for (int k0 = kbeg; k0 < kbeg + 256; k0 += 16) {
        float4 av = *(const float4*)&A[(long)(k0 + akk) * 1024 + m0 + amq];
        float4 bv = bvalid ? *(const float4*)&Bp[k0 + bkq] : (float4){0.f, 0.f, 0.f, 0.f};
        __syncthreads();
        *(float4*)&As[akk][amq] = av;
        Bs[bkq + 0][bnn] = bv.x;
        Bs[bkq + 1][bnn] = bv.y;
        Bs[bkq + 2][bnn] = bv.z;
        Bs[bkq + 3][bnn] = bv.w;
        __syncthreads();
#pragma unroll
        for (int kk = 0; kk < 16; ++kk) {
            float4 a4 = *(const float4*)&As[kk][tm * 4];
            float4 b4 = *(const float4*)&Bs[kk][tn * 4];
            float a[4] = {a4.x, a4.y, a4.z, a4.w};
            float b[4] = {b4.x, b4.y, b4.z, b4.w};
#pragma unroll
            for (int i = 0; i < 4; i++)
#pragma unroll
                for (int j = 0; j < 4; j++) acc[i][j] += a[i] * b[j];
        }
    }
#pragma unroll
    for (int i = 0; i < 4; i++) {
        int m = m0 + tm * 4 + i;
#pragma unroll
        for (int j = 0; j < 4; j++) {
            int n = n0 + tn * 4 + j;
            if (n < 98) Cp[(long)m * 98 + n] = acc[i][j];
        }
    }
}

// ---------- sum nz split-K partial buffers ----------
__global__ void sk_reduce(const float* __restrict__ Cpart, float* __restrict__ C,
                          long len, int nz)
{
    long i = (long)blockIdx.x * 256 + threadIdx.x;
    if (i >= len) return;
    float s = 0.f;
    for (int z = 0; z < nz; z++) s += Cpart[(long)z * len + i];
    C[i] = s;
}

// ---------- bf16 MFMA GEMM: C[M,N] = A[M,K] x B[K,N] ----------
// Abf: bf16 bits, row-major [Mpad][K] (Mpad >= gridDim.x*128)
// Bbf: bf16 bits, B TRANSPOSED layout [N][K]
// 128x128 tile, 4 waves (2x2 of 64x64), 16x16x32 MFMA, BK=32.
__global__ __launch_bounds__(256) void mfma_gemm(
    const unsigned short* __restrict__ Abf, const unsigned short* __restrict__ Bbf,
    float* __restrict__ C, int M, int N, int K, int ldc)
{
    __shared__ __align__(16) short As[128 * 40];   // +8 pad kills ds_read conflicts
    __shared__ __align__(16) short Bs[128 * 40];
    int tid = threadIdx.x;
    int m0 = blockIdx.x * 128, n0 = blockIdx.y * 128;
    int w = tid >> 6, l = tid & 63;
    int wm = (w >> 1) * 64, wn = (w & 1) * 64;
    int lr = l & 15, lq = l >> 4;
    int row0 = tid >> 2, kc = (tid & 3) * 8;
    floatx4 acc[4][4];
#pragma unroll
    for (int i = 0; i < 4; i++)
#pragma unroll
        for (int j = 0; j < 4; j++) acc[i][j] = (floatx4){0.f, 0.f, 0.f, 0.f};
    const unsigned short* Ap  = Abf + (long)(m0 + row0) * K + kc;
    const unsigned short* Ap2 = Abf + (long)(m0 + row0 + 64) * K + kc;
    const unsigned short* Bp  = Bbf + (long)(n0 + row0) * K + kc;
    const unsigned short* Bp2 = Bbf + (long)(n0 + row0 + 64) * K + kc;
    for (int k0 = 0; k0 < K; k0 += 32) {
        uint4 a0 = *(const uint4*)(Ap + k0);
        uint4 a1 = *(const uint4*)(Ap2 + k0);
        uint4 b0 = *(const uint4*)(Bp + k0);
        uint4 b1 = *(const uint4*)(Bp2 + k0);
        __syncthreads();
        *(uint4*)&As[row0 * 40 + kc] = a0;
        *(uint4*)&As[(row0 + 64) * 40 + kc] = a1;
        *(uint4*)&Bs[row0 * 40 + kc] = b0;
        *(uint4*)&Bs[(row0 + 64) * 40 + kc] = b1;
        __syncthreads();
        short8 af[4], bfr[4];
#pragma unroll
        for (int i = 0; i < 4; i++) af[i]  = *(const short8*)&As[(wm + i * 16 + lr) * 40 + lq * 8];
#pragma unroll
        for (int i = 0; i < 4; i++) bfr[i] = *(const short8*)&Bs[(wn + i * 16 + lr) * 40 + lq * 8];
#pragma unroll
        for (int i = 0; i < 4; i++)
#pragma unroll
            for (int j = 0; j < 4; j++)
                acc[i][j] = __builtin_amdgcn_mfma_f32_16x16x32_bf16(af[i], bfr[j], acc[i][j], 0, 0, 0);
    }
#pragma unroll
    for (int i = 0; i < 4; i++) {
#pragma unroll
        for (int r = 0; r < 4; r++) {
            int m = m0 + wm + i * 16 + lq * 4 + r;
            if (m >= M) continue;
#pragma unroll
            for (int j = 0; j < 4; j++)
                C[(long)m * ldc + n0 + wn + j * 16 + lr] = acc[i][j][r];
        }
    }
}

// ---------- fp32 [K][N] -> bf16-bits transposed [N][K] (tiled via LDS) ----------
__global__ __launch_bounds__(256) void tpose_cvt(const float* __restrict__ src,
                                                 unsigned short* __restrict__ dst,
                                                 int K, int N)
{
    __shared__ float t[32][33];
    int n0 = blockIdx.x * 32, k0 = blockIdx.y * 32;
    int tid = threadIdx.x;
    int r = tid >> 3, c4 = (tid & 7) * 4;
    float4 v = *(const float4*)&src[(long)(k0 + r) * N + n0 + c4];
    t[r][c4] = v.x; t[r][c4 + 1] = v.y; t[r][c4 + 2] = v.z; t[r][c4 + 3] = v.w;
    __syncthreads();
    ushort4 o;
    o.x = f2b(t[c4][r]);
    o.y = f2b(t[c4 + 1][r]);
    o.z = f2b(t[c4 + 2][r]);
    o.w = f2b(t[c4 + 3][r]);
    *(ushort4*)&dst[(long)(n0 + r) * K + k0 + c4] = o;
}

// ---------- fp32 [M][C] -> bf16-bits [Mpad][C] (zero pad rows >= M) ----------
__global__ void cvt_pad(const float* __restrict__ src, unsigned short* __restrict__ dst,
                        int M, int Mpad, int C)
{
    long i4 = ((long)blockIdx.x * 256 + threadIdx.x) * 4;
    if (i4 >= (long)Mpad * C) return;
    int row = (int)(i4 / C);
    ushort4 o = {0, 0, 0, 0};
    if (row < M) {
        float4 v = *(const float4*)&src[i4];
        o.x = f2b(v.x); o.y = f2b(v.y); o.z = f2b(v.z); o.w = f2b(v.w);
    }
    *(ushort4*)&dst[i4] = o;
}

// ---------- y * silu(z) -> bf16-bits [Mpad][C] ----------
__global__ void gate_cvt(const float* __restrict__ y, const float* __restrict__ z,
                         unsigned short* __restrict__ dst, int M, int Mpad, int C, int ldz)
{
    long i4 = ((long)blockIdx.x * 256 + threadIdx.x) * 4;
    if (i4 >= (long)Mpad * C) return;
    int row = (int)(i4 / C);
    int col = (int)(i4 - (long)row * C);
    ushort4 o = {0, 0, 0, 0};
    if (row < M) {
        float4 yv = *(const float4*)&y[i4];
        float4 zv = *(const float4*)&z[(long)row * ldz + col];
        o.x = f2b(yv.x * siluf(zv.x));
        o.y = f2b(yv.y * siluf(zv.y));
        o.z = f2b(yv.z * siluf(zv.z));
        o.w = f2b(yv.w * siluf(zv.w));
    }
    *(ushort4*)&dst[i4] = o;
}

// ---------- causal depthwise conv (k=4) + bias + silu ----------
__global__ void conv_silu_kernel(const float* __restrict__ xz, const float* __restrict__ w,
                                 const float* __restrict__ bias, float* __restrict__ out,
                                 int Bn, int L, int din, int ldx)
{
    int idx = blockIdx.x * 256 + threadIdx.x;
    int total = Bn * L * din;
    if (idx >= total) return;
    int c = idx % din;
    int r = idx / din;
    int t = r % L;
    int b = r / L;
    float acc = bias[c];
#pragma unroll
    for (int i = 0; i < 4; i++) {
        int tt = t - 3 + i;
        if (tt >= 0) acc += w[c * 4 + i] * xz[((long)(b * L + tt)) * ldx + c];
    }
    out[idx] = siluf(acc);
}

// ---------- selective scan (u/y may alias) ----------
// 16-step groups; n-reduce done with DPP (quad_perm + row_ror) entirely on
// the VALU pipe — no LDS-pipe shuffle latency (ds_swizzle ~120cy was the
// critical path at 1 wave/SIMD occupancy). Lane n==0's add order is
// bit-identical to the original xor butterfly.
template<int T>
__global__ __launch_bounds__(256) void scan_kernel(
    const float* u, const float* dt,
    const float* xdbl, const float* __restrict__ A_log,
    const float* __restrict__ Dp, float* y,
    int din, int L, int xld, int boff, int coff)
{
    __shared__ float Bc[T][16], Cc[T][16], dtc[T][16], uc[T][16], yc[T][16];
    int tx = threadIdx.x;
    int dl = tx >> 4;
    int n = tx & 15;
    int dbase = blockIdx.x * 16;
    int dg = dbase + dl;
    int b = blockIdx.y;
    bool act = dg < din;
    float Acoef = act ? -__expf(A_log[dg * 16 + n]) : 0.f;
    float Dv = act ? Dp[dg] : 0.f;
    int nvalid = min(16, din - dbase);
    float h = 0.f;
    for (int c0 = 0; c0 < L; c0 += T) {
        int tcnt = min(T, L - c0);
        for (int i = tx; i < T * 16; i += 256) {
            int tt = i >> 4, c = i & 15;
            if (tt < tcnt) {
                long row = (long)b * L + c0 + tt;
                float uv = 0.f, dv = 0.f;
                if (c < nvalid) { uv = u[row * din + dbase + c]; dv = dt[row * din + dbase + c]; }
                uc[tt][c] = uv; dtc[tt][c] = dv;
                Bc[tt][c] = xdbl[row * xld + boff + c];
                Cc[tt][c] = xdbl[row * xld + coff + c];
            }
        }
        __syncthreads();
        int tt = 0;
        for (; tt + 16 <= tcnt; tt += 16) {
            float pbuf[16];
#pragma unroll
            for (int q = 0; q < 16; q++) {
                float dtv = dtc[tt + q][dl];
                float uv = uc[tt + q][dl];
                float dA = __expf(dtv * Acoef);
                h = dA * h + (dtv * uv) * Bc[tt + q][n];
                pbuf[q] = h * Cc[tt + q][n];
            }
#pragma unroll
            for (int q = 0; q < 16; q++) pbuf[q] = row16_sum(pbuf[q]);
            if (n == 0) {
#pragma unroll
                for (int q = 0; q < 16; q++)
                    yc[tt + q][dl] = pbuf[q] + Dv * uc[tt + q][dl];
            }
        }
        for (; tt < tcnt; ++tt) {
            float dtv = dtc[tt][dl];
            float uv = uc[tt][dl];
            float dA = __expf(dtv * Acoef);
            h = dA * h + (dtv * uv) * Bc[tt][n];
            float p = row16_sum(h * Cc[tt][n]);
            if (n == 0) yc[tt][dl] = p + Dv * uv;
        }
        __syncthreads();
        for (int i = tx; i < tcnt * 16; i += 256) {
            int tt2 = i >> 4, c = i & 15;
            if (c < nvalid) y[((long)b * L + c0 + tt2) * din + dbase + c] = yc[tt2][c];
        }
        __syncthreads();
    }
}

// ---------- row mean: one wave per row of score[8192][98] ----------
__global__ __launch_bounds__(256) void row_mean_kernel(const float* __restrict__ sc2,
                                                       float* __restrict__ means)
{
    int row = blockIdx.x * 4 + (threadIdx.x >> 6);
    int lane = threadIdx.x & 63;
    const float* p = sc2 + (long)row * 98;
    float s = p[lane];
    if (lane < 34) s += p[lane + 64];
    s += __shfl_xor(s, 1);
    s += __shfl_xor(s, 2);
    s += __shfl_xor(s, 4);
    s += __shfl_xor(s, 8);
    s += __shfl_xor(s, 16);
    s += __shfl_xor(s, 32);
    if (lane == 0) means[row] = s * (1.f / 98.f);
}

// ---------- softmax over k (1024) per batch, means -> s ----------
__global__ __launch_bounds__(256) void softmax1024_kernel(const float* __restrict__ means,
                                                          float* __restrict__ s)
{
    __shared__ float red[256];
    int b = blockIdx.x, tx = threadIdx.x;
    float v[4];
    float mx = -1e30f;
#pragma unroll
    for (int i = 0; i < 4; i++) {
        v[i] = means[b * 1024 + tx + i * 256];
        mx = fmaxf(mx, v[i]);
    }
    red[tx] = mx; __syncthreads();
    for (int st = 128; st > 0; st >>= 1) { if (tx < st) red[tx] = fmaxf(red[tx], red[tx + st]); __syncthreads(); }
    mx = red[0]; __syncthreads();
    float lsum = 0.f;
#pragma unroll
    for (int i = 0; i < 4; i++) { v[i] = __expf(v[i] - mx); lsum += v[i]; }
    red[tx] = lsum; __syncthreads();
    for (int st = 128; st > 0; st >>= 1) { if (tx < st) red[tx] += red[tx + st]; __syncthreads(); }
    float inv = 1.f / red[0];
#pragma unroll
    for (int i = 0; i < 4; i++) s[b * 1024 + tx + i * 256] = v[i] * inv;
}

// ---------- top-98 sequential selection (jax tie semantics) ----------
__global__ __launch_bounds__(256) void topk_select_kernel(const float* __restrict__ s,
                                                          int* __restrict__ ind,
                                                          float* __restrict__ vtopk)
{
    __shared__ unsigned long long arr[1024];
    __shared__ unsigned long long red[256];
    int b = blockIdx.x, tx = threadIdx.x;
    for (int k = tx; k < 1024; k += 256) {
        float v = s[b * 1024 + k];
        unsigned u = __float_as_uint(v);
        u = (u & 0x80000000u) ? ~u : (u | 0x80000000u);
        arr[k] = ((unsigned long long)u << 32) | (unsigned)(~k);
    }
    __syncthreads();
    for (int r = 0; r < 98; ++r) {
        unsigned long long m = 0ull;
        for (int k = tx; k < 1024; k += 256) m = (arr[k] > m) ? arr[k] : m;
        red[tx] = m; __syncthreads();
        for (int st = 128; st > 0; st >>= 1) {
            if (tx < st && red[tx + st] > red[tx]) red[tx] = red[tx + st];
            __syncthreads();
        }
        unsigned long long best = red[0];
        if (tx == 0) {
            unsigned lo = (unsigned)(best & 0xffffffffu);
            int kidx = (int)(~lo);
            unsigned ub = (unsigned)(best >> 32);
            unsigned fb = (ub & 0x80000000u) ? (ub ^ 0x80000000u) : ~ub;
            ind[b * 98 + r] = kidx;
            vtopk[b * 98 + r] = __uint_as_float(fb);
            arr[kidx] = 0ull;
        }
        __syncthreads();
    }
}

// ---------- gather: h[b,j,:] = img[j,:] + kf[b,:,ind]*v ----------
__global__ void gather_kernel(const float* __restrict__ img, const float* __restrict__ kf,
                              const int* __restrict__ ind, const float* __restrict__ vtopk,
                              float* __restrict__ h)
{
    int j = blockIdx.x, b = blockIdx.y;
    int kidx = ind[b * 98 + j];
    float v = vtopk[b * 98 + j];
    long hbase = ((long)b * 98 + j) * 2048;
    const float* kfb = kf + (long)b * 2048 * 1024 + kidx;
    for (int d = threadIdx.x; d < 2048; d += 256)
        h[hbase + d] = img[(long)j * 2048 + d] + kfb[(long)d * 1024] * v;
}

// ---------- host launch ----------
extern "C" void kernel_launch(void* const* d_in, const int* in_sizes, int n_in,
                              void* d_out, int out_size, void* d_ws, size_t ws_size,
                              hipStream_t stream)
{
    const float* imgF      = (const float*)d_in[0];
    const float* kf        = (const float*)d_in[1];
    const float* a_in_w    = (const float*)d_in[2];
    const float* a_conv_w  = (const float*)d_in[3];
    const float* a_conv_b  = (const float*)d_in[4];
    const float* a_xproj_w = (const float*)d_in[5];
    const float* a_dt_w    = (const float*)d_in[6];
    const float* a_dt_b    = (const float*)d_in[7];
    const float* a_A_log   = (const float*)d_in[8];
    const float* a_D       = (const float*)d_in[9];
    const float* a_out_w   = (const float*)d_in[10];
    const float* c_in_w    = (const float*)d_in[11];
    const float* c_conv_w  = (const float*)d_in[12];
    const float* c_conv_b  = (const float*)d_in[13];
    const float* c_xproj_w = (const float*)d_in[14];
    const float* c_dt_w    = (const float*)d_in[15];
    const float* c_dt_b    = (const float*)d_in[16];
    const float* c_A_log   = (const float*)d_in[17];
    const float* c_D       = (const float*)d_in[18];
    const float* c_out_w   = (const float*)d_in[19];

    float* fout = (float*)d_out;

    float* ws = (float*)d_ws;
    float* h_buf  = ws;                      // 1,605,632 floats
    float* S      = ws + 1605632;
    // stage A
    float* score  = S;                       // 802,816 (reused as score2)
    float* xz_a   = S + 802816;              // 3,211,264
    float* xi_a   = S + 4014080;             // 1,605,632 (scan in-place)
    float* xdbl_a = S + 5619712;             // 319,488
    float* dt_a   = S + 5939200;             // 1,605,632
    float* sbuf   = S + 7544832;             // 8,192
    int*   indb   = (int*)(S + 7553024);     // 784
    float* vtopk  = S + 7553808;             // 784
    // stage C (aliases stage A region)
    float* xz_c   = S;                       // 6,422,528
    float* xi_c   = S + 6422528;             // 3,211,264 (scan in-place)
    float* xdbl_c = S + 9633792;             // 125,440
    float* dt_c   = S + 9759232;             // 3,211,264
    // bf16 scratch (beyond the fp32 region: base float offset 14,576,128)
    unsigned short* cwbf  = (unsigned short*)(ws + 14576128);          // 16,777,216 bf16
    unsigned short* h_bf  = (unsigned short*)(ws + 14576128 + 8388608);// 1,835,008 bf16
    unsigned short* yz_bf = (unsigned short*)(ws + 14576128 + 9306112);// 3,670,016 bf16
    // split-K partials:
    //  - step 1 (stage A): bf16 region is dead until step 11 -> reuse it.
    //    8 chunks x 802,816 = 6,422,528 floats at 14,576,128..20,998,656.
    float* CpartS1 = ws + 14576128;
    //  - step 13 (stage C): upper half of cwbf region is dead between
    //    mfma_gemm #11 and tpose_cvt #16. 16 x 784 x 160 floats.
    float* Cpart  = ws + 18770432;
    // means scratch for step 8: dt_a region is dead after scan_kernel (step 6)
    float* means  = dt_a;
    // total ws: 25,717,248 floats ~= 103 MB

    // ===== stage A (fp32) =====
    // 1. score[b] = kf[b]^T @ imgF^T : specialized split-K x8 (2048 blocks)
    gemm_s1<<<dim3(16, 2, 64), 256, 0, stream>>>(kf, imgF, CpartS1);
    sk_reduce<<<3136, 256, 0, stream>>>(CpartS1, score, 802816L, 8);

    gemm64<false, false, false, 0><<<dim3(128, 7, 1), 256, 0, stream>>>(
        score, a_in_w, xz_a, nullptr, nullptr, 8192, 392, 98, 98, 392, 392, 0, 0L, 0L, 0L);
    conv_silu_kernel<<<6272, 256, 0, stream>>>(xz_a, a_conv_w, a_conv_b, xi_a, 8, 1024, 196, 392);
    gemm64<false, false, false, 0><<<dim3(128, 1, 1), 256, 0, stream>>>(
        xi_a, a_xproj_w, xdbl_a, nullptr, nullptr, 8192, 39, 196, 196, 39, 39, 0, 0L, 0L, 0L);
    gemm64<false, false, false, 1><<<dim3(128, 4, 1), 256, 0, stream>>>(
        xdbl_a, a_dt_w, dt_a, nullptr, a_dt_b, 8192, 196, 7, 39, 196, 196, 0, 0L, 0L, 0L);
    scan_kernel<64><<<dim3(13, 8, 1), 256, 0, stream>>>(
        xi_a, dt_a, xdbl_a, a_A_log, a_D, xi_a, 196, 1024, 39, 7, 23);
    gemm64<false, false, true, 0><<<dim3(128, 2, 1), 256, 0, stream>>>(
        xi_a, a_out_w, score, xz_a + 196, nullptr, 8192, 98, 196, 196, 98, 98, 392, 0L, 0L, 0L);
    // 8. mean over n + softmax over k (parallel mean, tiny softmax)
    row_mean_kernel<<<2048, 256, 0, stream>>>(score, means);
    softmax1024_kernel<<<8, 256, 0, stream>>>(means, sbuf);
    topk_select_kernel<<<8, 256, 0, stream>>>(sbuf, indb, vtopk);
    gather_kernel<<<dim3(98, 8, 1), 256, 0, stream>>>(imgF, kf, indb, vtopk, h_buf);

    // ===== stage C =====
    // 11. xz_c = h @ c_in_w  (bf16 MFMA)
    tpose_cvt<<<dim3(256, 64, 1), 256, 0, stream>>>(c_in_w, cwbf, 2048, 8192);
    cvt_pad<<<1792, 256, 0, stream>>>(h_buf, h_bf, 784, 896, 2048);
    mfma_gemm<<<dim3(7, 64, 1), 256, 0, stream>>>(h_bf, cwbf, xz_c, 784, 8192, 2048, 8192);

    // 12. conv + silu -> xi_c
    conv_silu_kernel<<<12544, 256, 0, stream>>>(xz_c, c_conv_w, c_conv_b, xi_c, 8, 98, 4096, 8192);

    // 13. xdbl_c = xi_c @ c_xproj_w (fp32, split-K x16)
    gemm64_sk<<<dim3(13, 3, 16), 256, 0, stream>>>(
        xi_c, c_xproj_w, Cpart, 784, 160, 4096, 4096, 160, 256);
    sk_reduce<<<490, 256, 0, stream>>>(Cpart, xdbl_c, 125440L, 16);

    // 14. dt_c = softplus(xdbl_c[:, :128] @ c_dt_w + c_dt_b) (fp32)
    gemm64<false, false, false, 1><<<dim3(13, 64, 1), 256, 0, stream>>>(
        xdbl_c, c_dt_w, dt_c, nullptr, c_dt_b, 784, 4096, 128, 160, 4096, 4096, 0, 0L, 0L, 0L);

    // 15. selective scan C (in-place)
    scan_kernel<98><<<dim3(256, 8, 1), 256, 0, stream>>>(
        xi_c, dt_c, xdbl_c, c_A_log, c_D, xi_c, 4096, 98, 160, 128, 144);

    // 16. out = (y_c * silu(z_c)) @ c_out_w  (bf16 MFMA, direct to d_out)
    gate_cvt<<<3584, 256, 0, stream>>>(xi_c, xz_c + 4096, yz_bf, 784, 896, 4096, 8192);
    tpose_cvt<<<dim3(64, 128, 1), 256, 0, stream>>>(c_out_w, cwbf, 4096, 2048);
    mfma_gemm<<<dim3(7, 16, 1), 256, 0, stream>>>(yz_bf, cwbf, fout, 784, 2048, 4096, 2048);
}

// Round 10
// 935.797 us; speedup vs baseline: 2.2203x; 1.0217x over previous
//
#include <hip/hip_runtime.h>
#include <hip/hip_bf16.h>
#include <math.h>

typedef __attribute__((ext_vector_type(8))) short short8;
typedef __attribute__((ext_vector_type(4))) float floatx4;

// ---------- helpers ----------
__device__ __forceinline__ float siluf(float x) {
    float e = __expf(-fabsf(x));
    float s = (x >= 0.f) ? 1.f / (1.f + e) : e / (1.f + e);
    return x * s;
}
__device__ __forceinline__ float softplusf(float x) {
    if (x > 20.f) return x;
    if (x < -20.f) return __expf(x);
    return log1pf(__expf(x));
}
__device__ __forceinline__ unsigned short f2b(float v) {
    __hip_bfloat16 b = __float2bfloat16(v);
    unsigned short u;
    __builtin_memcpy(&u, &b, 2);
    return u;
}
// DPP lane-add: x += x[neighbor] per 16-lane row, VALU-speed (no LDS pipe).
template<int CTRL>
__device__ __forceinline__ float dpp_add(float x) {
    int yi = __builtin_amdgcn_mov_dpp(__float_as_int(x), CTRL, 0xF, 0xF, true);
    return x + __int_as_float(yi);
}
// Sum over the 16-lane row (n-dim). For lane (n==0) the add order is
// bit-identical to the xor1/2/4/8 butterfly: ((p0+p1)+(p2+p3)) per quad,
// then (s0+s1)+(s2+s3) via row_ror:4 + row_ror:8.
__device__ __forceinline__ float row16_sum(float p) {
    p = dpp_add<0xB1>(p);    // quad_perm [1,0,3,2]  : xor 1
    p = dpp_add<0x4E>(p);    // quad_perm [2,3,0,1]  : xor 2
    p = dpp_add<0x124>(p);   // row_ror:4
    p = dpp_add<0x128>(p);   // row_ror:8
    return p;
}

// ---------- generic 64x64 tiled GEMM (fp32) — LDS rows padded to 68 ----------
// (64-stride rows put consecutive-kk staging writes all in one bank: 16-way
//  conflict. 68 = bank stride 4, rows stay 16B-aligned.)
template<bool ACOL, bool BCOL, bool AMUL, int EPI>
__global__ __launch_bounds__(256) void gemm64(
    const float* __restrict__ A, const float* __restrict__ Bw, float* __restrict__ C,
    const float* __restrict__ A2, const float* __restrict__ bias,
    int M, int N, int K, int lda, int ldb, int ldc, int lda2,
    long batA, long batB, long batC)
{
    __shared__ __align__(16) float As[16][68];
    __shared__ __align__(16) float Bs[16][68];
    int tx = threadIdx.x;
    int m0 = blockIdx.x * 64, n0 = blockIdx.y * 64;
    A += blockIdx.z * batA; Bw += blockIdx.z * batB; C += blockIdx.z * batC;
    int tm = tx >> 4, tn = tx & 15;
    float acc[4][4] = {};
    for (int k0 = 0; k0 < K; k0 += 16) {
        for (int i = tx; i < 1024; i += 256) {
            int mm, kk;
            if (ACOL) { mm = i & 63; kk = i >> 6; } else { kk = i & 15; mm = i >> 4; }
            int m = m0 + mm, k = k0 + kk;
            float v = 0.f;
            if (m < M && k < K) {
                long ia = ACOL ? ((long)k * lda + m) : ((long)m * lda + k);
                v = A[ia];
                if (AMUL) v *= siluf(A2[(long)m * lda2 + k]);
            }
            As[kk][mm] = v;
        }
        for (int i = tx; i < 1024; i += 256) {
            int nn, kk;
            if (BCOL) { kk = i & 15; nn = i >> 4; } else { nn = i & 63; kk = i >> 6; }
            int n = n0 + nn, k = k0 + kk;
            float v = 0.f;
            if (n < N && k < K) {
                long ib = BCOL ? ((long)n * ldb + k) : ((long)k * ldb + n);
                v = Bw[ib];
            }
            Bs[kk][nn] = v;
        }
        __syncthreads();
#pragma unroll
        for (int kk = 0; kk < 16; ++kk) {
            float4 av = *(const float4*)&As[kk][tm * 4];
            float4 bv = *(const float4*)&Bs[kk][tn * 4];
            float a[4] = {av.x, av.y, av.z, av.w};
            float b[4] = {bv.x, bv.y, bv.z, bv.w};
#pragma unroll
            for (int i = 0; i < 4; i++)
#pragma unroll
                for (int j = 0; j < 4; j++) acc[i][j] += a[i] * b[j];
        }
        __syncthreads();
    }
#pragma unroll
    for (int i = 0; i < 4; i++) {
        int m = m0 + tm * 4 + i;
        if (m >= M) continue;
#pragma unroll
        for (int j = 0; j < 4; j++) {
            int n = n0 + tn * 4 + j;
            if (n >= N) continue;
            float v = acc[i][j];
            if (EPI == 1) v = softplusf(v + bias[n]);
            C[(long)m * ldc + n] = v;
        }
    }
}

// ---------- split-K fp32 GEMM (row-major A,B): Cpart[z] = partial ----------
__global__ __launch_bounds__(256) void gemm64_sk(
    const float* __restrict__ A, const float* __restrict__ Bw, float* __restrict__ Cpart,
    int M, int N, int K, int lda, int ldb, int kch)
{
    __shared__ __align__(16) float As[16][68];
    __shared__ __align__(16) float Bs[16][68];
    int tx = threadIdx.x;
    int m0 = blockIdx.x * 64, n0 = blockIdx.y * 64;
    int kbeg = blockIdx.z * kch;
    int kend = min(kbeg + kch, K);
    Cpart += (long)blockIdx.z * M * N;
    int tm = tx >> 4, tn = tx & 15;
    float acc[4][4] = {};
    for (int k0 = kbeg; k0 < kend; k0 += 16) {
        for (int i = tx; i < 1024; i += 256) {
            int kk = i & 15, mm = i >> 4;
            int m = m0 + mm, k = k0 + kk;
            As[kk][mm] = (m < M && k < kend) ? A[(long)m * lda + k] : 0.f;
        }
        for (int i = tx; i < 1024; i += 256) {
            int nn = i & 63, kk = i >> 6;
            int n = n0 + nn, k = k0 + kk;
            Bs[kk][nn] = (n < N && k < kend) ? Bw[(long)k * ldb + n] : 0.f;
        }
        __syncthreads();
#pragma unroll
        for (int kk = 0; kk < 16; ++kk) {
            float4 av = *(const float4*)&As[kk][tm * 4];
            float4 bv = *(const float4*)&Bs[kk][tn * 4];
            float a[4] = {av.x, av.y, av.z, av.w};
            float b[4] = {bv.x, bv.y, bv.z, bv.w};
#pragma unroll
            for (int i = 0; i < 4; i++)
#pragma unroll
                for (int j = 0; j < 4; j++) acc[i][j] += a[i] * b[j];
        }
        __syncthreads();
    }
#pragma unroll
    for (int i = 0; i < 4; i++) {
        int m = m0 + tm * 4 + i;
        if (m >= M) continue;
#pragma unroll
        for (int j = 0; j < 4; j++) {
            int n = n0 + tn * 4 + j;
            if (n >= N) continue;
            Cpart[(long)m * N + n] = acc[i][j];
        }
    }
}

// ---------- step-1 specialized split-K GEMM ----------
// score[b][q][n] = sum_d kf[b][d][q] * img[n][d]; M=1024,N=98,K=2048.
// grid (16, 2, 64): z = bz*8 + kz, kch=256. Vectorized float4 staging,
// padded LDS. FMA order per thread identical to generic path.
__global__ __launch_bounds__(256) void gemm_s1(
    const float* __restrict__ kf, const float* __restrict__ img,
    float* __restrict__ Cpart)
{
    __shared__ __align__(16) float As[16][68];
    __shared__ __align__(16) float Bs[16][68];
    int tx = threadIdx.x;
    int m0 = blockIdx.x * 64, n0 = blockIdx.y * 64;
    int bz = blockIdx.z >> 3, kz = blockIdx.z & 7;
    const float* A = kf + (long)bz * 2048 * 1024;      // [d][q] col-major A
    float* Cp = Cpart + (long)kz * 802816 + (long)bz * 100352;
    int kbeg = kz * 256;
    int tm = tx >> 4, tn = tx & 15;
    int akk = tx >> 4, amq = (tx & 15) * 4;            // A stage: 16 k-rows x 64 m
    int bnn = tx >> 2, bkq = (tx & 3) * 4;             // B stage: 64 n-rows x 16 k
    bool bvalid = (n0 + bnn) < 98;
    const float* Bp = img + (long)(n0 + bnn) * 2048;
    float acc[4][4] = {};
    for (int k0 = kbeg; k0 < kbeg + 256; k0 += 16) {
        float4 av = *(const float4*)&A[(long)(k0 + akk) * 1024 + m0 + amq];
        float4 bv = bvalid ? *(const float4*)&Bp[k0 + bkq] : (float4){0.f, 0.f, 0.f, 0.f};
        __syncthreads();
        *(float4*)&As[akk][amq] = av;
        Bs[bkq + 0][bnn] = bv.x;
        Bs[bkq + 1][bnn] = bv.y;
        Bs[bkq + 2][bnn] = bv.z;
        Bs[bkq + 3][bnn] = bv.w;
        __syncthreads();
#pragma unroll
        for (int kk = 0; kk < 16; ++kk) {
            float4 a4 = *(const float4*)&As[kk][tm * 4];
            float4 b4 = *(const float4*)&Bs[kk][tn * 4];
            float a[4] = {a4.x, a4.y, a4.z, a4.w};
            float b[4] = {b4.x, b4.y, b4.z, b4.w};
#pragma unroll
            for (int i = 0; i < 4; i++)
#pragma unroll
                for (int j = 0; j < 4; j++) acc[i][j] += a[i] * b[j];
        }
    }
#pragma unroll
    for (int i = 0; i < 4; i++) {
        int m = m0 + tm * 4 + i;
#pragma unroll
        for (int j = 0; j < 4; j++) {
            int n = n0 + tn * 4 + j;
            if (n < 98) Cp[(long)m * 98 + n] = acc[i][j];
        }
    }
}

// ---------- sum nz split-K partial buffers ----------
__global__ void sk_reduce(const float* __restrict__ Cpart, float* __restrict__ C,
                          long len, int nz)
{
    long i = (long)blockIdx.x * 256 + threadIdx.x;
    if (i >= len) return;
    float s = 0.f;
    for (int z = 0; z < nz; z++) s += Cpart[(long)z * len + i];
    C[i] = s;
}

// ---------- bf16 MFMA GEMM: C[M,N] = A[M,K] x B[K,N] ----------
// Abf: bf16 bits, row-major [Mpad][K] (Mpad >= gridDim.x*128)
// Bbf: bf16 bits, B TRANSPOSED layout [N][K]
// 128x128 tile, 4 waves (2x2 of 64x64), 16x16x32 MFMA, BK=32.
__global__ __launch_bounds__(256) void mfma_gemm(
    const unsigned short* __restrict__ Abf, const unsigned short* __restrict__ Bbf,
    float* __restrict__ C, int M, int N, int K, int ldc)
{
    __shared__ __align__(16) short As[128 * 40];   // +8 pad kills ds_read conflicts
    __shared__ __align__(16) short Bs[128 * 40];
    int tid = threadIdx.x;
    int m0 = blockIdx.x * 128, n0 = blockIdx.y * 128;
    int w = tid >> 6, l = tid & 63;
    int wm = (w >> 1) * 64, wn = (w & 1) * 64;
    int lr = l & 15, lq = l >> 4;
    int row0 = tid >> 2, kc = (tid & 3) * 8;
    floatx4 acc[4][4];
#pragma unroll
    for (int i = 0; i < 4; i++)
#pragma unroll
        for (int j = 0; j < 4; j++) acc[i][j] = (floatx4){0.f, 0.f, 0.f, 0.f};
    const unsigned short* Ap  = Abf + (long)(m0 + row0) * K + kc;
    const unsigned short* Ap2 = Abf + (long)(m0 + row0 + 64) * K + kc;
    const unsigned short* Bp  = Bbf + (long)(n0 + row0) * K + kc;
    const unsigned short* Bp2 = Bbf + (long)(n0 + row0 + 64) * K + kc;
    for (int k0 = 0; k0 < K; k0 += 32) {
        uint4 a0 = *(const uint4*)(Ap + k0);
        uint4 a1 = *(const uint4*)(Ap2 + k0);
        uint4 b0 = *(const uint4*)(Bp + k0);
        uint4 b1 = *(const uint4*)(Bp2 + k0);
        __syncthreads();
        *(uint4*)&As[row0 * 40 + kc] = a0;
        *(uint4*)&As[(row0 + 64) * 40 + kc] = a1;
        *(uint4*)&Bs[row0 * 40 + kc] = b0;
        *(uint4*)&Bs[(row0 + 64) * 40 + kc] = b1;
        __syncthreads();
        short8 af[4], bfr[4];
#pragma unroll
        for (int i = 0; i < 4; i++) af[i]  = *(const short8*)&As[(wm + i * 16 + lr) * 40 + lq * 8];
#pragma unroll
        for (int i = 0; i < 4; i++) bfr[i] = *(const short8*)&Bs[(wn + i * 16 + lr) * 40 + lq * 8];
#pragma unroll
        for (int i = 0; i < 4; i++)
#pragma unroll
            for (int j = 0; j < 4; j++)
                acc[i][j] = __builtin_amdgcn_mfma_f32_16x16x32_bf16(af[i], bfr[j], acc[i][j], 0, 0, 0);
    }
#pragma unroll
    for (int i = 0; i < 4; i++) {
#pragma unroll
        for (int r = 0; r < 4; r++) {
            int m = m0 + wm + i * 16 + lq * 4 + r;
            if (m >= M) continue;
#pragma unroll
            for (int j = 0; j < 4; j++)
                C[(long)m * ldc + n0 + wn + j * 16 + lr] = acc[i][j][r];
        }
    }
}

// ---------- fp32 [K][N] -> bf16-bits transposed [N][K] (tiled via LDS) ----------
__global__ __launch_bounds__(256) void tpose_cvt(const float* __restrict__ src,
                                                 unsigned short* __restrict__ dst,
                                                 int K, int N)
{
    __shared__ float t[32][33];
    int n0 = blockIdx.x * 32, k0 = blockIdx.y * 32;
    int tid = threadIdx.x;
    int r = tid >> 3, c4 = (tid & 7) * 4;
    float4 v = *(const float4*)&src[(long)(k0 + r) * N + n0 + c4];
    t[r][c4] = v.x; t[r][c4 + 1] = v.y; t[r][c4 + 2] = v.z; t[r][c4 + 3] = v.w;
    __syncthreads();
    ushort4 o;
    o.x = f2b(t[c4][r]);
    o.y = f2b(t[c4 + 1][r]);
    o.z = f2b(t[c4 + 2][r]);
    o.w = f2b(t[c4 + 3][r]);
    *(ushort4*)&dst[(long)(n0 + r) * K + k0 + c4] = o;
}

// ---------- fp32 [M][C] -> bf16-bits [Mpad][C] (zero pad rows >= M) ----------
__global__ void cvt_pad(const float* __restrict__ src, unsigned short* __restrict__ dst,
                        int M, int Mpad, int C)
{
    long i4 = ((long)blockIdx.x * 256 + threadIdx.x) * 4;
    if (i4 >= (long)Mpad * C) return;
    int row = (int)(i4 / C);
    ushort4 o = {0, 0, 0, 0};
    if (row < M) {
        float4 v = *(const float4*)&src[i4];
        o.x = f2b(v.x); o.y = f2b(v.y); o.z = f2b(v.z); o.w = f2b(v.w);
    }
    *(ushort4*)&dst[i4] = o;
}

// ---------- y * silu(z) -> bf16-bits [Mpad][C] ----------
__global__ void gate_cvt(const float* __restrict__ y, const float* __restrict__ z,
                         unsigned short* __restrict__ dst, int M, int Mpad, int C, int ldz)
{
    long i4 = ((long)blockIdx.x * 256 + threadIdx.x) * 4;
    if (i4 >= (long)Mpad * C) return;
    int row = (int)(i4 / C);
    int col = (int)(i4 - (long)row * C);
    ushort4 o = {0, 0, 0, 0};
    if (row < M) {
        float4 yv = *(const float4*)&y[i4];
        float4 zv = *(const float4*)&z[(long)row * ldz + col];
        o.x = f2b(yv.x * siluf(zv.x));
        o.y = f2b(yv.y * siluf(zv.y));
        o.z = f2b(yv.z * siluf(zv.z));
        o.w = f2b(yv.w * siluf(zv.w));
    }
    *(ushort4*)&dst[i4] = o;
}

// ---------- causal depthwise conv (k=4) + bias + silu ----------
__global__ void conv_silu_kernel(const float* __restrict__ xz, const float* __restrict__ w,
                                 const float* __restrict__ bias, float* __restrict__ out,
                                 int Bn, int L, int din, int ldx)
{
    int idx = blockIdx.x * 256 + threadIdx.x;
    int total = Bn * L * din;
    if (idx >= total) return;
    int c = idx % din;
    int r = idx / din;
    int t = r % L;
    int b = r / L;
    float acc = bias[c];
#pragma unroll
    for (int i = 0; i < 4; i++) {
        int tt = t - 3 + i;
        if (tt >= 0) acc += w[c * 4 + i] * xz[((long)(b * L + tt)) * ldx + c];
    }
    out[idx] = siluf(acc);
}

// ---------- selective scan (u/y may alias) ----------
// Channel-major LDS ([16][ST], ST ≡ 4 mod 32, rows 16B-aligned) so the
// compute phase loads 16 x ds_read_b128 per 16-step group instead of 64
// scalar ds_reads (u/dt broadcast across the 16 n-lanes; B/C <=2-way bank
// alias = free). DPP n-reduce; all FMA/add orders unchanged -> bit-identical.
template<int T>
__global__ __launch_bounds__(256) void scan_kernel(
    const float* u, const float* dt,
    const float* xdbl, const float* __restrict__ A_log,
    const float* __restrict__ Dp, float* y,
    int din, int L, int xld, int boff, int coff)
{
    constexpr int ST = ((T - 4 + 31) / 32) * 32 + 4;   // 64->68, 98->100
    __shared__ __align__(16) float dtc[16][ST], uc[16][ST];
    __shared__ __align__(16) float Bc[16][ST], Cc[16][ST], yc[16][ST];
    int tx = threadIdx.x;
    int dl = tx >> 4;
    int n = tx & 15;
    int dbase = blockIdx.x * 16;
    int dg = dbase + dl;
    int b = blockIdx.y;
    bool act = dg < din;
    float Acoef = act ? -__expf(A_log[dg * 16 + n]) : 0.f;
    float Dv = act ? Dp[dg] : 0.f;
    int nvalid = min(16, din - dbase);
    float h = 0.f;
    for (int c0 = 0; c0 < L; c0 += T) {
        int tcnt = min(T, L - c0);
        for (int i = tx; i < T * 16; i += 256) {
            int tt = i >> 4, c = i & 15;
            if (tt < tcnt) {
                long row = (long)b * L + c0 + tt;
                float uv = 0.f, dv = 0.f;
                if (c < nvalid) { uv = u[row * din + dbase + c]; dv = dt[row * din + dbase + c]; }
                uc[c][tt] = uv; dtc[c][tt] = dv;
                Bc[c][tt] = xdbl[row * xld + boff + c];
                Cc[c][tt] = xdbl[row * xld + coff + c];
            }
        }
        __syncthreads();
        int tt = 0;
        for (; tt + 16 <= tcnt; tt += 16) {
            float4 dt4[4], u4[4], B4[4], C4[4];
#pragma unroll
            for (int g = 0; g < 4; g++) {
                dt4[g] = *(const float4*)&dtc[dl][tt + g * 4];
                u4[g]  = *(const float4*)&uc[dl][tt + g * 4];
                B4[g]  = *(const float4*)&Bc[n][tt + g * 4];
                C4[g]  = *(const float4*)&Cc[n][tt + g * 4];
            }
            float pbuf[16];
#pragma unroll
            for (int g = 0; g < 4; g++) {
                float dts[4] = {dt4[g].x, dt4[g].y, dt4[g].z, dt4[g].w};
                float us[4]  = {u4[g].x, u4[g].y, u4[g].z, u4[g].w};
                float bs[4]  = {B4[g].x, B4[g].y, B4[g].z, B4[g].w};
                float cs[4]  = {C4[g].x, C4[g].y, C4[g].z, C4[g].w};
#pragma unroll
                for (int s = 0; s < 4; s++) {
                    float dA = __expf(dts[s] * Acoef);
                    h = dA * h + (dts[s] * us[s]) * bs[s];
                    pbuf[g * 4 + s] = h * cs[s];
                }
            }
#pragma unroll
            for (int q = 0; q < 16; q++) pbuf[q] = row16_sum(pbuf[q]);
            if (n == 0) {
#pragma unroll
                for (int g = 0; g < 4; g++) {
                    float4 y4;
                    y4.x = pbuf[g * 4 + 0] + Dv * u4[g].x;
                    y4.y = pbuf[g * 4 + 1] + Dv * u4[g].y;
                    y4.z = pbuf[g * 4 + 2] + Dv * u4[g].z;
                    y4.w = pbuf[g * 4 + 3] + Dv * u4[g].w;
                    *(float4*)&yc[dl][tt + g * 4] = y4;
                }
            }
        }
        for (; tt < tcnt; ++tt) {
            float dtv = dtc[dl][tt];
            float uv  = uc[dl][tt];
            float dA = __expf(dtv * Acoef);
            h = dA * h + (dtv * uv) * Bc[n][tt];
            float p = row16_sum(h * Cc[n][tt]);
            if (n == 0) yc[dl][tt] = p + Dv * uv;
        }
        __syncthreads();
        for (int i = tx; i < tcnt * 16; i += 256) {
            int tt2 = i >> 4, c = i & 15;
            if (c < nvalid) y[((long)b * L + c0 + tt2) * din + dbase + c] = yc[c][tt2];
        }
        __syncthreads();
    }
}

// ---------- row mean: one wave per row of score[8192][98] ----------
__global__ __launch_bounds__(256) void row_mean_kernel(const float* __restrict__ sc2,
                                                       float* __restrict__ means)
{
    int row = blockIdx.x * 4 + (threadIdx.x >> 6);
    int lane = threadIdx.x & 63;
    const float* p = sc2 + (long)row * 98;
    float s = p[lane];
    if (lane < 34) s += p[lane + 64];
    s += __shfl_xor(s, 1);
    s += __shfl_xor(s, 2);
    s += __shfl_xor(s, 4);
    s += __shfl_xor(s, 8);
    s += __shfl_xor(s, 16);
    s += __shfl_xor(s, 32);
    if (lane == 0) means[row] = s * (1.f / 98.f);
}

// ---------- softmax over k (1024) per batch, means -> s ----------
__global__ __launch_bounds__(256) void softmax1024_kernel(const float* __restrict__ means,
                                                          float* __restrict__ s)
{
    __shared__ float red[256];
    int b = blockIdx.x, tx = threadIdx.x;
    float v[4];
    float mx = -1e30f;
#pragma unroll
    for (int i = 0; i < 4; i++) {
        v[i] = means[b * 1024 + tx + i * 256];
        mx = fmaxf(mx, v[i]);
    }
    red[tx] = mx; __syncthreads();
    for (int st = 128; st > 0; st >>= 1) { if (tx < st) red[tx] = fmaxf(red[tx], red[tx + st]); __syncthreads(); }
    mx = red[0]; __syncthreads();
    float lsum = 0.f;
#pragma unroll
    for (int i = 0; i < 4; i++) { v[i] = __expf(v[i] - mx); lsum += v[i]; }
    red[tx] = lsum; __syncthreads();
    for (int st = 128; st > 0; st >>= 1) { if (tx < st) red[tx] += red[tx + st]; __syncthreads(); }
    float inv = 1.f / red[0];
#pragma unroll
    for (int i = 0; i < 4; i++) s[b * 1024 + tx + i * 256] = v[i] * inv;
}

// ---------- top-98 sequential selection (jax tie semantics) ----------
__global__ __launch_bounds__(256) void topk_select_kernel(const float* __restrict__ s,
                                                          int* __restrict__ ind,
                                                          float* __restrict__ vtopk)
{
    __shared__ unsigned long long arr[1024];
    __shared__ unsigned long long red[256];
    int b = blockIdx.x, tx = threadIdx.x;
    for (int k = tx; k < 1024; k += 256) {
        float v = s[b * 1024 + k];
        unsigned u = __float_as_uint(v);
        u = (u & 0x80000000u) ? ~u : (u | 0x80000000u);
        arr[k] = ((unsigned long long)u << 32) | (unsigned)(~k);
    }
    __syncthreads();
    for (int r = 0; r < 98; ++r) {
        unsigned long long m = 0ull;
        for (int k = tx; k < 1024; k += 256) m = (arr[k] > m) ? arr[k] : m;
        red[tx] = m; __syncthreads();
        for (int st = 128; st > 0; st >>= 1) {
            if (tx < st && red[tx + st] > red[tx]) red[tx] = red[tx + st];
            __syncthreads();
        }
        unsigned long long best = red[0];
        if (tx == 0) {
            unsigned lo = (unsigned)(best & 0xffffffffu);
            int kidx = (int)(~lo);
            unsigned ub = (unsigned)(best >> 32);
            unsigned fb = (ub & 0x80000000u) ? (ub ^ 0x80000000u) : ~ub;
            ind[b * 98 + r] = kidx;
            vtopk[b * 98 + r] = __uint_as_float(fb);
            arr[kidx] = 0ull;
        }
        __syncthreads();
    }
}

// ---------- gather: h[b,j,:] = img[j,:] + kf[b,:,ind]*v ----------
__global__ void gather_kernel(const float* __restrict__ img, const float* __restrict__ kf,
                              const int* __restrict__ ind, const float* __restrict__ vtopk,
                              float* __restrict__ h)
{
    int j = blockIdx.x, b = blockIdx.y;
    int kidx = ind[b * 98 + j];
    float v = vtopk[b * 98 + j];
    long hbase = ((long)b * 98 + j) * 2048;
    const float* kfb = kf + (long)b * 2048 * 1024 + kidx;
    for (int d = threadIdx.x; d < 2048; d += 256)
        h[hbase + d] = img[(long)j * 2048 + d] + kfb[(long)d * 1024] * v;
}

// ---------- host launch ----------
extern "C" void kernel_launch(void* const* d_in, const int* in_sizes, int n_in,
                              void* d_out, int out_size, void* d_ws, size_t ws_size,
                              hipStream_t stream)
{
    const float* imgF      = (const float*)d_in[0];
    const float* kf        = (const float*)d_in[1];
    const float* a_in_w    = (const float*)d_in[2];
    const float* a_conv_w  = (const float*)d_in[3];
    const float* a_conv_b  = (const float*)d_in[4];
    const float* a_xproj_w = (const float*)d_in[5];
    const float* a_dt_w    = (const float*)d_in[6];
    const float* a_dt_b    = (const float*)d_in[7];
    const float* a_A_log   = (const float*)d_in[8];
    const float* a_D       = (const float*)d_in[9];
    const float* a_out_w   = (const float*)d_in[10];
    const float* c_in_w    = (const float*)d_in[11];
    const float* c_conv_w  = (const float*)d_in[12];
    const float* c_conv_b  = (const float*)d_in[13];
    const float* c_xproj_w = (const float*)d_in[14];
    const float* c_dt_w    = (const float*)d_in[15];
    const float* c_dt_b    = (const float*)d_in[16];
    const float* c_A_log   = (const float*)d_in[17];
    const float* c_D       = (const float*)d_in[18];
    const float* c_out_w   = (const float*)d_in[19];

    float* fout = (float*)d_out;

    float* ws = (float*)d_ws;
    float* h_buf  = ws;                      // 1,605,632 floats
    float* S      = ws + 1605632;
    // stage A
    float* score  = S;                       // 802,816 (reused as score2)
    float* xz_a   = S + 802816;              // 3,211,264
    float* xi_a   = S + 4014080;             // 1,605,632 (scan in-place)
    float* xdbl_a = S + 5619712;             // 319,488
    float* dt_a   = S + 5939200;             // 1,605,632
    float* sbuf   = S + 7544832;             // 8,192
    int*   indb   = (int*)(S + 7553024);     // 784
    float* vtopk  = S + 7553808;             // 784
    // stage C (aliases stage A region)
    float* xz_c   = S;                       // 6,422,528
    float* xi_c   = S + 6422528;             // 3,211,264 (scan in-place)
    float* xdbl_c = S + 9633792;             // 125,440
    float* dt_c   = S + 9759232;             // 3,211,264
    // bf16 scratch (beyond the fp32 region: base float offset 14,576,128)
    unsigned short* cwbf  = (unsigned short*)(ws + 14576128);          // 16,777,216 bf16
    unsigned short* h_bf  = (unsigned short*)(ws + 14576128 + 8388608);// 1,835,008 bf16
    unsigned short* yz_bf = (unsigned short*)(ws + 14576128 + 9306112);// 3,670,016 bf16
    // split-K partials:
    //  - step 1 (stage A): bf16 region is dead until step 11 -> reuse it.
    //    8 chunks x 802,816 = 6,422,528 floats at 14,576,128..20,998,656.
    float* CpartS1 = ws + 14576128;
    //  - step 13 (stage C): upper half of cwbf region is dead between
    //    mfma_gemm #11 and tpose_cvt #16. 16 x 784 x 160 floats.
    float* Cpart  = ws + 18770432;
    // means scratch for step 8: dt_a region is dead after scan_kernel (step 6)
    float* means  = dt_a;
    // total ws: 25,717,248 floats ~= 103 MB

    // ===== stage A (fp32) =====
    // 1. score[b] = kf[b]^T @ imgF^T : specialized split-K x8 (2048 blocks)
    gemm_s1<<<dim3(16, 2, 64), 256, 0, stream>>>(kf, imgF, CpartS1);
    sk_reduce<<<3136, 256, 0, stream>>>(CpartS1, score, 802816L, 8);

    gemm64<false, false, false, 0><<<dim3(128, 7, 1), 256, 0, stream>>>(
        score, a_in_w, xz_a, nullptr, nullptr, 8192, 392, 98, 98, 392, 392, 0, 0L, 0L, 0L);
    conv_silu_kernel<<<6272, 256, 0, stream>>>(xz_a, a_conv_w, a_conv_b, xi_a, 8, 1024, 196, 392);
    gemm64<false, false, false, 0><<<dim3(128, 1, 1), 256, 0, stream>>>(
        xi_a, a_xproj_w, xdbl_a, nullptr, nullptr, 8192, 39, 196, 196, 39, 39, 0, 0L, 0L, 0L);
    gemm64<false, false, false, 1><<<dim3(128, 4, 1), 256, 0, stream>>>(
        xdbl_a, a_dt_w, dt_a, nullptr, a_dt_b, 8192, 196, 7, 39, 196, 196, 0, 0L, 0L, 0L);
    scan_kernel<64><<<dim3(13, 8, 1), 256, 0, stream>>>(
        xi_a, dt_a, xdbl_a, a_A_log, a_D, xi_a, 196, 1024, 39, 7, 23);
    gemm64<false, false, true, 0><<<dim3(128, 2, 1), 256, 0, stream>>>(
        xi_a, a_out_w, score, xz_a + 196, nullptr, 8192, 98, 196, 196, 98, 98, 392, 0L, 0L, 0L);
    // 8. mean over n + softmax over k (parallel mean, tiny softmax)
    row_mean_kernel<<<2048, 256, 0, stream>>>(score, means);
    softmax1024_kernel<<<8, 256, 0, stream>>>(means, sbuf);
    topk_select_kernel<<<8, 256, 0, stream>>>(sbuf, indb, vtopk);
    gather_kernel<<<dim3(98, 8, 1), 256, 0, stream>>>(imgF, kf, indb, vtopk, h_buf);

    // ===== stage C =====
    // 11. xz_c = h @ c_in_w  (bf16 MFMA)
    tpose_cvt<<<dim3(256, 64, 1), 256, 0, stream>>>(c_in_w, cwbf, 2048, 8192);
    cvt_pad<<<1792, 256, 0, stream>>>(h_buf, h_bf, 784, 896, 2048);
    mfma_gemm<<<dim3(7, 64, 1), 256, 0, stream>>>(h_bf, cwbf, xz_c, 784, 8192, 2048, 8192);

    // 12. conv + silu -> xi_c
    conv_silu_kernel<<<12544, 256, 0, stream>>>(xz_c, c_conv_w, c_conv_b, xi_c, 8, 98, 4096, 8192);

    // 13. xdbl_c = xi_c @ c_xproj_w (fp32, split-K x16)
    gemm64_sk<<<dim3(13, 3, 16), 256, 0, stream>>>(
        xi_c, c_xproj_w, Cpart, 784, 160, 4096, 4096, 160, 256);
    sk_reduce<<<490, 256, 0, stream>>>(Cpart, xdbl_c, 125440L, 16);

    // 14. dt_c = softplus(xdbl_c[:, :128] @ c_dt_w + c_dt_b) (fp32)
    gemm64<false, false, false, 1><<<dim3(13, 64, 1), 256, 0, stream>>>(
        xdbl_c, c_dt_w, dt_c, nullptr, c_dt_b, 784, 4096, 128, 160, 4096, 4096, 0, 0L, 0L, 0L);

    // 15. selective scan C (in-place)
    scan_kernel<98><<<dim3(256, 8, 1), 256, 0, stream>>>(
        xi_c, dt_c, xdbl_c, c_A_log, c_D, xi_c, 4096, 98, 160, 128, 144);

    // 16. out = (y_c * silu(z_c)) @ c_out_w  (bf16 MFMA, direct to d_out)
    gate_cvt<<<3584, 256, 0, stream>>>(xi_c, xz_c + 4096, yz_bf, 784, 896, 4096, 8192);
    tpose_cvt<<<dim3(64, 128, 1), 256, 0, stream>>>(c_out_w, cwbf, 4096, 2048);
    mfma_gemm<<<dim3(7, 16, 1), 256, 0, stream>>>(yz_bf, cwbf, fout, 784, 2048, 4096, 2048);
}

// Round 11
// 855.870 us; speedup vs baseline: 2.4276x; 1.0934x over previous
//
#include <hip/hip_runtime.h>
#include <hip/hip_bf16.h>
#include <math.h>

typedef __attribute__((ext_vector_type(8))) short short8;
typedef __attribute__((ext_vector_type(4))) float floatx4;

// ---------- helpers ----------
__device__ __forceinline__ float siluf(float x) {
    float e = __expf(-fabsf(x));
    float s = (x >= 0.f) ? 1.f / (1.f + e) : e / (1.f + e);
    return x * s;
}
__device__ __forceinline__ float softplusf(float x) {
    if (x > 20.f) return x;
    if (x < -20.f) return __expf(x);
    return log1pf(__expf(x));
}
__device__ __forceinline__ unsigned short f2b(float v) {
    __hip_bfloat16 b = __float2bfloat16(v);
    unsigned short u;
    __builtin_memcpy(&u, &b, 2);
    return u;
}
// DPP lane-add: x += x[neighbor] per 16-lane row, VALU-speed (no LDS pipe).
template<int CTRL>
__device__ __forceinline__ float dpp_add(float x) {
    int yi = __builtin_amdgcn_mov_dpp(__float_as_int(x), CTRL, 0xF, 0xF, true);
    return x + __int_as_float(yi);
}
// Sum over the 16-lane row (n-dim). For lane (n==0) the add order is
// bit-identical to the xor1/2/4/8 butterfly: ((p0+p1)+(p2+p3)) per quad,
// then (s0+s1)+(s2+s3) via row_ror:4 + row_ror:8.
__device__ __forceinline__ float row16_sum(float p) {
    p = dpp_add<0xB1>(p);    // quad_perm [1,0,3,2]  : xor 1
    p = dpp_add<0x4E>(p);    // quad_perm [2,3,0,1]  : xor 2
    p = dpp_add<0x124>(p);   // row_ror:4
    p = dpp_add<0x128>(p);   // row_ror:8
    return p;
}

// ---------- generic 64x64 tiled GEMM (fp32) — LDS rows padded to 68 ----------
// (64-stride rows put consecutive-kk staging writes all in one bank: 16-way
//  conflict. 68 = bank stride 4, rows stay 16B-aligned.)
template<bool ACOL, bool BCOL, bool AMUL, int EPI>
__global__ __launch_bounds__(256) void gemm64(
    const float* __restrict__ A, const float* __restrict__ Bw, float* __restrict__ C,
    const float* __restrict__ A2, const float* __restrict__ bias,
    int M, int N, int K, int lda, int ldb, int ldc, int lda2,
    long batA, long batB, long batC)
{
    __shared__ __align__(16) float As[16][68];
    __shared__ __align__(16) float Bs[16][68];
    int tx = threadIdx.x;
    int m0 = blockIdx.x * 64, n0 = blockIdx.y * 64;
    A += blockIdx.z * batA; Bw += blockIdx.z * batB; C += blockIdx.z * batC;
    int tm = tx >> 4, tn = tx & 15;
    float acc[4][4] = {};
    for (int k0 = 0; k0 < K; k0 += 16) {
        for (int i = tx; i < 1024; i += 256) {
            int mm, kk;
            if (ACOL) { mm = i & 63; kk = i >> 6; } else { kk = i & 15; mm = i >> 4; }
            int m = m0 + mm, k = k0 + kk;
            float v = 0.f;
            if (m < M && k < K) {
                long ia = ACOL ? ((long)k * lda + m) : ((long)m * lda + k);
                v = A[ia];
                if (AMUL) v *= siluf(A2[(long)m * lda2 + k]);
            }
            As[kk][mm] = v;
        }
        for (int i = tx; i < 1024; i += 256) {
            int nn, kk;
            if (BCOL) { kk = i & 15; nn = i >> 4; } else { nn = i & 63; kk = i >> 6; }
            int n = n0 + nn, k = k0 + kk;
            float v = 0.f;
            if (n < N && k < K) {
                long ib = BCOL ? ((long)n * ldb + k) : ((long)k * ldb + n);
                v = Bw[ib];
            }
            Bs[kk][nn] = v;
        }
        __syncthreads();
#pragma unroll
        for (int kk = 0; kk < 16; ++kk) {
            float4 av = *(const float4*)&As[kk][tm * 4];
            float4 bv = *(const float4*)&Bs[kk][tn * 4];
            float a[4] = {av.x, av.y, av.z, av.w};
            float b[4] = {bv.x, bv.y, bv.z, bv.w};
#pragma unroll
            for (int i = 0; i < 4; i++)
#pragma unroll
                for (int j = 0; j < 4; j++) acc[i][j] += a[i] * b[j];
        }
        __syncthreads();
    }
#pragma unroll
    for (int i = 0; i < 4; i++) {
        int m = m0 + tm * 4 + i;
        if (m >= M) continue;
#pragma unroll
        for (int j = 0; j < 4; j++) {
            int n = n0 + tn * 4 + j;
            if (n >= N) continue;
            float v = acc[i][j];
            if (EPI == 1) v = softplusf(v + bias[n]);
            C[(long)m * ldc + n] = v;
        }
    }
}

// ---------- split-K fp32 GEMM (row-major A,B): Cpart[z] = partial ----------
__global__ __launch_bounds__(256) void gemm64_sk(
    const float* __restrict__ A, const float* __restrict__ Bw, float* __restrict__ Cpart,
    int M, int N, int K, int lda, int ldb, int kch)
{
    __shared__ __align__(16) float As[16][68];
    __shared__ __align__(16) float Bs[16][68];
    int tx = threadIdx.x;
    int m0 = blockIdx.x * 64, n0 = blockIdx.y * 64;
    int kbeg = blockIdx.z * kch;
    int kend = min(kbeg + kch, K);
    Cpart += (long)blockIdx.z * M * N;
    int tm = tx >> 4, tn = tx & 15;
    float acc[4][4] = {};
    for (int k0 = kbeg; k0 < kend; k0 += 16) {
        for (int i = tx; i < 1024; i += 256) {
            int kk = i & 15, mm = i >> 4;
            int m = m0 + mm, k = k0 + kk;
            As[kk][mm] = (m < M && k < kend) ? A[(long)m * lda + k] : 0.f;
        }
        for (int i = tx; i < 1024; i += 256) {
            int nn = i & 63, kk = i >> 6;
            int n = n0 + nn, k = k0 + kk;
            Bs[kk][nn] = (n < N && k < kend) ? Bw[(long)k * ldb + n] : 0.f;
        }
        __syncthreads();
#pragma unroll
        for (int kk = 0; kk < 16; ++kk) {
            float4 av = *(const float4*)&As[kk][tm * 4];
            float4 bv = *(const float4*)&Bs[kk][tn * 4];
            float a[4] = {av.x, av.y, av.z, av.w};
            float b[4] = {bv.x, bv.y, bv.z, bv.w};
#pragma unroll
            for (int i = 0; i < 4; i++)
#pragma unroll
                for (int j = 0; j < 4; j++) acc[i][j] += a[i] * b[j];
        }
        __syncthreads();
    }
#pragma unroll
    for (int i = 0; i < 4; i++) {
        int m = m0 + tm * 4 + i;
        if (m >= M) continue;
#pragma unroll
        for (int j = 0; j < 4; j++) {
            int n = n0 + tn * 4 + j;
            if (n >= N) continue;
            Cpart[(long)m * N + n] = acc[i][j];
        }
    }
}

// ---------- step-1 specialized split-K GEMM ----------
// score[b][q][n] = sum_d kf[b][d][q] * img[n][d]; M=1024,N=98,K=2048.
// grid (16, 2, 64): z = bz*8 + kz, kch=256. Vectorized float4 staging,
// padded LDS. FMA order per thread identical to generic path.
__global__ __launch_bounds__(256) void gemm_s1(
    const float* __restrict__ kf, const float* __restrict__ img,
    float* __restrict__ Cpart)
{
    __shared__ __align__(16) float As[16][68];
    __shared__ __align__(16) float Bs[16][68];
    int tx = threadIdx.x;
    int m0 = blockIdx.x * 64, n0 = blockIdx.y * 64;
    int bz = blockIdx.z >> 3, kz = blockIdx.z & 7;
    const float* A = kf + (long)bz * 2048 * 1024;      // [d][q] col-major A
    float* Cp = Cpart + (long)kz * 802816 + (long)bz * 100352;
    int kbeg = kz * 256;
    int tm = tx >> 4, tn = tx & 15;
    int akk = tx >> 4, amq = (tx & 15) * 4;            // A stage: 16 k-rows x 64 m
    int bnn = tx >> 2, bkq = (tx & 3) * 4;             // B stage: 64 n-rows x 16 k
    bool bvalid = (n0 + bnn) < 98;
    const float* Bp = img + (long)(n0 + bnn) * 2048;
    float acc[4][4] = {};
    for (int k0 = kbeg; k0 < kbeg + 256; k0 += 16) {
        float4 av = *(const float4*)&A[(long)(k0 + akk) * 1024 + m0 + amq];
        float4 bv = bvalid ? *(const float4*)&Bp[k0 + bkq] : (float4){0.f, 0.f, 0.f, 0.f};
        __syncthreads();
        *(float4*)&As[akk][amq] = av;
        Bs[bkq + 0][bnn] = bv.x;
        Bs[bkq + 1][bnn] = bv.y;
        Bs[bkq + 2][bnn] = bv.z;
        Bs[bkq + 3][bnn] = bv.w;
        __syncthreads();
#pragma unroll
        for (int kk = 0; kk < 16; ++kk) {
            float4 a4 = *(const float4*)&As[kk][tm * 4];
            float4 b4 = *(const float4*)&Bs[kk][tn * 4];
            float a[4] = {a4.x, a4.y, a4.z, a4.w};
            float b[4] = {b4.x, b4.y, b4.z, b4.w};
#pragma unroll
            for (int i = 0; i < 4; i++)
#pragma unroll
                for (int j = 0; j < 4; j++) acc[i][j] += a[i] * b[j];
        }
    }
#pragma unroll
    for (int i = 0; i < 4; i++) {
        int m = m0 + tm * 4 + i;
#pragma unroll
        for (int j = 0; j < 4; j++) {
            int n = n0 + tn * 4 + j;
            if (n < 98) Cp[(long)m * 98 + n] = acc[i][j];
        }
    }
}

// ---------- sum nz split-K partial buffers ----------
__global__ void sk_reduce(const float* __restrict__ Cpart, float* __restrict__ C,
                          long len, int nz)
{
    long i = (long)blockIdx.x * 256 + threadIdx.x;
    if (i >= len) return;
    float s = 0.f;
    for (int z = 0; z < nz; z++) s += Cpart[(long)z * len + i];
    C[i] = s;
}

// ---------- bf16 MFMA GEMM with split-K + register prefetch ----------
// Abf: bf16 bits, row-major [Mpad][K]; Bbf: B TRANSPOSED [N][K].
// 128x128 tile, 4 waves, 16x16x32 MFMA, BK=32. blockIdx.z = K-chunk;
// partial tile written to Cp + z*partStride (partStride=0, gridDim.z=1
// -> plain GEMM). Next tile's global loads issued right after the LDS
// write so their latency hides under ds_read+MFMA (was fully exposed).
__global__ __launch_bounds__(256) void mfma_gemm(
    const unsigned short* __restrict__ Abf, const unsigned short* __restrict__ Bbf,
    float* __restrict__ Cp, int M, int N, int K, int ldc, int kch, long partStride)
{
    __shared__ __align__(16) short As[128 * 40];   // +8 pad kills ds_read conflicts
    __shared__ __align__(16) short Bs[128 * 40];
    int tid = threadIdx.x;
    int m0 = blockIdx.x * 128, n0 = blockIdx.y * 128;
    int kbeg = blockIdx.z * kch;
    int kend = kbeg + kch;
    float* C = Cp + (long)blockIdx.z * partStride;
    int w = tid >> 6, l = tid & 63;
    int wm = (w >> 1) * 64, wn = (w & 1) * 64;
    int lr = l & 15, lq = l >> 4;
    int row0 = tid >> 2, kc = (tid & 3) * 8;
    floatx4 acc[4][4];
#pragma unroll
    for (int i = 0; i < 4; i++)
#pragma unroll
        for (int j = 0; j < 4; j++) acc[i][j] = (floatx4){0.f, 0.f, 0.f, 0.f};
    const unsigned short* Ap  = Abf + (long)(m0 + row0) * K + kc;
    const unsigned short* Ap2 = Abf + (long)(m0 + row0 + 64) * K + kc;
    const unsigned short* Bp  = Bbf + (long)(n0 + row0) * K + kc;
    const unsigned short* Bp2 = Bbf + (long)(n0 + row0 + 64) * K + kc;
    uint4 a0 = *(const uint4*)(Ap + kbeg);
    uint4 a1 = *(const uint4*)(Ap2 + kbeg);
    uint4 b0 = *(const uint4*)(Bp + kbeg);
    uint4 b1 = *(const uint4*)(Bp2 + kbeg);
    for (int k0 = kbeg; k0 < kend; k0 += 32) {
        __syncthreads();
        *(uint4*)&As[row0 * 40 + kc] = a0;
        *(uint4*)&As[(row0 + 64) * 40 + kc] = a1;
        *(uint4*)&Bs[row0 * 40 + kc] = b0;
        *(uint4*)&Bs[(row0 + 64) * 40 + kc] = b1;
        int kn = k0 + 32;
        if (kn < kend) {                 // wave-uniform; prefetch next tile
            a0 = *(const uint4*)(Ap + kn);
            a1 = *(const uint4*)(Ap2 + kn);
            b0 = *(const uint4*)(Bp + kn);
            b1 = *(const uint4*)(Bp2 + kn);
        }
        __syncthreads();
        short8 af[4], bfr[4];
#pragma unroll
        for (int i = 0; i < 4; i++) af[i]  = *(const short8*)&As[(wm + i * 16 + lr) * 40 + lq * 8];
#pragma unroll
        for (int i = 0; i < 4; i++) bfr[i] = *(const short8*)&Bs[(wn + i * 16 + lr) * 40 + lq * 8];
#pragma unroll
        for (int i = 0; i < 4; i++)
#pragma unroll
            for (int j = 0; j < 4; j++)
                acc[i][j] = __builtin_amdgcn_mfma_f32_16x16x32_bf16(af[i], bfr[j], acc[i][j], 0, 0, 0);
    }
#pragma unroll
    for (int i = 0; i < 4; i++) {
#pragma unroll
        for (int r = 0; r < 4; r++) {
            int m = m0 + wm + i * 16 + lq * 4 + r;
            if (m >= M) continue;
#pragma unroll
            for (int j = 0; j < 4; j++)
                C[(long)m * ldc + n0 + wn + j * 16 + lr] = acc[i][j][r];
        }
    }
}

// ---------- fp32 [K][N] -> bf16-bits transposed [N][K] (tiled via LDS) ----------
__global__ __launch_bounds__(256) void tpose_cvt(const float* __restrict__ src,
                                                 unsigned short* __restrict__ dst,
                                                 int K, int N)
{
    __shared__ float t[32][33];
    int n0 = blockIdx.x * 32, k0 = blockIdx.y * 32;
    int tid = threadIdx.x;
    int r = tid >> 3, c4 = (tid & 7) * 4;
    float4 v = *(const float4*)&src[(long)(k0 + r) * N + n0 + c4];
    t[r][c4] = v.x; t[r][c4 + 1] = v.y; t[r][c4 + 2] = v.z; t[r][c4 + 3] = v.w;
    __syncthreads();
    ushort4 o;
    o.x = f2b(t[c4][r]);
    o.y = f2b(t[c4 + 1][r]);
    o.z = f2b(t[c4 + 2][r]);
    o.w = f2b(t[c4 + 3][r]);
    *(ushort4*)&dst[(long)(n0 + r) * K + k0 + c4] = o;
}

// ---------- fp32 [M][C] -> bf16-bits [Mpad][C] (zero pad rows >= M) ----------
__global__ void cvt_pad(const float* __restrict__ src, unsigned short* __restrict__ dst,
                        int M, int Mpad, int C)
{
    long i4 = ((long)blockIdx.x * 256 + threadIdx.x) * 4;
    if (i4 >= (long)Mpad * C) return;
    int row = (int)(i4 / C);
    ushort4 o = {0, 0, 0, 0};
    if (row < M) {
        float4 v = *(const float4*)&src[i4];
        o.x = f2b(v.x); o.y = f2b(v.y); o.z = f2b(v.z); o.w = f2b(v.w);
    }
    *(ushort4*)&dst[i4] = o;
}

// ---------- y * silu(z) -> bf16-bits [Mpad][C] ----------
__global__ void gate_cvt(const float* __restrict__ y, const float* __restrict__ z,
                         unsigned short* __restrict__ dst, int M, int Mpad, int C, int ldz)
{
    long i4 = ((long)blockIdx.x * 256 + threadIdx.x) * 4;
    if (i4 >= (long)Mpad * C) return;
    int row = (int)(i4 / C);
    int col = (int)(i4 - (long)row * C);
    ushort4 o = {0, 0, 0, 0};
    if (row < M) {
        float4 yv = *(const float4*)&y[i4];
        float4 zv = *(const float4*)&z[(long)row * ldz + col];
        o.x = f2b(yv.x * siluf(zv.x));
        o.y = f2b(yv.y * siluf(zv.y));
        o.z = f2b(yv.z * siluf(zv.z));
        o.w = f2b(yv.w * siluf(zv.w));
    }
    *(ushort4*)&dst[i4] = o;
}

// ---------- causal depthwise conv (k=4) + bias + silu ----------
__global__ void conv_silu_kernel(const float* __restrict__ xz, const float* __restrict__ w,
                                 const float* __restrict__ bias, float* __restrict__ out,
                                 int Bn, int L, int din, int ldx)
{
    int idx = blockIdx.x * 256 + threadIdx.x;
    int total = Bn * L * din;
    if (idx >= total) return;
    int c = idx % din;
    int r = idx / din;
    int t = r % L;
    int b = r / L;
    float acc = bias[c];
#pragma unroll
    for (int i = 0; i < 4; i++) {
        int tt = t - 3 + i;
        if (tt >= 0) acc += w[c * 4 + i] * xz[((long)(b * L + tt)) * ldx + c];
    }
    out[idx] = siluf(acc);
}

// ---------- selective scan (u/y may alias) ----------
// Channel-major LDS ([16][ST], ST ≡ 4 mod 32, rows 16B-aligned) so the
// compute phase loads 16 x ds_read_b128 per 16-step group instead of 64
// scalar ds_reads (u/dt broadcast across the 16 n-lanes; B/C <=2-way bank
// alias = free). DPP n-reduce; all FMA/add orders unchanged -> bit-identical.
template<int T>
__global__ __launch_bounds__(256) void scan_kernel(
    const float* u, const float* dt,
    const float* xdbl, const float* __restrict__ A_log,
    const float* __restrict__ Dp, float* y,
    int din, int L, int xld, int boff, int coff)
{
    constexpr int ST = ((T - 4 + 31) / 32) * 32 + 4;   // 64->68, 98->100
    __shared__ __align__(16) float dtc[16][ST], uc[16][ST];
    __shared__ __align__(16) float Bc[16][ST], Cc[16][ST], yc[16][ST];
    int tx = threadIdx.x;
    int dl = tx >> 4;
    int n = tx & 15;
    int dbase = blockIdx.x * 16;
    int dg = dbase + dl;
    int b = blockIdx.y;
    bool act = dg < din;
    float Acoef = act ? -__expf(A_log[dg * 16 + n]) : 0.f;
    float Dv = act ? Dp[dg] : 0.f;
    int nvalid = min(16, din - dbase);
    float h = 0.f;
    for (int c0 = 0; c0 < L; c0 += T) {
        int tcnt = min(T, L - c0);
        for (int i = tx; i < T * 16; i += 256) {
            int tt = i >> 4, c = i & 15;
            if (tt < tcnt) {
                long row = (long)b * L + c0 + tt;
                float uv = 0.f, dv = 0.f;
                if (c < nvalid) { uv = u[row * din + dbase + c]; dv = dt[row * din + dbase + c]; }
                uc[c][tt] = uv; dtc[c][tt] = dv;
                Bc[c][tt] = xdbl[row * xld + boff + c];
                Cc[c][tt] = xdbl[row * xld + coff + c];
            }
        }
        __syncthreads();
        int tt = 0;
        for (; tt + 16 <= tcnt; tt += 16) {
            float4 dt4[4], u4[4], B4[4], C4[4];
#pragma unroll
            for (int g = 0; g < 4; g++) {
                dt4[g] = *(const float4*)&dtc[dl][tt + g * 4];
                u4[g]  = *(const float4*)&uc[dl][tt + g * 4];
                B4[g]  = *(const float4*)&Bc[n][tt + g * 4];
                C4[g]  = *(const float4*)&Cc[n][tt + g * 4];
            }
            float pbuf[16];
#pragma unroll
            for (int g = 0; g < 4; g++) {
                float dts[4] = {dt4[g].x, dt4[g].y, dt4[g].z, dt4[g].w};
                float us[4]  = {u4[g].x, u4[g].y, u4[g].z, u4[g].w};
                float bs[4]  = {B4[g].x, B4[g].y, B4[g].z, B4[g].w};
                float cs[4]  = {C4[g].x, C4[g].y, C4[g].z, C4[g].w};
#pragma unroll
                for (int s = 0; s < 4; s++) {
                    float dA = __expf(dts[s] * Acoef);
                    h = dA * h + (dts[s] * us[s]) * bs[s];
                    pbuf[g * 4 + s] = h * cs[s];
                }
            }
#pragma unroll
            for (int q = 0; q < 16; q++) pbuf[q] = row16_sum(pbuf[q]);
            if (n == 0) {
#pragma unroll
                for (int g = 0; g < 4; g++) {
                    float4 y4;
                    y4.x = pbuf[g * 4 + 0] + Dv * u4[g].x;
                    y4.y = pbuf[g * 4 + 1] + Dv * u4[g].y;
                    y4.z = pbuf[g * 4 + 2] + Dv * u4[g].z;
                    y4.w = pbuf[g * 4 + 3] + Dv * u4[g].w;
                    *(float4*)&yc[dl][tt + g * 4] = y4;
                }
            }
        }
        for (; tt < tcnt; ++tt) {
            float dtv = dtc[dl][tt];
            float uv  = uc[dl][tt];
            float dA = __expf(dtv * Acoef);
            h = dA * h + (dtv * uv) * Bc[n][tt];
            float p = row16_sum(h * Cc[n][tt]);
            if (n == 0) yc[dl][tt] = p + Dv * uv;
        }
        __syncthreads();
        for (int i = tx; i < tcnt * 16; i += 256) {
            int tt2 = i >> 4, c = i & 15;
            if (c < nvalid) y[((long)b * L + c0 + tt2) * din + dbase + c] = yc[c][tt2];
        }
        __syncthreads();
    }
}

// ---------- row mean: one wave per row of score[8192][98] ----------
__global__ __launch_bounds__(256) void row_mean_kernel(const float* __restrict__ sc2,
                                                       float* __restrict__ means)
{
    int row = blockIdx.x * 4 + (threadIdx.x >> 6);
    int lane = threadIdx.x & 63;
    const float* p = sc2 + (long)row * 98;
    float s = p[lane];
    if (lane < 34) s += p[lane + 64];
    s += __shfl_xor(s, 1);
    s += __shfl_xor(s, 2);
    s += __shfl_xor(s, 4);
    s += __shfl_xor(s, 8);
    s += __shfl_xor(s, 16);
    s += __shfl_xor(s, 32);
    if (lane == 0) means[row] = s * (1.f / 98.f);
}

// ---------- softmax over k (1024) per batch, means -> s ----------
__global__ __launch_bounds__(256) void softmax1024_kernel(const float* __restrict__ means,
                                                          float* __restrict__ s)
{
    __shared__ float red[256];
    int b = blockIdx.x, tx = threadIdx.x;
    float v[4];
    float mx = -1e30f;
#pragma unroll
    for (int i = 0; i < 4; i++) {
        v[i] = means[b * 1024 + tx + i * 256];
        mx = fmaxf(mx, v[i]);
    }
    red[tx] = mx; __syncthreads();
    for (int st = 128; st > 0; st >>= 1) { if (tx < st) red[tx] = fmaxf(red[tx], red[tx + st]); __syncthreads(); }
    mx = red[0]; __syncthreads();
    float lsum = 0.f;
#pragma unroll
    for (int i = 0; i < 4; i++) { v[i] = __expf(v[i] - mx); lsum += v[i]; }
    red[tx] = lsum; __syncthreads();
    for (int st = 128; st > 0; st >>= 1) { if (tx < st) red[tx] += red[tx + st]; __syncthreads(); }
    float inv = 1.f / red[0];
#pragma unroll
    for (int i = 0; i < 4; i++) s[b * 1024 + tx + i * 256] = v[i] * inv;
}

// ---------- top-98 sequential selection (jax tie semantics) ----------
__global__ __launch_bounds__(256) void topk_select_kernel(const float* __restrict__ s,
                                                          int* __restrict__ ind,
                                                          float* __restrict__ vtopk)
{
    __shared__ unsigned long long arr[1024];
    __shared__ unsigned long long red[256];
    int b = blockIdx.x, tx = threadIdx.x;
    for (int k = tx; k < 1024; k += 256) {
        float v = s[b * 1024 + k];
        unsigned u = __float_as_uint(v);
        u = (u & 0x80000000u) ? ~u : (u | 0x80000000u);
        arr[k] = ((unsigned long long)u << 32) | (unsigned)(~k);
    }
    __syncthreads();
    for (int r = 0; r < 98; ++r) {
        unsigned long long m = 0ull;
        for (int k = tx; k < 1024; k += 256) m = (arr[k] > m) ? arr[k] : m;
        red[tx] = m; __syncthreads();
        for (int st = 128; st > 0; st >>= 1) {
            if (tx < st && red[tx + st] > red[tx]) red[tx] = red[tx + st];
            __syncthreads();
        }
        unsigned long long best = red[0];
        if (tx == 0) {
            unsigned lo = (unsigned)(best & 0xffffffffu);
            int kidx = (int)(~lo);
            unsigned ub = (unsigned)(best >> 32);
            unsigned fb = (ub & 0x80000000u) ? (ub ^ 0x80000000u) : ~ub;
            ind[b * 98 + r] = kidx;
            vtopk[b * 98 + r] = __uint_as_float(fb);
            arr[kidx] = 0ull;
        }
        __syncthreads();
    }
}

// ---------- gather: h[b,j,:] = img[j,:] + kf[b,:,ind]*v ----------
__global__ void gather_kernel(const float* __restrict__ img, const float* __restrict__ kf,
                              const int* __restrict__ ind, const float* __restrict__ vtopk,
                              float* __restrict__ h)
{
    int j = blockIdx.x, b = blockIdx.y;
    int kidx = ind[b * 98 + j];
    float v = vtopk[b * 98 + j];
    long hbase = ((long)b * 98 + j) * 2048;
    const float* kfb = kf + (long)b * 2048 * 1024 + kidx;
    for (int d = threadIdx.x; d < 2048; d += 256)
        h[hbase + d] = img[(long)j * 2048 + d] + kfb[(long)d * 1024] * v;
}

// ---------- host launch ----------
extern "C" void kernel_launch(void* const* d_in, const int* in_sizes, int n_in,
                              void* d_out, int out_size, void* d_ws, size_t ws_size,
                              hipStream_t stream)
{
    const float* imgF      = (const float*)d_in[0];
    const float* kf        = (const float*)d_in[1];
    const float* a_in_w    = (const float*)d_in[2];
    const float* a_conv_w  = (const float*)d_in[3];
    const float* a_conv_b  = (const float*)d_in[4];
    const float* a_xproj_w = (const float*)d_in[5];
    const float* a_dt_w    = (const float*)d_in[6];
    const float* a_dt_b    = (const float*)d_in[7];
    const float* a_A_log   = (const float*)d_in[8];
    const float* a_D       = (const float*)d_in[9];
    const float* a_out_w   = (const float*)d_in[10];
    const float* c_in_w    = (const float*)d_in[11];
    const float* c_conv_w  = (const float*)d_in[12];
    const float* c_conv_b  = (const float*)d_in[13];
    const float* c_xproj_w = (const float*)d_in[14];
    const float* c_dt_w    = (const float*)d_in[15];
    const float* c_dt_b    = (const float*)d_in[16];
    const float* c_A_log   = (const float*)d_in[17];
    const float* c_D       = (const float*)d_in[18];
    const float* c_out_w   = (const float*)d_in[19];

    float* fout = (float*)d_out;

    float* ws = (float*)d_ws;
    float* h_buf  = ws;                      // 1,605,632 floats
    float* S      = ws + 1605632;
    // stage A
    float* score  = S;                       // 802,816 (reused as score2)
    float* xz_a   = S + 802816;              // 3,211,264
    float* xi_a   = S + 4014080;             // 1,605,632 (scan in-place)
    float* xdbl_a = S + 5619712;             // 319,488
    float* dt_a   = S + 5939200;             // 1,605,632
    float* sbuf   = S + 7544832;             // 8,192
    int*   indb   = (int*)(S + 7553024);     // 784
    float* vtopk  = S + 7553808;             // 784
    // stage C (aliases stage A region)
    float* xz_c   = S;                       // 6,422,528
    float* xi_c   = S + 6422528;             // 3,211,264 (scan in-place)
    float* xdbl_c = S + 9633792;             // 125,440
    float* dt_c   = S + 9759232;             // 3,211,264
    // bf16 scratch (beyond the fp32 region: base float offset 14,576,128)
    unsigned short* cwbf  = (unsigned short*)(ws + 14576128);          // 16,777,216 bf16
    unsigned short* h_bf  = (unsigned short*)(ws + 14576128 + 8388608);// 1,835,008 bf16
    unsigned short* yz_bf = (unsigned short*)(ws + 14576128 + 9306112);// 3,670,016 bf16
    // split-K partials:
    //  - step 1 (stage A): bf16 region is dead until step 11 -> reuse it.
    //    8 chunks x 802,816 = 6,422,528 floats at 14,576,128..20,998,656.
    float* CpartS1 = ws + 14576128;
    //  - step 13 (stage C): upper half of cwbf region is dead between
    //    mfma_gemm #11 and tpose_cvt #16. 16 x 784 x 160 floats.
    float* Cpart  = ws + 18770432;
    // means scratch for step 8: dt_a region is dead after scan_kernel (step 6)
    float* means  = dt_a;
    // step-16 split-K partials: whole fp32 S region is dead during the final
    // mfma (z was consumed by gate_cvt). 4 x 784 x 2048 = 6,422,528 floats.
    float* Cpart16 = S;
    // total ws: 25,717,248 floats ~= 103 MB

    // ===== stage A (fp32) =====
    // 1. score[b] = kf[b]^T @ imgF^T : specialized split-K x8 (2048 blocks)
    gemm_s1<<<dim3(16, 2, 64), 256, 0, stream>>>(kf, imgF, CpartS1);
    sk_reduce<<<3136, 256, 0, stream>>>(CpartS1, score, 802816L, 8);

    gemm64<false, false, false, 0><<<dim3(128, 7, 1), 256, 0, stream>>>(
        score, a_in_w, xz_a, nullptr, nullptr, 8192, 392, 98, 98, 392, 392, 0, 0L, 0L, 0L);
    conv_silu_kernel<<<6272, 256, 0, stream>>>(xz_a, a_conv_w, a_conv_b, xi_a, 8, 1024, 196, 392);
    gemm64<false, false, false, 0><<<dim3(128, 1, 1), 256, 0, stream>>>(
        xi_a, a_xproj_w, xdbl_a, nullptr, nullptr, 8192, 39, 196, 196, 39, 39, 0, 0L, 0L, 0L);
    gemm64<false, false, false, 1><<<dim3(128, 4, 1), 256, 0, stream>>>(
        xdbl_a, a_dt_w, dt_a, nullptr, a_dt_b, 8192, 196, 7, 39, 196, 196, 0, 0L, 0L, 0L);
    scan_kernel<64><<<dim3(13, 8, 1), 256, 0, stream>>>(
        xi_a, dt_a, xdbl_a, a_A_log, a_D, xi_a, 196, 1024, 39, 7, 23);
    gemm64<false, false, true, 0><<<dim3(128, 2, 1), 256, 0, stream>>>(
        xi_a, a_out_w, score, xz_a + 196, nullptr, 8192, 98, 196, 196, 98, 98, 392, 0L, 0L, 0L);
    // 8. mean over n + softmax over k (parallel mean, tiny softmax)
    row_mean_kernel<<<2048, 256, 0, stream>>>(score, means);
    softmax1024_kernel<<<8, 256, 0, stream>>>(means, sbuf);
    topk_select_kernel<<<8, 256, 0, stream>>>(sbuf, indb, vtopk);
    gather_kernel<<<dim3(98, 8, 1), 256, 0, stream>>>(imgF, kf, indb, vtopk, h_buf);

    // ===== stage C =====
    // 11. xz_c = h @ c_in_w  (bf16 MFMA, prefetch pipeline)
    tpose_cvt<<<dim3(256, 64, 1), 256, 0, stream>>>(c_in_w, cwbf, 2048, 8192);
    cvt_pad<<<1792, 256, 0, stream>>>(h_buf, h_bf, 784, 896, 2048);
    mfma_gemm<<<dim3(7, 64, 1), 256, 0, stream>>>(
        h_bf, cwbf, xz_c, 784, 8192, 2048, 8192, 2048, 0L);

    // 12. conv + silu -> xi_c
    conv_silu_kernel<<<12544, 256, 0, stream>>>(xz_c, c_conv_w, c_conv_b, xi_c, 8, 98, 4096, 8192);

    // 13. xdbl_c = xi_c @ c_xproj_w (fp32, split-K x16)
    gemm64_sk<<<dim3(13, 3, 16), 256, 0, stream>>>(
        xi_c, c_xproj_w, Cpart, 784, 160, 4096, 4096, 160, 256);
    sk_reduce<<<490, 256, 0, stream>>>(Cpart, xdbl_c, 125440L, 16);

    // 14. dt_c = softplus(xdbl_c[:, :128] @ c_dt_w + c_dt_b) (fp32)
    gemm64<false, false, false, 1><<<dim3(13, 64, 1), 256, 0, stream>>>(
        xdbl_c, c_dt_w, dt_c, nullptr, c_dt_b, 784, 4096, 128, 160, 4096, 4096, 0, 0L, 0L, 0L);

    // 15. selective scan C (in-place)
    scan_kernel<98><<<dim3(256, 8, 1), 256, 0, stream>>>(
        xi_c, dt_c, xdbl_c, c_A_log, c_D, xi_c, 4096, 98, 160, 128, 144);

    // 16. out = (y_c * silu(z_c)) @ c_out_w  (bf16 MFMA, split-K x4 + reduce)
    gate_cvt<<<3584, 256, 0, stream>>>(xi_c, xz_c + 4096, yz_bf, 784, 896, 4096, 8192);
    tpose_cvt<<<dim3(64, 128, 1), 256, 0, stream>>>(c_out_w, cwbf, 4096, 2048);
    mfma_gemm<<<dim3(7, 16, 4), 256, 0, stream>>>(
        yz_bf, cwbf, Cpart16, 784, 2048, 4096, 2048, 1024, 1605632L);
    sk_reduce<<<6272, 256, 0, stream>>>(Cpart16, fout, 1605632L, 4);
}